// Round 9
// baseline (320.571 us; speedup 1.0000x reference)
//
#include <hip/hip_runtime.h>
#include <hip/hip_bf16.h>
#include <math.h>

#define DEVFN __device__ __forceinline__

constexpr int BATCH = 2;
constexpr int SEQ   = 2048;
constexpr int DM    = 256;    // d_model
constexpr int DI    = 512;    // d_inner
constexpr int DSTATE= 128;
constexpr int NH    = 8;
constexpr int HD    = 64;     // mamba head dim
constexpr int CDIM  = 768;    // conv dim
constexpr int DPROJ = 1288;
constexpr int MTOK  = BATCH*SEQ;  // 4096
constexpr int HID   = 1024;   // mlp hidden
constexpr int CHUNK = 32;
constexpr int NCHUNK= SEQ/CHUNK;  // 64
constexpr int NSPLIT= 4;          // flash KV splits
constexpr int KVLEN = SEQ/NSPLIT; // 512

typedef __bf16 bf16x8 __attribute__((ext_vector_type(8)));
typedef __bf16 bf16x4 __attribute__((ext_vector_type(4)));
typedef __bf16 bf16x2 __attribute__((ext_vector_type(2)));
typedef float  f32x4  __attribute__((ext_vector_type(4)));

DEVFN float gelu_exact(float x){ return 0.5f*x*(1.f+erff(x*0.70710678118654752f)); }
DEVFN float silu_f(float x){ return x/(1.f+expf(-x)); }

DEVFN bf16x8 pack8(float4 a, float4 b){
  bf16x8 r;
  r[0]=(__bf16)a.x; r[1]=(__bf16)a.y; r[2]=(__bf16)a.z; r[3]=(__bf16)a.w;
  r[4]=(__bf16)b.x; r[5]=(__bf16)b.y; r[6]=(__bf16)b.z; r[7]=(__bf16)b.w;
  return r;
}
DEVFN f32x4 mfma16(bf16x8 a, bf16x8 b, f32x4 c){
  return __builtin_amdgcn_mfma_f32_16x16x32_bf16(a, b, c, 0, 0, 0);
}

// ---------------------------------------------------------------------------
// bf16-MFMA GEMM, 128x128 tile, 4 waves, BK=32, register-prefetch pipeline.
// AF32: A is fp32 (converted during staging) else bf16. W fp32. Out bf16.
// ---------------------------------------------------------------------------
template<int ACT, bool HASBIAS, bool AF32>
__global__ __launch_bounds__(256)
void gemm128(const void* __restrict__ Av, const float* __restrict__ W,
             const float* __restrict__ bias, __bf16* __restrict__ C,
             int M, int N, int K)
{
  __shared__ __bf16 As[128][40];
  __shared__ __bf16 Ws[128][40];
  const int tid = threadIdx.x;
  const int bm = blockIdx.x * 128, bn = blockIdx.y * 128;
  const int wv = tid >> 6, lane = tid & 63;
  const int quad = lane >> 4, mr = lane & 15;
  const int wm = (wv >> 1) * 64, wn = (wv & 1) * 64;
  const int srow = tid >> 2;
  const int skc  = (tid & 3) * 8;

  const float*  af0 = (const float*)Av + (size_t)(bm + srow)*K + skc;
  const float*  af1 = (const float*)Av + (size_t)(bm + srow + 64)*K + skc;
  const __bf16* ab0 = (const __bf16*)Av + (size_t)(bm + srow)*K + skc;
  const __bf16* ab1 = (const __bf16*)Av + (size_t)(bm + srow + 64)*K + skc;
  const bool wok0 = (bn + srow) < N;
  const bool wok1 = (bn + srow + 64) < N;
  const float* wp0 = W + (size_t)(bn + srow)*K + skc;
  const float* wp1 = W + (size_t)(bn + srow + 64)*K + skc;

  bf16x8 A0, A1;
  if (AF32){
    A0 = pack8(*(const float4*)af0, *(const float4*)(af0+4));
    A1 = pack8(*(const float4*)af1, *(const float4*)(af1+4));
  } else {
    A0 = *(const bf16x8*)ab0;
    A1 = *(const bf16x8*)ab1;
  }
  float4 z4 = make_float4(0,0,0,0);
  float4 W00 = wok0 ? *(const float4*)wp0     : z4;
  float4 W01 = wok0 ? *(const float4*)(wp0+4) : z4;
  float4 W10 = wok1 ? *(const float4*)wp1     : z4;
  float4 W11 = wok1 ? *(const float4*)(wp1+4) : z4;

  f32x4 acc[4][4];
  #pragma unroll
  for (int i=0;i<4;i++)
    #pragma unroll
    for (int j=0;j<4;j++) acc[i][j] = f32x4{0.f,0.f,0.f,0.f};

  for (int k0 = 0; k0 < K; k0 += 32) {
    __syncthreads();
    *(bf16x8*)&As[srow   ][skc] = A0;
    *(bf16x8*)&As[srow+64][skc] = A1;
    *(bf16x8*)&Ws[srow   ][skc] = pack8(W00, W01);
    *(bf16x8*)&Ws[srow+64][skc] = pack8(W10, W11);
    __syncthreads();
    if (k0 + 32 < K){
      int kn = k0 + 32;
      if (AF32){
        A0 = pack8(*(const float4*)(af0+kn), *(const float4*)(af0+kn+4));
        A1 = pack8(*(const float4*)(af1+kn), *(const float4*)(af1+kn+4));
      } else {
        A0 = *(const bf16x8*)(ab0+kn);
        A1 = *(const bf16x8*)(ab1+kn);
      }
      W00 = wok0 ? *(const float4*)(wp0+kn)   : z4;
      W01 = wok0 ? *(const float4*)(wp0+kn+4) : z4;
      W10 = wok1 ? *(const float4*)(wp1+kn)   : z4;
      W11 = wok1 ? *(const float4*)(wp1+kn+4) : z4;
    }
    bf16x8 afr[4], bfr[4];
    #pragma unroll
    for (int i=0;i<4;i++) afr[i] = *(const bf16x8*)&As[wm + i*16 + mr][quad*8];
    #pragma unroll
    for (int j=0;j<4;j++) bfr[j] = *(const bf16x8*)&Ws[wn + j*16 + mr][quad*8];
    #pragma unroll
    for (int i=0;i<4;i++)
      #pragma unroll
      for (int j=0;j<4;j++)
        acc[i][j] = mfma16(afr[i], bfr[j], acc[i][j]);
  }

  #pragma unroll
  for (int j=0;j<4;j++){
    int col = bn + wn + j*16 + mr;
    if (col >= N) continue;
    float bb = HASBIAS ? bias[col] : 0.f;
    #pragma unroll
    for (int i=0;i<4;i++){
      #pragma unroll
      for (int reg=0; reg<4; reg++){
        int row = bm + wm + i*16 + quad*4 + reg;
        float vv = acc[i][j][reg] + bb;
        if (ACT == 1) vv = gelu_exact(vv);
        C[(size_t)row*N + col] = (__bf16)vv;
      }
    }
  }
}

// ---------------------------------------------------------------------------
// out_proj: 64x64 tile, A=ybuf bf16 (K=512), +resid fp32 x, out bf16 hres
// ---------------------------------------------------------------------------
__global__ __launch_bounds__(256)
void gemm_outproj(const __bf16* __restrict__ A, const float* __restrict__ W,
                  const float* __restrict__ residf, __bf16* __restrict__ Cb,
                  int M, int N, int K)
{
  __shared__ __bf16 As[64][40];
  __shared__ __bf16 Ws[64][40];
  const int tid = threadIdx.x;
  const int bm = blockIdx.x*64, bn = blockIdx.y*64;
  const int w = tid >> 6, lane = tid & 63;
  const int quad = lane >> 4, mr = lane & 15;
  const int wm = (w >> 1) * 32, wn = (w & 1) * 32;
  const int srow = tid >> 2, skc = (tid & 3) * 8;

  const __bf16* ap = A + (size_t)(bm + srow)*K + skc;
  const float*  wp = W + (size_t)(bn + srow)*K + skc;
  bf16x8 a0 = *(const bf16x8*)ap;
  float4 w0 = *(const float4*)wp, w1 = *(const float4*)(wp+4);

  f32x4 acc[2][2];
  #pragma unroll
  for (int i=0;i<2;i++)
    #pragma unroll
    for (int j=0;j<2;j++) acc[i][j] = f32x4{0.f,0.f,0.f,0.f};

  for (int k0 = 0; k0 < K; k0 += 32){
    __syncthreads();
    *(bf16x8*)&As[srow][skc] = a0;
    *(bf16x8*)&Ws[srow][skc] = pack8(w0, w1);
    __syncthreads();
    if (k0 + 32 < K){
      a0 = *(const bf16x8*)(ap+k0+32);
      w0 = *(const float4*)(wp+k0+32); w1 = *(const float4*)(wp+k0+36);
    }
    bf16x8 af[2], bfr[2];
    af[0]  = *(const bf16x8*)&As[wm      + mr][quad*8];
    af[1]  = *(const bf16x8*)&As[wm + 16 + mr][quad*8];
    bfr[0] = *(const bf16x8*)&Ws[wn      + mr][quad*8];
    bfr[1] = *(const bf16x8*)&Ws[wn + 16 + mr][quad*8];
    #pragma unroll
    for (int i=0;i<2;i++)
      #pragma unroll
      for (int j=0;j<2;j++)
        acc[i][j] = mfma16(af[i], bfr[j], acc[i][j]);
  }

  #pragma unroll
  for (int j=0;j<2;j++){
    int col = bn + wn + j*16 + mr;
    #pragma unroll
    for (int i=0;i<2;i++)
      #pragma unroll
      for (int reg=0;reg<4;reg++){
        int row = bm + wm + i*16 + quad*4 + reg;
        float vv = acc[i][j][reg] + residf[(size_t)row*N + col];
        Cb[(size_t)row*N + col] = (__bf16)vv;
      }
  }
}

// ---------------------------------------------------------------------------
// batched q,k,v GEMM: grid (M/64, N/64, 3). z=0: A=hres bf16; z=1,2: A=ctx f32.
// z=2 writes transposed Vt[bh][d][t].
// ---------------------------------------------------------------------------
__global__ __launch_bounds__(256)
void qkv_gemm(const __bf16* __restrict__ hres, const float* __restrict__ ctx,
              const float* __restrict__ wq, const float* __restrict__ wk,
              const float* __restrict__ wv, __bf16* __restrict__ qo,
              __bf16* __restrict__ ko, __bf16* __restrict__ vt)
{
  __shared__ __bf16 As[64][40];
  __shared__ __bf16 Ws[64][40];
  const int tid = threadIdx.x;
  const int bm = blockIdx.x*64, bn = blockIdx.y*64, z = blockIdx.z;
  const int K = DM, N = DM;
  const bool abf = (z == 0);
  const float*  W = (z == 0) ? wq : (z == 1) ? wk : wv;
  const int w = tid >> 6, lane = tid & 63;
  const int quad = lane >> 4, mr = lane & 15;
  const int wm = (w >> 1) * 32, wn = (w & 1) * 32;
  const int srow = tid >> 2, skc = (tid & 3) * 8;

  const __bf16* apb = hres + (size_t)(bm + srow)*K + skc;
  const float*  apf = ctx  + (size_t)(bm + srow)*K + skc;
  const float*  wp  = W + (size_t)(bn + srow)*K + skc;
  bf16x8 a0;
  if (abf) a0 = *(const bf16x8*)apb;
  else     a0 = pack8(*(const float4*)apf, *(const float4*)(apf+4));
  float4 w0 = *(const float4*)wp, w1 = *(const float4*)(wp+4);

  f32x4 acc[2][2];
  #pragma unroll
  for (int i=0;i<2;i++)
    #pragma unroll
    for (int j=0;j<2;j++) acc[i][j] = f32x4{0.f,0.f,0.f,0.f};

  for (int k0 = 0; k0 < K; k0 += 32){
    __syncthreads();
    *(bf16x8*)&As[srow][skc] = a0;
    *(bf16x8*)&Ws[srow][skc] = pack8(w0, w1);
    __syncthreads();
    if (k0 + 32 < K){
      if (abf) a0 = *(const bf16x8*)(apb+k0+32);
      else     a0 = pack8(*(const float4*)(apf+k0+32), *(const float4*)(apf+k0+36));
      w0 = *(const float4*)(wp+k0+32); w1 = *(const float4*)(wp+k0+36);
    }
    bf16x8 af[2], bfr[2];
    af[0]  = *(const bf16x8*)&As[wm      + mr][quad*8];
    af[1]  = *(const bf16x8*)&As[wm + 16 + mr][quad*8];
    bfr[0] = *(const bf16x8*)&Ws[wn      + mr][quad*8];
    bfr[1] = *(const bf16x8*)&Ws[wn + 16 + mr][quad*8];
    #pragma unroll
    for (int i=0;i<2;i++)
      #pragma unroll
      for (int j=0;j<2;j++)
        acc[i][j] = mfma16(af[i], bfr[j], acc[i][j]);
  }

  if (z < 2){
    __bf16* C = (z == 0) ? qo : ko;
    #pragma unroll
    for (int j=0;j<2;j++){
      int col = bn + wn + j*16 + mr;
      #pragma unroll
      for (int i=0;i<2;i++)
        #pragma unroll
        for (int reg=0;reg<4;reg++){
          int row = bm + wm + i*16 + quad*4 + reg;
          C[(size_t)row*N + col] = (__bf16)acc[i][j][reg];
        }
    }
  } else {
    #pragma unroll
    for (int j=0;j<2;j++){
      int col = bn + wn + j*16 + mr;
      int h = col >> 5, dl = col & 31;
      #pragma unroll
      for (int i=0;i<2;i++){
        int rowb = bm + wm + i*16 + quad*4;
        int b = rowb >> 11, t = rowb & 2047;
        bf16x4 o;
        #pragma unroll
        for (int reg=0;reg<4;reg++) o[reg] = (__bf16)acc[i][j][reg];
        *(bf16x4*)(vt + ((size_t)(b*NH + h)*32 + dl)*SEQ + t) = o;
      }
    }
  }
}

// ---------------------------------------------------------------------------
// wo GEMM with fused flash-combine A-staging:
// A[row][k] = (sum_s opart[s][row][k]) / (sum_s lpart[s][b*8+h][t]), h=k>>5
// ---------------------------------------------------------------------------
__global__ __launch_bounds__(256)
void wo_gemm(const float* __restrict__ opart, const float* __restrict__ lpart,
             const float* __restrict__ W, const float* __restrict__ bias,
             __bf16* __restrict__ Cb)
{
  __shared__ __bf16 As[64][40];
  __shared__ __bf16 Ws[64][40];
  const int tid = threadIdx.x;
  const int bm = blockIdx.x*64, bn = blockIdx.y*64;
  const int K = DM, N = DM;
  const int w = tid >> 6, lane = tid & 63;
  const int quad = lane >> 4, mr = lane & 15;
  const int wm = (w >> 1) * 32, wn = (w & 1) * 32;
  const int srow = tid >> 2, skc = (tid & 3) * 8;

  const int row = bm + srow;
  const int b = row >> 11, t = row & 2047;
  const float* wp = W + (size_t)(bn + srow)*K + skc;

  f32x4 acc[2][2];
  #pragma unroll
  for (int i=0;i<2;i++)
    #pragma unroll
    for (int j=0;j<2;j++) acc[i][j] = f32x4{0.f,0.f,0.f,0.f};

  for (int k0 = 0; k0 < K; k0 += 32){
    __syncthreads();
    {
      int col = k0 + skc;
      int h = col >> 5;
      float lsum = 0.f;
      #pragma unroll
      for (int s=0;s<NSPLIT;s++)
        lsum += lpart[((size_t)s*16 + b*8 + h)*SEQ + t];
      float inv = 1.f / lsum;
      float va[8] = {0,0,0,0,0,0,0,0};
      #pragma unroll
      for (int s=0;s<NSPLIT;s++){
        const float* op = opart + ((size_t)s*MTOK + row)*DM + col;
        float4 u0 = *(const float4*)op;
        float4 u1 = *(const float4*)(op+4);
        va[0]+=u0.x; va[1]+=u0.y; va[2]+=u0.z; va[3]+=u0.w;
        va[4]+=u1.x; va[5]+=u1.y; va[6]+=u1.z; va[7]+=u1.w;
      }
      bf16x8 a;
      #pragma unroll
      for (int e=0;e<8;e++) a[e] = (__bf16)(va[e]*inv);
      *(bf16x8*)&As[srow][skc] = a;
      float4 w0 = *(const float4*)(wp+k0);
      float4 w1 = *(const float4*)(wp+k0+4);
      *(bf16x8*)&Ws[srow][skc] = pack8(w0, w1);
    }
    __syncthreads();
    bf16x8 af[2], bfr[2];
    af[0]  = *(const bf16x8*)&As[wm      + mr][quad*8];
    af[1]  = *(const bf16x8*)&As[wm + 16 + mr][quad*8];
    bfr[0] = *(const bf16x8*)&Ws[wn      + mr][quad*8];
    bfr[1] = *(const bf16x8*)&Ws[wn + 16 + mr][quad*8];
    #pragma unroll
    for (int i=0;i<2;i++)
      #pragma unroll
      for (int j=0;j<2;j++)
        acc[i][j] = mfma16(af[i], bfr[j], acc[i][j]);
  }

  #pragma unroll
  for (int j=0;j<2;j++){
    int col = bn + wn + j*16 + mr;
    float bb = bias[col];
    #pragma unroll
    for (int i=0;i<2;i++)
      #pragma unroll
      for (int reg=0;reg<4;reg++){
        int r2 = bm + wm + i*16 + quad*4 + reg;
        Cb[(size_t)r2*N + col] = (__bf16)(acc[i][j][reg] + bb);
      }
  }
}

// ---------------------------------------------------------------------------
// fused causal depthwise conv(4)+SiLU and dt/log-dA (c<8 threads)
// ---------------------------------------------------------------------------
__global__ __launch_bounds__(256)
void conv_dt_kernel(const __bf16* __restrict__ zx, const float* __restrict__ convw,
                    const float* __restrict__ convb, const float* __restrict__ dt_bias,
                    const float* __restrict__ A_log, __bf16* __restrict__ xBC,
                    float* __restrict__ dtb, float* __restrict__ ldab)
{
  int idx = blockIdx.x*256 + threadIdx.x;
  int c = idx % CDIM;
  int bt = idx / CDIM;
  int b = bt >> 11, t = bt & 2047;
  float4 w4 = *(const float4*)(convw + c*4);
  const float* wp = (const float*)&w4;
  float acc = convb[c];
  #pragma unroll
  for (int k=0;k<4;k++){
    int ts = t - 3 + k;
    if (ts >= 0)
      acc = fmaf(wp[k], (float)zx[(size_t)(b*SEQ + ts)*DPROJ + DI + c], acc);
  }
  xBC[(size_t)bt*CDIM + c] = (__bf16)silu_f(acc);
  if (c < NH){
    float raw = (float)zx[(size_t)bt*DPROJ + 2*DI + 2*DSTATE + c] + dt_bias[c];
    float dt = fmaxf(raw, 0.f) + log1pf(expf(-fabsf(raw)));
    int o = (b*NH + c)*SEQ + t;
    dtb[o]  = dt;
    ldab[o] = -__expf(A_log[c]) * dt;
  }
}

// ---------------------------------------------------------------------------
// SSD chunk_state (bf16 xBC, bf16 Hc out)
// ---------------------------------------------------------------------------
__global__ __launch_bounds__(256)
void chunk_state(const __bf16* __restrict__ xBC, const float* __restrict__ dtb,
                 const float* __restrict__ ldab, __bf16* __restrict__ Hc,
                 float* __restrict__ Ac)
{
  const int blk = blockIdx.x;
  const int ch = blk & 63, bh = blk >> 6;
  const int b = bh >> 3, h = bh & 7;
  const int t0 = ch*CHUNK;
  const int tid = threadIdx.x;
  __shared__ float csS[CHUNK], wendS[CHUNK];
  __shared__ __bf16 Xw[64][40];
  __shared__ __bf16 Bt[128][40];

  if (tid < 32){
    float v  = ldab[bh*SEQ + t0 + tid];
    float dtv = dtb[bh*SEQ + t0 + tid];
    #pragma unroll
    for (int off=1; off<32; off<<=1){
      float o = __shfl_up(v, off, 32);
      if (tid >= off) v += o;
    }
    csS[tid] = v;
    float cs31 = __shfl(v, 31, 32);
    wendS[tid] = __expf(cs31 - v) * dtv;
  }
  __syncthreads();
  {
    int s  = tid >> 3;
    int pg = (tid & 7) * 8;
    bf16x8 xv = *(const bf16x8*)(xBC + (size_t)(b*SEQ + t0 + s)*CDIM + h*HD + pg);
    float wgt = wendS[s];
    #pragma unroll
    for (int e=0;e<8;e++) Xw[pg+e][s] = (__bf16)((float)xv[e] * wgt);
    int ng = (tid & 7) * 16;
    const __bf16* bp = xBC + (size_t)(b*SEQ + t0 + s)*CDIM + DI + ng;
    bf16x8 b0 = *(const bf16x8*)bp;
    bf16x8 b1 = *(const bf16x8*)(bp+8);
    #pragma unroll
    for (int e=0;e<8;e++){ Bt[ng+e][s] = b0[e]; Bt[ng+8+e][s] = b1[e]; }
  }
  if (tid == 0) Ac[blk] = __expf(csS[31]);
  __syncthreads();

  const int w = tid >> 6, lane = tid & 63, quad = lane >> 4, mr = lane & 15;
  bf16x8 af = *(const bf16x8*)&Xw[w*16 + mr][quad*8];
  __bf16* out = Hc + (size_t)blk*8192;
  #pragma unroll
  for (int j=0;j<8;j++){
    bf16x8 bfm = *(const bf16x8*)&Bt[j*16 + mr][quad*8];
    f32x4 a = mfma16(af, bfm, f32x4{0.f,0.f,0.f,0.f});
    #pragma unroll
    for (int reg=0; reg<4; reg++){
      int p = w*16 + quad*4 + reg;
      out[p*128 + j*16 + mr] = (__bf16)a[reg];
    }
  }
}

// ---------------------------------------------------------------------------
// state_prefix v2: batch all 64 strided loads up front, then serial fma chain.
// grid 256 = 16 bh x 16 sub; thread owns 2 consecutive n.
// ---------------------------------------------------------------------------
__global__ __launch_bounds__(256)
void state_prefix(__bf16* __restrict__ Hc, const float* __restrict__ Ac)
{
  const int blk = blockIdx.x;
  const int bh = blk >> 4, sub = blk & 15;
  const int tid = threadIdx.x;
  const int off = sub*512 + tid*2;
  __shared__ float AcS[64];
  if (tid < 64) AcS[tid] = Ac[bh*64 + tid];
  __bf16* base = Hc + (size_t)bh*64*8192 + off;
  bf16x2 v[64];
  #pragma unroll
  for (int c=0;c<64;c++) v[c] = *(const bf16x2*)(base + (size_t)c*8192);
  __syncthreads();
  float r0 = 0.f, r1 = 0.f;
  #pragma unroll
  for (int c=0;c<64;c++){
    bf16x2 o; o[0] = (__bf16)r0; o[1] = (__bf16)r1;
    *(bf16x2*)(base + (size_t)c*8192) = o;
    float a = AcS[c];
    r0 = fmaf(a, r0, (float)v[c][0]);
    r1 = fmaf(a, r1, (float)v[c][1]);
  }
}

// ---------------------------------------------------------------------------
// SSD chunk_out (bf16 xBC/h0, bf16 y out)
// ---------------------------------------------------------------------------
__global__ __launch_bounds__(256)
void chunk_out(const __bf16* __restrict__ xBC, const float* __restrict__ dtb,
               const float* __restrict__ ldab, const __bf16* __restrict__ h0buf,
               const float* __restrict__ Dparam, __bf16* __restrict__ ybuf)
{
  const int blk = blockIdx.x;
  const int ch = blk & 63, bh = blk >> 6;
  const int b = bh >> 3, h = bh & 7;
  const int t0 = ch*CHUNK;
  const int tid = threadIdx.x;
  __shared__ float csS[CHUNK], dtS[CHUNK];
  __shared__ __bf16 Xct[64][40];
  __shared__ __bf16 Ms[32][40];

  if (tid < 32){
    float v = ldab[bh*SEQ + t0 + tid];
    dtS[tid] = dtb[bh*SEQ + t0 + tid];
    #pragma unroll
    for (int off=1; off<32; off<<=1){
      float o = __shfl_up(v, off, 32);
      if (tid >= off) v += o;
    }
    csS[tid] = v;
  }
  __syncthreads();
  {
    int s  = tid >> 3;
    int pg = (tid & 7) * 8;
    bf16x8 xv = *(const bf16x8*)(xBC + (size_t)(b*SEQ + t0 + s)*CDIM + h*HD + pg);
    #pragma unroll
    for (int e=0;e<8;e++) Xct[pg+e][s] = xv[e];
  }

  const int w = tid >> 6, lane = tid & 63, quad = lane >> 4, mr = lane & 15;
  const int ti = w >> 1, si = w & 1;

  const __bf16* Crow = xBC + (size_t)(b*SEQ + t0 + ti*16 + mr)*CDIM + DI + DSTATE;
  bf16x8 af[4];
  #pragma unroll
  for (int kk=0; kk<4; kk++)
    af[kk] = *(const bf16x8*)(Crow + kk*32 + quad*8);
  f32x4 sacc = f32x4{0.f,0.f,0.f,0.f};
  const __bf16* Brow = xBC + (size_t)(b*SEQ + t0 + si*16 + mr)*CDIM + DI;
  #pragma unroll
  for (int kk=0; kk<4; kk++){
    bf16x8 bfm = *(const bf16x8*)(Brow + kk*32 + quad*8);
    sacc = mfma16(af[kk], bfm, sacc);
  }
  #pragma unroll
  for (int reg=0; reg<4; reg++){
    int t = ti*16 + quad*4 + reg;
    int s = si*16 + mr;
    float m = 0.f;
    if (s <= t) m = __expf(csS[t] - csS[s]) * dtS[s] * sacc[reg];
    Ms[t][s] = (__bf16)m;
  }
  __syncthreads();

  f32x4 acc[2] = { f32x4{0.f,0.f,0.f,0.f}, f32x4{0.f,0.f,0.f,0.f} };
  const __bf16* h0r = h0buf + (size_t)blk*8192;
  #pragma unroll
  for (int j=0;j<2;j++){
    int p = (si*2 + j)*16 + mr;
    #pragma unroll
    for (int kk=0; kk<4; kk++){
      bf16x8 bh0 = *(const bf16x8*)(h0r + (size_t)p*128 + kk*32 + quad*8);
      acc[j] = mfma16(af[kk], bh0, acc[j]);
    }
  }
  #pragma unroll
  for (int reg=0;reg<4;reg++){
    int t = ti*16 + quad*4 + reg;
    float e = __expf(csS[t]);
    acc[0][reg] *= e;
    acc[1][reg] *= e;
  }
  bf16x8 am = *(const bf16x8*)&Ms[ti*16 + mr][quad*8];
  #pragma unroll
  for (int j=0;j<2;j++){
    int p = (si*2 + j)*16 + mr;
    bf16x8 bx = *(const bf16x8*)&Xct[p][quad*8];
    acc[j] = mfma16(am, bx, acc[j]);
  }
  const float Dv = Dparam[h];
  #pragma unroll
  for (int j=0;j<2;j++){
    int p = (si*2 + j)*16 + mr;
    #pragma unroll
    for (int reg=0;reg<4;reg++){
      int t = t0 + ti*16 + quad*4 + reg;
      float xv = (float)xBC[(size_t)(b*SEQ + t)*CDIM + h*HD + p];
      ybuf[(size_t)(b*SEQ + t)*DI + h*HD + p] = (__bf16)fmaf(Dv, xv, acc[j][reg]);
    }
  }
}

// ---------------------------------------------------------------------------
// gated RMSNorm (bf16 y in-place, bf16 z)
// ---------------------------------------------------------------------------
__global__ __launch_bounds__(128)
void rmsgate_kernel(__bf16* __restrict__ y, const __bf16* __restrict__ zx,
                    const float* __restrict__ normw)
{
  const int row = blockIdx.x, tid = threadIdx.x;
  const __bf16* zrow = zx + (size_t)row*DPROJ;
  __bf16* yrow = y + (size_t)row*DI;
  bf16x4 yv = *(const bf16x4*)(yrow + tid*4);
  bf16x4 zv = *(const bf16x4*)(zrow + tid*4);
  float g[4];
  float ss = 0.f;
  #pragma unroll
  for (int e=0;e<4;e++){
    g[e] = (float)yv[e] * silu_f((float)zv[e]);
    ss += g[e]*g[e];
  }
  #pragma unroll
  for (int off=1; off<64; off<<=1) ss += __shfl_xor(ss, off);
  __shared__ float red[2];
  if ((tid & 63)==0) red[tid>>6] = ss;
  __syncthreads();
  float tot = red[0] + red[1];
  float rs = rsqrtf(tot * (1.f/DI) + 1e-5f);
  float4 nw = *(const float4*)(normw + tid*4);
  const float* nwp = (const float*)&nw;
  bf16x4 o;
  #pragma unroll
  for (int e=0;e<4;e++) o[e] = (__bf16)(g[e]*rs*nwp[e]);
  *(bf16x4*)(yrow + tid*4) = o;
}

// ---------------------------------------------------------------------------
// Split-KV MFMA flash attention (hd=32), barrier-free K-loop.
// ---------------------------------------------------------------------------
__global__ __launch_bounds__(256)
void flash_part(const __bf16* __restrict__ qb, const __bf16* __restrict__ kb,
                const __bf16* __restrict__ vt, float* __restrict__ opart,
                float* __restrict__ lpart)
{
  const int qt = blockIdx.x, ksp = blockIdx.y, bh = blockIdx.z;
  const int b = bh >> 3, h = bh & 7;
  const int tid = threadIdx.x;
  const int w = tid >> 6, lane = tid & 63;
  const int quad = lane >> 4, mr = lane & 15;
  const int qrow0 = b*SEQ + qt*128 + w*32;
  const float SC = 0.17677669529663687f;   // 1/sqrt(32)
  __shared__ __bf16 Pq[4][32][72];

  bf16x8 bq[2];
  #pragma unroll
  for (int i2=0;i2<2;i2++)
    bq[i2] = *(const bf16x8*)(qb + (size_t)(qrow0 + i2*16 + mr)*DM + h*32 + quad*8);

  f32x4 accO[2][2];
  #pragma unroll
  for (int i=0;i<2;i++)
    #pragma unroll
    for (int j=0;j<2;j++) accO[i][j] = f32x4{0.f,0.f,0.f,0.f};
  float lacc[2] = {0.f, 0.f};

  for (int kt=0; kt<KVLEN/64; kt++){
    const int kbase = b*SEQ + ksp*KVLEN + kt*64;
    float tl[2] = {0.f, 0.f};
    #pragma unroll
    for (int ik=0; ik<4; ik++){
      bf16x8 ak = *(const bf16x8*)(kb + (size_t)(kbase + ik*16 + mr)*DM + h*32 + quad*8);
      #pragma unroll
      for (int jq=0; jq<2; jq++){
        f32x4 st = mfma16(ak, bq[jq], f32x4{0.f,0.f,0.f,0.f});
        bf16x4 e4;
        float sa = 0.f;
        #pragma unroll
        for (int reg=0; reg<4; reg++){
          float e = __expf(st[reg] * SC);
          sa += e;
          e4[reg] = (__bf16)e;
        }
        tl[jq] += sa;
        *(bf16x4*)&Pq[w][jq*16 + mr][ik*16 + quad*4] = e4;
      }
    }
    #pragma unroll
    for (int jq=0; jq<2; jq++){
      float v = tl[jq];
      v += __shfl_xor(v, 16);
      v += __shfl_xor(v, 32);
      lacc[jq] += v;
    }
    #pragma unroll
    for (int ks=0; ks<2; ks++){
      bf16x8 pa0 = *(const bf16x8*)&Pq[w][     mr][ks*32 + quad*8];
      bf16x8 pa1 = *(const bf16x8*)&Pq[w][16 + mr][ks*32 + quad*8];
      #pragma unroll
      for (int j2=0; j2<2; j2++){
        bf16x8 bv = *(const bf16x8*)(vt + ((size_t)bh*32 + j2*16 + mr)*SEQ
                        + ksp*KVLEN + kt*64 + ks*32 + quad*8);
        accO[0][j2] = mfma16(pa0, bv, accO[0][j2]);
        accO[1][j2] = mfma16(pa1, bv, accO[1][j2]);
      }
    }
  }

  #pragma unroll
  for (int i2=0;i2<2;i2++)
    #pragma unroll
    for (int j2=0;j2<2;j2++)
      #pragma unroll
      for (int reg=0;reg<4;reg++){
        int row = qrow0 + i2*16 + quad*4 + reg;
        opart[((size_t)ksp*MTOK + row)*DM + h*32 + j2*16 + mr] = accO[i2][j2][reg];
      }
  if (quad == 0){
    #pragma unroll
    for (int jq=0;jq<2;jq++)
      lpart[((size_t)ksp*16 + bh)*SEQ + (qt*128 + w*32 + jq*16 + mr)] = lacc[jq];
  }
}

// ---------------------------------------------------------------------------
// LayerNorm over 1024, in place (bf16)
// ---------------------------------------------------------------------------
__global__ __launch_bounds__(256)
void lnorm_kernel(__bf16* __restrict__ hb, const float* __restrict__ lnw,
                  const float* __restrict__ lnb)
{
  const int row = blockIdx.x, tid = threadIdx.x;
  __bf16* hr = hb + (size_t)row*HID;
  bf16x4 v4 = *(const bf16x4*)(hr + tid*4);
  float v[4];
  float sum = 0.f, sq = 0.f;
  #pragma unroll
  for (int e=0;e<4;e++){ v[e] = (float)v4[e]; sum += v[e]; sq += v[e]*v[e]; }
  #pragma unroll
  for (int off=1; off<64; off<<=1){ sum += __shfl_xor(sum,off); sq += __shfl_xor(sq,off); }
  __shared__ float s1[4], s2[4];
  int w = tid>>6;
  if ((tid & 63)==0){ s1[w]=sum; s2[w]=sq; }
  __syncthreads();
  sum = (s1[0]+s1[1])+(s1[2]+s1[3]);
  sq  = (s2[0]+s2[1])+(s2[2]+s2[3]);
  float mu = sum * (1.f/HID);
  float var = sq * (1.f/HID) - mu*mu;
  float rstd = rsqrtf(var + 1e-5f);
  float4 wv = *(const float4*)(lnw + tid*4);
  float4 bv = *(const float4*)(lnb + tid*4);
  const float* wp = (const float*)&wv;
  const float* bp = (const float*)&bv;
  bf16x4 o;
  #pragma unroll
  for (int e=0;e<4;e++) o[e] = (__bf16)((v[e]-mu)*rstd*wp[e] + bp[e]);
  *(bf16x4*)(hr + tid*4) = o;
}

// ---------------------------------------------------------------------------
// pool LN output: partial column sums. grid 128 = 2b x 64 seg (32 rows each)
// ---------------------------------------------------------------------------
__global__ __launch_bounds__(256)
void pool_ln(const __bf16* __restrict__ h1, float* __restrict__ pp)
{
  const int blk = blockIdx.x;
  const int b = blk >> 6, seg = blk & 63;
  const int tid = threadIdx.x;
  const int c4 = tid*4;
  float4 s = make_float4(0,0,0,0);
  const __bf16* basep = h1 + ((size_t)(b*SEQ + seg*32))*HID + c4;
  #pragma unroll 4
  for (int r=0;r<32;r++){
    bf16x4 v = *(const bf16x4*)(basep + (size_t)r*HID);
    s.x += (float)v[0]; s.y += (float)v[1]; s.z += (float)v[2]; s.w += (float)v[3];
  }
  *(float4*)(pp + ((size_t)(b*64+seg))*HID + c4) = s;
}

// ---------------------------------------------------------------------------
// head: out = ((mean pooled) @ w2^T + b2) @ head_w^T + head_b.  2 blocks.
// (mean commutes with the fc2 linear layer)
// ---------------------------------------------------------------------------
__global__ __launch_bounds__(256)
void head2_kernel(const float* __restrict__ pp, const float* __restrict__ w2,
                  const float* __restrict__ b2, const float* __restrict__ hw,
                  const float* __restrict__ hb, float* __restrict__ out)
{
  const int b = blockIdx.x, tid = threadIdx.x;
  __shared__ float pooled[HID];
  __shared__ float w2h[DM];
  {
    int c4 = tid*4;
    float4 s = make_float4(0,0,0,0);
    #pragma unroll 4
    for (int seg=0;seg<64;seg++){
      float4 v = *(const float4*)(pp + ((size_t)(b*64+seg))*HID + c4);
      s.x+=v.x; s.y+=v.y; s.z+=v.z; s.w+=v.w;
    }
    const float inv = 1.f/(float)SEQ;
    *(float4*)&pooled[c4] = make_float4(s.x*inv, s.y*inv, s.z*inv, s.w*inv);
  }
  __syncthreads();
  {
    float acc = 0.f;
    const float* wr = w2 + (size_t)tid*HID;
    #pragma unroll 8
    for (int k=0;k<HID;k+=4){
      float4 wv4 = *(const float4*)(wr+k);
      float4 pv  = *(const float4*)&pooled[k];
      acc += wv4.x*pv.x + wv4.y*pv.y + wv4.z*pv.z + wv4.w*pv.w;
    }
    w2h[tid] = acc + b2[tid];
  }
  __syncthreads();
  if (tid < 128){
    int cls = tid >> 6, lane = tid & 63;
    float acc = 0.f;
    for (int c=lane;c<DM;c+=64) acc += w2h[c]*hw[cls*DM+c];
    #pragma unroll
    for (int off=1;off<64;off<<=1) acc += __shfl_xor(acc, off);
    if (lane == 0) out[b*2 + cls] = acc + hb[cls];
  }
}

// ---------------------------------------------------------------------------
extern "C" void kernel_launch(void* const* d_in, const int* in_sizes, int n_in,
                              void* d_out, int out_size, void* d_ws, size_t ws_size,
                              hipStream_t stream)
{
  const float* x         = (const float*)d_in[0];
  const float* context   = (const float*)d_in[1];
  const float* in_proj_w = (const float*)d_in[2];
  const float* conv_w    = (const float*)d_in[3];
  const float* conv_b    = (const float*)d_in[4];
  const float* dt_bias   = (const float*)d_in[5];
  const float* A_log     = (const float*)d_in[6];
  const float* D_param   = (const float*)d_in[7];
  const float* norm_w    = (const float*)d_in[8];
  const float* out_proj_w= (const float*)d_in[9];
  const float* wq  = (const float*)d_in[10];
  const float* wk  = (const float*)d_in[11];
  const float* wv  = (const float*)d_in[12];
  const float* wo  = (const float*)d_in[13];
  const float* wo_b= (const float*)d_in[14];
  const float* w1  = (const float*)d_in[15];
  const float* b1  = (const float*)d_in[16];
  const float* ln_w= (const float*)d_in[17];
  const float* ln_b= (const float*)d_in[18];
  const float* w2  = (const float*)d_in[19];
  const float* b2  = (const float*)d_in[20];
  const float* head_w = (const float*)d_in[21];
  const float* head_b = (const float*)d_in[22];
  float* out = (float*)d_out;
  float* ws  = (float*)d_ws;

  // workspace layout (float offsets; bf16 regions cast). Aliases noted.
  __bf16* zx    = (__bf16*)ws;                     // 2,637,824 fl
  __bf16* xBC   = (__bf16*)(ws + 2637824);         // 1,572,864
  float* dtb    = ws + 4210688;                    // 32,768
  float* ldab   = ws + 4243456;                    // 32,768
  __bf16* Hcb   = (__bf16*)(ws + 4276224);         // 4,194,304 fl
  float* Acb    = ws + 8470528;                    // 1,024
  __bf16* ybuf  = (__bf16*)(ws + 8471552);         // 1,048,576
  __bf16* hres  = (__bf16*)(ws + 9520128);         // 524,288
  __bf16* qbf   = (__bf16*)(ws + 10044416);        // 524,288
  __bf16* kbf   = (__bf16*)(ws + 10568704);        // 524,288
  __bf16* vtbf  = (__bf16*)(ws + 11092992);        // 524,288
  float* opart  = ws + 11617280;                   // 4,194,304
  float* lpart  = ws + 15811584;                   // 131,072
  __bf16* o2bf  = (__bf16*)(ws + 15942656);        // 524,288
  // h1 (4096x1024 bf16 = 1,048,576 fl) -> Hcb region (dead after chunk_out)
  __bf16* h1bf  = (__bf16*)(ws + 4276224);
  // poolpart [2][64][1024] = 131,072 fl -> opart region (dead after wo_gemm)
  float* poolp  = ws + 11617280;

  const dim3 g64(MTOK/64, DM/64);                  // 256 blocks

  // 1. in_proj (4096 x 1288 x 256), A fp32 -> zx bf16
  gemm128<0,false,true><<<dim3(MTOK/128, (DPROJ+127)/128), dim3(256), 0, stream>>>(
      x, in_proj_w, nullptr, zx, MTOK, DPROJ, DM);
  // 2. conv + silu + dt/log-dA (fused)
  conv_dt_kernel<<<dim3(MTOK*CDIM/256), dim3(256), 0, stream>>>(
      zx, conv_w, conv_b, dt_bias, A_log, xBC, dtb, ldab);
  // 3. SSD scan
  chunk_state<<<dim3(BATCH*NH*NCHUNK), dim3(256), 0, stream>>>(
      xBC, dtb, ldab, Hcb, Acb);
  state_prefix<<<dim3(256), dim3(256), 0, stream>>>(Hcb, Acb);
  chunk_out<<<dim3(BATCH*NH*NCHUNK), dim3(256), 0, stream>>>(
      xBC, dtb, ldab, Hcb, D_param, ybuf);
  // 4. gated rmsnorm (in place, bf16)
  rmsgate_kernel<<<dim3(MTOK), dim3(128), 0, stream>>>(ybuf, zx, norm_w);
  // 5. out_proj + residual x (fp32) -> hres bf16
  gemm_outproj<<<g64, dim3(256), 0, stream>>>(
      ybuf, out_proj_w, x, hres, MTOK, DM, DI);
  // 6. q,k,v in one launch; v written transposed
  qkv_gemm<<<dim3(MTOK/64, DM/64, 3), dim3(256), 0, stream>>>(
      hres, context, wq, wk, wv, qbf, kbf, vtbf);
  // 7. attention partials
  flash_part<<<dim3(SEQ/128, NSPLIT, BATCH*NH), dim3(256), 0, stream>>>(
      qbf, kbf, vtbf, opart, lpart);
  // 8. wo out_proj with fused flash-combine -> o2 bf16
  wo_gemm<<<g64, dim3(256), 0, stream>>>(opart, lpart, wo, wo_b, o2bf);
  // 9. mlp fc1 + gelu -> h1 bf16 (in Hcb region)
  gemm128<1,true,false><<<dim3(MTOK/128, HID/128), dim3(256), 0, stream>>>(
      o2bf, w1, b1, h1bf, MTOK, HID, DM);
  // 10. layernorm (in place, bf16)
  lnorm_kernel<<<dim3(MTOK), dim3(256), 0, stream>>>(h1bf, ln_w, ln_b);
  // 11. pool LN output (mean commutes with fc2) -> partials
  pool_ln<<<dim3(128), dim3(256), 0, stream>>>(h1bf, poolp);
  // 12. head: (pooled @ w2^T + b2) @ head_w^T + head_b
  head2_kernel<<<dim3(BATCH), dim3(256), 0, stream>>>(
      poolp, w2, b2, head_w, head_b, out);
  (void)in_sizes; (void)n_in; (void)out_size; (void)ws_size;
}

// Round 10
// 304.332 us; speedup vs baseline: 1.0534x; 1.0534x over previous
//
#include <hip/hip_runtime.h>
#include <hip/hip_bf16.h>
#include <math.h>

#define DEVFN __device__ __forceinline__

constexpr int BATCH = 2;
constexpr int SEQ   = 2048;
constexpr int DM    = 256;    // d_model
constexpr int DI    = 512;    // d_inner
constexpr int DSTATE= 128;
constexpr int NH    = 8;
constexpr int HD    = 64;     // mamba head dim
constexpr int CDIM  = 768;    // conv dim
constexpr int DPROJ = 1288;
constexpr int MTOK  = BATCH*SEQ;  // 4096
constexpr int HID   = 1024;   // mlp hidden
constexpr int CHUNK = 32;
constexpr int NCHUNK= SEQ/CHUNK;  // 64
constexpr int NSPLIT= 2;          // flash KV splits
constexpr int KVLEN = SEQ/NSPLIT; // 1024

// bf16 weight pool offsets (elements)
constexpr int W_INPROJ = 0;              // 1288*256 = 329728
constexpr int W_OUTPROJ= 329728;         // 256*512  = 131072
constexpr int W_Q      = 460800;         // 65536
constexpr int W_K      = 526336;         // 65536
constexpr int W_V      = 591872;         // 65536
constexpr int W_O      = 657408;         // 65536
constexpr int W_1      = 722944;         // 262144
constexpr int W_TOT    = 985088;

typedef __bf16 bf16x8 __attribute__((ext_vector_type(8)));
typedef __bf16 bf16x4 __attribute__((ext_vector_type(4)));
typedef __bf16 bf16x2 __attribute__((ext_vector_type(2)));
typedef float  f32x4  __attribute__((ext_vector_type(4)));

DEVFN float gelu_exact(float x){ return 0.5f*x*(1.f+erff(x*0.70710678118654752f)); }
DEVFN float silu_f(float x){ return x/(1.f+expf(-x)); }

DEVFN bf16x8 pack8(float4 a, float4 b){
  bf16x8 r;
  r[0]=(__bf16)a.x; r[1]=(__bf16)a.y; r[2]=(__bf16)a.z; r[3]=(__bf16)a.w;
  r[4]=(__bf16)b.x; r[5]=(__bf16)b.y; r[6]=(__bf16)b.z; r[7]=(__bf16)b.w;
  return r;
}
DEVFN f32x4 mfma16(bf16x8 a, bf16x8 b, f32x4 c){
  return __builtin_amdgcn_mfma_f32_16x16x32_bf16(a, b, c, 0, 0, 0);
}

// ---------------------------------------------------------------------------
// convert all GEMM weights fp32 -> bf16 pool (one pass)
// ---------------------------------------------------------------------------
__global__ __launch_bounds__(256)
void cvt_w(const float* __restrict__ w_inproj, const float* __restrict__ w_outproj,
           const float* __restrict__ wq, const float* __restrict__ wk,
           const float* __restrict__ wv, const float* __restrict__ wo,
           const float* __restrict__ w1, __bf16* __restrict__ wbf)
{
  int i4 = (blockIdx.x*256 + threadIdx.x)*4;
  const float* src;
  if      (i4 < W_OUTPROJ) src = w_inproj  + i4;
  else if (i4 < W_Q)       src = w_outproj + (i4 - W_OUTPROJ);
  else if (i4 < W_K)       src = wq + (i4 - W_Q);
  else if (i4 < W_V)       src = wk + (i4 - W_K);
  else if (i4 < W_O)       src = wv + (i4 - W_V);
  else if (i4 < W_1)       src = wo + (i4 - W_O);
  else                     src = w1 + (i4 - W_1);
  float4 v = *(const float4*)src;
  bf16x4 o;
  o[0]=(__bf16)v.x; o[1]=(__bf16)v.y; o[2]=(__bf16)v.z; o[3]=(__bf16)v.w;
  *(bf16x4*)(wbf + i4) = o;
}

// ---------------------------------------------------------------------------
// bf16-MFMA GEMM, 128x128 tile, 4 waves, BK=32, register-prefetch pipeline.
// AF32: A fp32 (cvt during staging) else bf16. W bf16. Out bf16.
// ---------------------------------------------------------------------------
template<int ACT, bool HASBIAS, bool AF32>
__global__ __launch_bounds__(256)
void gemm128(const void* __restrict__ Av, const __bf16* __restrict__ W,
             const float* __restrict__ bias, __bf16* __restrict__ C,
             int M, int N, int K)
{
  __shared__ __bf16 As[128][40];
  __shared__ __bf16 Ws[128][40];
  const int tid = threadIdx.x;
  const int bm = blockIdx.x * 128, bn = blockIdx.y * 128;
  const int wv = tid >> 6, lane = tid & 63;
  const int quad = lane >> 4, mr = lane & 15;
  const int wm = (wv >> 1) * 64, wn = (wv & 1) * 64;
  const int srow = tid >> 2;
  const int skc  = (tid & 3) * 8;

  const float*  af0 = (const float*)Av + (size_t)(bm + srow)*K + skc;
  const float*  af1 = (const float*)Av + (size_t)(bm + srow + 64)*K + skc;
  const __bf16* ab0 = (const __bf16*)Av + (size_t)(bm + srow)*K + skc;
  const __bf16* ab1 = (const __bf16*)Av + (size_t)(bm + srow + 64)*K + skc;
  const bool wok0 = (bn + srow) < N;
  const bool wok1 = (bn + srow + 64) < N;
  const __bf16* wp0 = W + (size_t)(bn + srow)*K + skc;
  const __bf16* wp1 = W + (size_t)(bn + srow + 64)*K + skc;

  bf16x8 zb{};
  bf16x8 A0, A1;
  if (AF32){
    A0 = pack8(*(const float4*)af0, *(const float4*)(af0+4));
    A1 = pack8(*(const float4*)af1, *(const float4*)(af1+4));
  } else {
    A0 = *(const bf16x8*)ab0;
    A1 = *(const bf16x8*)ab1;
  }
  bf16x8 W0 = wok0 ? *(const bf16x8*)wp0 : zb;
  bf16x8 W1 = wok1 ? *(const bf16x8*)wp1 : zb;

  f32x4 acc[4][4];
  #pragma unroll
  for (int i=0;i<4;i++)
    #pragma unroll
    for (int j=0;j<4;j++) acc[i][j] = f32x4{0.f,0.f,0.f,0.f};

  for (int k0 = 0; k0 < K; k0 += 32) {
    __syncthreads();
    *(bf16x8*)&As[srow   ][skc] = A0;
    *(bf16x8*)&As[srow+64][skc] = A1;
    *(bf16x8*)&Ws[srow   ][skc] = W0;
    *(bf16x8*)&Ws[srow+64][skc] = W1;
    __syncthreads();
    if (k0 + 32 < K){
      int kn = k0 + 32;
      if (AF32){
        A0 = pack8(*(const float4*)(af0+kn), *(const float4*)(af0+kn+4));
        A1 = pack8(*(const float4*)(af1+kn), *(const float4*)(af1+kn+4));
      } else {
        A0 = *(const bf16x8*)(ab0+kn);
        A1 = *(const bf16x8*)(ab1+kn);
      }
      W0 = wok0 ? *(const bf16x8*)(wp0+kn) : zb;
      W1 = wok1 ? *(const bf16x8*)(wp1+kn) : zb;
    }
    bf16x8 afr[4], bfr[4];
    #pragma unroll
    for (int i=0;i<4;i++) afr[i] = *(const bf16x8*)&As[wm + i*16 + mr][quad*8];
    #pragma unroll
    for (int j=0;j<4;j++) bfr[j] = *(const bf16x8*)&Ws[wn + j*16 + mr][quad*8];
    #pragma unroll
    for (int i=0;i<4;i++)
      #pragma unroll
      for (int j=0;j<4;j++)
        acc[i][j] = mfma16(afr[i], bfr[j], acc[i][j]);
  }

  #pragma unroll
  for (int j=0;j<4;j++){
    int col = bn + wn + j*16 + mr;
    if (col >= N) continue;
    float bb = HASBIAS ? bias[col] : 0.f;
    #pragma unroll
    for (int i=0;i<4;i++){
      #pragma unroll
      for (int reg=0; reg<4; reg++){
        int row = bm + wm + i*16 + quad*4 + reg;
        float vv = acc[i][j][reg] + bb;
        if (ACT == 1) vv = gelu_exact(vv);
        C[(size_t)row*N + col] = (__bf16)vv;
      }
    }
  }
}

// ---------------------------------------------------------------------------
// 64x64-tile GEMM, A bf16, W bf16, register-prefetch pipelined.
// HASRESF: add fp32 resid. Out bf16. N=256 shapes.
// ---------------------------------------------------------------------------
template<bool HASBIAS, bool HASRESF>
__global__ __launch_bounds__(256)
void gemm64b(const __bf16* __restrict__ A, const __bf16* __restrict__ W,
             const float* __restrict__ bias, const float* __restrict__ residf,
             __bf16* __restrict__ Cb, int M, int N, int K)
{
  __shared__ __bf16 As[64][40];
  __shared__ __bf16 Ws[64][40];
  const int tid = threadIdx.x;
  const int bm = blockIdx.x*64, bn = blockIdx.y*64;
  const int w = tid >> 6, lane = tid & 63;
  const int quad = lane >> 4, mr = lane & 15;
  const int wm = (w >> 1) * 32, wn = (w & 1) * 32;
  const int srow = tid >> 2, skc = (tid & 3) * 8;

  const __bf16* ap = A + (size_t)(bm + srow)*K + skc;
  const __bf16* wp = W + (size_t)(bn + srow)*K + skc;
  bf16x8 a0 = *(const bf16x8*)ap;
  bf16x8 w0 = *(const bf16x8*)wp;

  f32x4 acc[2][2];
  #pragma unroll
  for (int i=0;i<2;i++)
    #pragma unroll
    for (int j=0;j<2;j++) acc[i][j] = f32x4{0.f,0.f,0.f,0.f};

  for (int k0 = 0; k0 < K; k0 += 32){
    __syncthreads();
    *(bf16x8*)&As[srow][skc] = a0;
    *(bf16x8*)&Ws[srow][skc] = w0;
    __syncthreads();
    if (k0 + 32 < K){
      a0 = *(const bf16x8*)(ap+k0+32);
      w0 = *(const bf16x8*)(wp+k0+32);
    }
    bf16x8 af[2], bfr[2];
    af[0]  = *(const bf16x8*)&As[wm      + mr][quad*8];
    af[1]  = *(const bf16x8*)&As[wm + 16 + mr][quad*8];
    bfr[0] = *(const bf16x8*)&Ws[wn      + mr][quad*8];
    bfr[1] = *(const bf16x8*)&Ws[wn + 16 + mr][quad*8];
    #pragma unroll
    for (int i=0;i<2;i++)
      #pragma unroll
      for (int j=0;j<2;j++)
        acc[i][j] = mfma16(af[i], bfr[j], acc[i][j]);
  }

  #pragma unroll
  for (int j=0;j<2;j++){
    int col = bn + wn + j*16 + mr;
    float bb = HASBIAS ? bias[col] : 0.f;
    #pragma unroll
    for (int i=0;i<2;i++)
      #pragma unroll
      for (int reg=0;reg<4;reg++){
        int row = bm + wm + i*16 + quad*4 + reg;
        float vv = acc[i][j][reg] + bb;
        if (HASRESF) vv += residf[(size_t)row*N + col];
        Cb[(size_t)row*N + col] = (__bf16)vv;
      }
  }
}

// ---------------------------------------------------------------------------
// batched q,k,v GEMM: grid (M/64, N/64, 3). z=0: A=hres bf16; z=1,2: A=ctx f32.
// z=2 writes transposed Vt[bh][d][t]. W bf16.
// ---------------------------------------------------------------------------
__global__ __launch_bounds__(256)
void qkv_gemm(const __bf16* __restrict__ hres, const float* __restrict__ ctx,
              const __bf16* __restrict__ wbf, __bf16* __restrict__ qo,
              __bf16* __restrict__ ko, __bf16* __restrict__ vt)
{
  __shared__ __bf16 As[64][40];
  __shared__ __bf16 Ws[64][40];
  const int tid = threadIdx.x;
  const int bm = blockIdx.x*64, bn = blockIdx.y*64, z = blockIdx.z;
  const int K = DM, N = DM;
  const bool abf = (z == 0);
  const __bf16* W = wbf + ((z == 0) ? W_Q : (z == 1) ? W_K : W_V);
  const int w = tid >> 6, lane = tid & 63;
  const int quad = lane >> 4, mr = lane & 15;
  const int wm = (w >> 1) * 32, wn = (w & 1) * 32;
  const int srow = tid >> 2, skc = (tid & 3) * 8;

  const __bf16* apb = hres + (size_t)(bm + srow)*K + skc;
  const float*  apf = ctx  + (size_t)(bm + srow)*K + skc;
  const __bf16* wp  = W + (size_t)(bn + srow)*K + skc;
  bf16x8 a0;
  if (abf) a0 = *(const bf16x8*)apb;
  else     a0 = pack8(*(const float4*)apf, *(const float4*)(apf+4));
  bf16x8 w0 = *(const bf16x8*)wp;

  f32x4 acc[2][2];
  #pragma unroll
  for (int i=0;i<2;i++)
    #pragma unroll
    for (int j=0;j<2;j++) acc[i][j] = f32x4{0.f,0.f,0.f,0.f};

  for (int k0 = 0; k0 < K; k0 += 32){
    __syncthreads();
    *(bf16x8*)&As[srow][skc] = a0;
    *(bf16x8*)&Ws[srow][skc] = w0;
    __syncthreads();
    if (k0 + 32 < K){
      if (abf) a0 = *(const bf16x8*)(apb+k0+32);
      else     a0 = pack8(*(const float4*)(apf+k0+32), *(const float4*)(apf+k0+36));
      w0 = *(const bf16x8*)(wp+k0+32);
    }
    bf16x8 af[2], bfr[2];
    af[0]  = *(const bf16x8*)&As[wm      + mr][quad*8];
    af[1]  = *(const bf16x8*)&As[wm + 16 + mr][quad*8];
    bfr[0] = *(const bf16x8*)&Ws[wn      + mr][quad*8];
    bfr[1] = *(const bf16x8*)&Ws[wn + 16 + mr][quad*8];
    #pragma unroll
    for (int i=0;i<2;i++)
      #pragma unroll
      for (int j=0;j<2;j++)
        acc[i][j] = mfma16(af[i], bfr[j], acc[i][j]);
  }

  if (z < 2){
    __bf16* C = (z == 0) ? qo : ko;
    #pragma unroll
    for (int j=0;j<2;j++){
      int col = bn + wn + j*16 + mr;
      #pragma unroll
      for (int i=0;i<2;i++)
        #pragma unroll
        for (int reg=0;reg<4;reg++){
          int row = bm + wm + i*16 + quad*4 + reg;
          C[(size_t)row*N + col] = (__bf16)acc[i][j][reg];
        }
    }
  } else {
    #pragma unroll
    for (int j=0;j<2;j++){
      int col = bn + wn + j*16 + mr;
      int h = col >> 5, dl = col & 31;
      #pragma unroll
      for (int i=0;i<2;i++){
        int rowb = bm + wm + i*16 + quad*4;
        int b = rowb >> 11, t = rowb & 2047;
        bf16x4 o;
        #pragma unroll
        for (int reg=0;reg<4;reg++) o[reg] = (__bf16)acc[i][j][reg];
        *(bf16x4*)(vt + ((size_t)(b*NH + h)*32 + dl)*SEQ + t) = o;
      }
    }
  }
}

// ---------------------------------------------------------------------------
// fused causal depthwise conv(4)+SiLU (x4 channels) and dt/log-dA
// ---------------------------------------------------------------------------
__global__ __launch_bounds__(256)
void conv_dt_kernel(const __bf16* __restrict__ zx, const float* __restrict__ convw,
                    const float* __restrict__ convb, const float* __restrict__ dt_bias,
                    const float* __restrict__ A_log, __bf16* __restrict__ xBC,
                    float* __restrict__ dtb, float* __restrict__ ldab)
{
  int idx = blockIdx.x*256 + threadIdx.x;     // over MTOK*CDIM/4
  int c4 = (idx % (CDIM/4))*4;
  int bt = idx / (CDIM/4);
  int b = bt >> 11, t = bt & 2047;
  float acc[4];
  float4 cb = *(const float4*)(convb + c4);
  acc[0]=cb.x; acc[1]=cb.y; acc[2]=cb.z; acc[3]=cb.w;
  float4 wrow[4];
  #pragma unroll
  for (int j=0;j<4;j++) wrow[j] = *(const float4*)(convw + (c4+j)*4);
  #pragma unroll
  for (int k=0;k<4;k++){
    int ts = t - 3 + k;
    if (ts >= 0){
      bf16x4 xv = *(const bf16x4*)(zx + (size_t)(b*SEQ + ts)*DPROJ + DI + c4);
      const float* wk4[4] = {(const float*)&wrow[0], (const float*)&wrow[1],
                             (const float*)&wrow[2], (const float*)&wrow[3]};
      #pragma unroll
      for (int j=0;j<4;j++) acc[j] = fmaf(wk4[j][k], (float)xv[j], acc[j]);
    }
  }
  bf16x4 o;
  #pragma unroll
  for (int j=0;j<4;j++) o[j] = (__bf16)silu_f(acc[j]);
  *(bf16x4*)(xBC + (size_t)bt*CDIM + c4) = o;
  if (c4 < NH){
    #pragma unroll
    for (int j=0;j<4;j++){
      int h = c4 + j;
      float raw = (float)zx[(size_t)bt*DPROJ + 2*DI + 2*DSTATE + h] + dt_bias[h];
      float dt = fmaxf(raw, 0.f) + log1pf(expf(-fabsf(raw)));
      int oo = (b*NH + h)*SEQ + t;
      dtb[oo]  = dt;
      ldab[oo] = -__expf(A_log[h]) * dt;
    }
  }
}

// ---------------------------------------------------------------------------
// SSD chunk_state (bf16 xBC, bf16 Hc out)
// ---------------------------------------------------------------------------
__global__ __launch_bounds__(256)
void chunk_state(const __bf16* __restrict__ xBC, const float* __restrict__ dtb,
                 const float* __restrict__ ldab, __bf16* __restrict__ Hc,
                 float* __restrict__ Ac)
{
  const int blk = blockIdx.x;
  const int ch = blk & 63, bh = blk >> 6;
  const int b = bh >> 3, h = bh & 7;
  const int t0 = ch*CHUNK;
  const int tid = threadIdx.x;
  __shared__ float csS[CHUNK], wendS[CHUNK];
  __shared__ __bf16 Xw[64][40];
  __shared__ __bf16 Bt[128][40];

  if (tid < 32){
    float v  = ldab[bh*SEQ + t0 + tid];
    float dtv = dtb[bh*SEQ + t0 + tid];
    #pragma unroll
    for (int off=1; off<32; off<<=1){
      float o = __shfl_up(v, off, 32);
      if (tid >= off) v += o;
    }
    csS[tid] = v;
    float cs31 = __shfl(v, 31, 32);
    wendS[tid] = __expf(cs31 - v) * dtv;
  }
  __syncthreads();
  {
    int s  = tid >> 3;
    int pg = (tid & 7) * 8;
    bf16x8 xv = *(const bf16x8*)(xBC + (size_t)(b*SEQ + t0 + s)*CDIM + h*HD + pg);
    float wgt = wendS[s];
    #pragma unroll
    for (int e=0;e<8;e++) Xw[pg+e][s] = (__bf16)((float)xv[e] * wgt);
    int ng = (tid & 7) * 16;
    const __bf16* bp = xBC + (size_t)(b*SEQ + t0 + s)*CDIM + DI + ng;
    bf16x8 b0 = *(const bf16x8*)bp;
    bf16x8 b1 = *(const bf16x8*)(bp+8);
    #pragma unroll
    for (int e=0;e<8;e++){ Bt[ng+e][s] = b0[e]; Bt[ng+8+e][s] = b1[e]; }
  }
  if (tid == 0) Ac[blk] = __expf(csS[31]);
  __syncthreads();

  const int w = tid >> 6, lane = tid & 63, quad = lane >> 4, mr = lane & 15;
  bf16x8 af = *(const bf16x8*)&Xw[w*16 + mr][quad*8];
  __bf16* out = Hc + (size_t)blk*8192;
  #pragma unroll
  for (int j=0;j<8;j++){
    bf16x8 bfm = *(const bf16x8*)&Bt[j*16 + mr][quad*8];
    f32x4 a = mfma16(af, bfm, f32x4{0.f,0.f,0.f,0.f});
    #pragma unroll
    for (int reg=0; reg<4; reg++){
      int p = w*16 + quad*4 + reg;
      out[p*128 + j*16 + mr] = (__bf16)a[reg];
    }
  }
}

// ---------------------------------------------------------------------------
// state_prefix: batch loads then serial fma chain
// ---------------------------------------------------------------------------
__global__ __launch_bounds__(256)
void state_prefix(__bf16* __restrict__ Hc, const float* __restrict__ Ac)
{
  const int blk = blockIdx.x;
  const int bh = blk >> 4, sub = blk & 15;
  const int tid = threadIdx.x;
  const int off = sub*512 + tid*2;
  __shared__ float AcS[64];
  if (tid < 64) AcS[tid] = Ac[bh*64 + tid];
  __bf16* base = Hc + (size_t)bh*64*8192 + off;
  bf16x2 v[64];
  #pragma unroll
  for (int c=0;c<64;c++) v[c] = *(const bf16x2*)(base + (size_t)c*8192);
  __syncthreads();
  float r0 = 0.f, r1 = 0.f;
  #pragma unroll
  for (int c=0;c<64;c++){
    bf16x2 o; o[0] = (__bf16)r0; o[1] = (__bf16)r1;
    *(bf16x2*)(base + (size_t)c*8192) = o;
    float a = AcS[c];
    r0 = fmaf(a, r0, (float)v[c][0]);
    r1 = fmaf(a, r1, (float)v[c][1]);
  }
}

// ---------------------------------------------------------------------------
// SSD chunk_out (bf16 xBC/h0, bf16 y out)
// ---------------------------------------------------------------------------
__global__ __launch_bounds__(256)
void chunk_out(const __bf16* __restrict__ xBC, const float* __restrict__ dtb,
               const float* __restrict__ ldab, const __bf16* __restrict__ h0buf,
               const float* __restrict__ Dparam, __bf16* __restrict__ ybuf)
{
  const int blk = blockIdx.x;
  const int ch = blk & 63, bh = blk >> 6;
  const int b = bh >> 3, h = bh & 7;
  const int t0 = ch*CHUNK;
  const int tid = threadIdx.x;
  __shared__ float csS[CHUNK], dtS[CHUNK];
  __shared__ __bf16 Xct[64][40];
  __shared__ __bf16 Ms[32][40];

  if (tid < 32){
    float v = ldab[bh*SEQ + t0 + tid];
    dtS[tid] = dtb[bh*SEQ + t0 + tid];
    #pragma unroll
    for (int off=1; off<32; off<<=1){
      float o = __shfl_up(v, off, 32);
      if (tid >= off) v += o;
    }
    csS[tid] = v;
  }
  __syncthreads();
  {
    int s  = tid >> 3;
    int pg = (tid & 7) * 8;
    bf16x8 xv = *(const bf16x8*)(xBC + (size_t)(b*SEQ + t0 + s)*CDIM + h*HD + pg);
    #pragma unroll
    for (int e=0;e<8;e++) Xct[pg+e][s] = xv[e];
  }

  const int w = tid >> 6, lane = tid & 63, quad = lane >> 4, mr = lane & 15;
  const int ti = w >> 1, si = w & 1;

  const __bf16* Crow = xBC + (size_t)(b*SEQ + t0 + ti*16 + mr)*CDIM + DI + DSTATE;
  bf16x8 af[4];
  #pragma unroll
  for (int kk=0; kk<4; kk++)
    af[kk] = *(const bf16x8*)(Crow + kk*32 + quad*8);
  f32x4 sacc = f32x4{0.f,0.f,0.f,0.f};
  const __bf16* Brow = xBC + (size_t)(b*SEQ + t0 + si*16 + mr)*CDIM + DI;
  #pragma unroll
  for (int kk=0; kk<4; kk++){
    bf16x8 bfm = *(const bf16x8*)(Brow + kk*32 + quad*8);
    sacc = mfma16(af[kk], bfm, sacc);
  }
  #pragma unroll
  for (int reg=0; reg<4; reg++){
    int t = ti*16 + quad*4 + reg;
    int s = si*16 + mr;
    float m = 0.f;
    if (s <= t) m = __expf(csS[t] - csS[s]) * dtS[s] * sacc[reg];
    Ms[t][s] = (__bf16)m;
  }
  __syncthreads();

  f32x4 acc[2] = { f32x4{0.f,0.f,0.f,0.f}, f32x4{0.f,0.f,0.f,0.f} };
  const __bf16* h0r = h0buf + (size_t)blk*8192;
  #pragma unroll
  for (int j=0;j<2;j++){
    int p = (si*2 + j)*16 + mr;
    #pragma unroll
    for (int kk=0; kk<4; kk++){
      bf16x8 bh0 = *(const bf16x8*)(h0r + (size_t)p*128 + kk*32 + quad*8);
      acc[j] = mfma16(af[kk], bh0, acc[j]);
    }
  }
  #pragma unroll
  for (int reg=0;reg<4;reg++){
    int t = ti*16 + quad*4 + reg;
    float e = __expf(csS[t]);
    acc[0][reg] *= e;
    acc[1][reg] *= e;
  }
  bf16x8 am = *(const bf16x8*)&Ms[ti*16 + mr][quad*8];
  #pragma unroll
  for (int j=0;j<2;j++){
    int p = (si*2 + j)*16 + mr;
    bf16x8 bx = *(const bf16x8*)&Xct[p][quad*8];
    acc[j] = mfma16(am, bx, acc[j]);
  }
  const float Dv = Dparam[h];
  #pragma unroll
  for (int j=0;j<2;j++){
    int p = (si*2 + j)*16 + mr;
    #pragma unroll
    for (int reg=0;reg<4;reg++){
      int t = t0 + ti*16 + quad*4 + reg;
      float xv = (float)xBC[(size_t)(b*SEQ + t)*CDIM + h*HD + p];
      ybuf[(size_t)(b*SEQ + t)*DI + h*HD + p] = (__bf16)fmaf(Dv, xv, acc[j][reg]);
    }
  }
}

// ---------------------------------------------------------------------------
// gated RMSNorm (bf16 y in-place, bf16 z)
// ---------------------------------------------------------------------------
__global__ __launch_bounds__(128)
void rmsgate_kernel(__bf16* __restrict__ y, const __bf16* __restrict__ zx,
                    const float* __restrict__ normw)
{
  const int row = blockIdx.x, tid = threadIdx.x;
  const __bf16* zrow = zx + (size_t)row*DPROJ;
  __bf16* yrow = y + (size_t)row*DI;
  bf16x4 yv = *(const bf16x4*)(yrow + tid*4);
  bf16x4 zv = *(const bf16x4*)(zrow + tid*4);
  float g[4];
  float ss = 0.f;
  #pragma unroll
  for (int e=0;e<4;e++){
    g[e] = (float)yv[e] * silu_f((float)zv[e]);
    ss += g[e]*g[e];
  }
  #pragma unroll
  for (int off=1; off<64; off<<=1) ss += __shfl_xor(ss, off);
  __shared__ float red[2];
  if ((tid & 63)==0) red[tid>>6] = ss;
  __syncthreads();
  float tot = red[0] + red[1];
  float rs = rsqrtf(tot * (1.f/DI) + 1e-5f);
  float4 nw = *(const float4*)(normw + tid*4);
  const float* nwp = (const float*)&nw;
  bf16x4 o;
  #pragma unroll
  for (int e=0;e<4;e++) o[e] = (__bf16)(g[e]*rs*nwp[e]);
  *(bf16x4*)(yrow + tid*4) = o;
}

// ---------------------------------------------------------------------------
// Split-KV MFMA flash attention (hd=32), barrier-free K-loop. NSPLIT=2.
// ---------------------------------------------------------------------------
__global__ __launch_bounds__(256)
void flash_part(const __bf16* __restrict__ qb, const __bf16* __restrict__ kb,
                const __bf16* __restrict__ vt, float* __restrict__ opart,
                float* __restrict__ lpart)
{
  const int qt = blockIdx.x, ksp = blockIdx.y, bh = blockIdx.z;
  const int b = bh >> 3, h = bh & 7;
  const int tid = threadIdx.x;
  const int w = tid >> 6, lane = tid & 63;
  const int quad = lane >> 4, mr = lane & 15;
  const int qrow0 = b*SEQ + qt*128 + w*32;
  const float SC = 0.17677669529663687f;   // 1/sqrt(32)
  __shared__ __bf16 Pq[4][32][72];

  bf16x8 bq[2];
  #pragma unroll
  for (int i2=0;i2<2;i2++)
    bq[i2] = *(const bf16x8*)(qb + (size_t)(qrow0 + i2*16 + mr)*DM + h*32 + quad*8);

  f32x4 accO[2][2];
  #pragma unroll
  for (int i=0;i<2;i++)
    #pragma unroll
    for (int j=0;j<2;j++) accO[i][j] = f32x4{0.f,0.f,0.f,0.f};
  float lacc[2] = {0.f, 0.f};

  for (int kt=0; kt<KVLEN/64; kt++){
    const int kbase = b*SEQ + ksp*KVLEN + kt*64;
    float tl[2] = {0.f, 0.f};
    #pragma unroll
    for (int ik=0; ik<4; ik++){
      bf16x8 ak = *(const bf16x8*)(kb + (size_t)(kbase + ik*16 + mr)*DM + h*32 + quad*8);
      #pragma unroll
      for (int jq=0; jq<2; jq++){
        f32x4 st = mfma16(ak, bq[jq], f32x4{0.f,0.f,0.f,0.f});
        bf16x4 e4;
        float sa = 0.f;
        #pragma unroll
        for (int reg=0; reg<4; reg++){
          float e = __expf(st[reg] * SC);
          sa += e;
          e4[reg] = (__bf16)e;
        }
        tl[jq] += sa;
        *(bf16x4*)&Pq[w][jq*16 + mr][ik*16 + quad*4] = e4;
      }
    }
    #pragma unroll
    for (int jq=0; jq<2; jq++){
      float v = tl[jq];
      v += __shfl_xor(v, 16);
      v += __shfl_xor(v, 32);
      lacc[jq] += v;
    }
    #pragma unroll
    for (int ks=0; ks<2; ks++){
      bf16x8 pa0 = *(const bf16x8*)&Pq[w][     mr][ks*32 + quad*8];
      bf16x8 pa1 = *(const bf16x8*)&Pq[w][16 + mr][ks*32 + quad*8];
      #pragma unroll
      for (int j2=0; j2<2; j2++){
        bf16x8 bv = *(const bf16x8*)(vt + ((size_t)bh*32 + j2*16 + mr)*SEQ
                        + ksp*KVLEN + kt*64 + ks*32 + quad*8);
        accO[0][j2] = mfma16(pa0, bv, accO[0][j2]);
        accO[1][j2] = mfma16(pa1, bv, accO[1][j2]);
      }
    }
  }

  #pragma unroll
  for (int i2=0;i2<2;i2++)
    #pragma unroll
    for (int j2=0;j2<2;j2++)
      #pragma unroll
      for (int reg=0;reg<4;reg++){
        int row = qrow0 + i2*16 + quad*4 + reg;
        opart[((size_t)ksp*MTOK + row)*DM + h*32 + j2*16 + mr] = accO[i2][j2][reg];
      }
  if (quad == 0){
    #pragma unroll
    for (int jq=0;jq<2;jq++)
      lpart[((size_t)ksp*16 + bh)*SEQ + (qt*128 + w*32 + jq*16 + mr)] = lacc[jq];
  }
}

// combine: o = sum_s O_s / sum_s l_s  -> bf16 (streaming)
__global__ __launch_bounds__(256)
void flash_combine(const float* __restrict__ opart, const float* __restrict__ lpart,
                   __bf16* __restrict__ o)
{
  int idx = blockIdx.x*256 + threadIdx.x;   // over MTOK*64
  int row = idx >> 6, d4 = (idx & 63)*4;
  int h = d4 >> 5;
  int b = row >> 11, t = row & 2047;
  float sx=0.f, sy=0.f, sz=0.f, sw=0.f, lsum=0.f;
  #pragma unroll
  for (int s4=0; s4<NSPLIT; s4++){
    float4 vv = *(const float4*)(opart + ((size_t)s4*MTOK + row)*DM + d4);
    sx += vv.x; sy += vv.y; sz += vv.z; sw += vv.w;
    lsum += lpart[((size_t)s4*16 + b*8 + h)*SEQ + t];
  }
  float inv = 1.f / lsum;
  bf16x4 ov;
  ov[0]=(__bf16)(sx*inv); ov[1]=(__bf16)(sy*inv);
  ov[2]=(__bf16)(sz*inv); ov[3]=(__bf16)(sw*inv);
  *(bf16x4*)(o + (size_t)row*DM + d4) = ov;
}

// ---------------------------------------------------------------------------
// fused LayerNorm + pool partial: block = 16 rows; no h1 writeback.
// grid 256 = b(2) x seg(128). poolp[b*128+seg][1024]
// ---------------------------------------------------------------------------
__global__ __launch_bounds__(256)
void ln_pool(const __bf16* __restrict__ h1, const float* __restrict__ lnw,
             const float* __restrict__ lnb, float* __restrict__ pp)
{
  const int blk = blockIdx.x;
  const int tid = threadIdx.x;
  const int row0 = blk*16;
  __shared__ float s1[4], s2[4];
  float4 wv = *(const float4*)(lnw + tid*4);
  float4 bv = *(const float4*)(lnb + tid*4);
  const float* wp = (const float*)&wv;
  const float* bp = (const float*)&bv;
  float acc[4] = {0.f,0.f,0.f,0.f};
  for (int r=0;r<16;r++){
    bf16x4 v4 = *(const bf16x4*)(h1 + (size_t)(row0+r)*HID + tid*4);
    float v[4];
    float sum=0.f, sq=0.f;
    #pragma unroll
    for (int e=0;e<4;e++){ v[e]=(float)v4[e]; sum+=v[e]; sq+=v[e]*v[e]; }
    #pragma unroll
    for (int off=1; off<64; off<<=1){ sum += __shfl_xor(sum,off); sq += __shfl_xor(sq,off); }
    int w = tid>>6;
    __syncthreads();                 // protect s1/s2 from previous iter
    if ((tid & 63)==0){ s1[w]=sum; s2[w]=sq; }
    __syncthreads();
    sum = (s1[0]+s1[1])+(s1[2]+s1[3]);
    sq  = (s2[0]+s2[1])+(s2[2]+s2[3]);
    float mu = sum * (1.f/HID);
    float var = sq * (1.f/HID) - mu*mu;
    float rstd = rsqrtf(var + 1e-5f);
    #pragma unroll
    for (int e=0;e<4;e++) acc[e] += (v[e]-mu)*rstd*wp[e] + bp[e];
  }
  *(float4*)(pp + (size_t)blk*HID + tid*4) = make_float4(acc[0],acc[1],acc[2],acc[3]);
}

// ---------------------------------------------------------------------------
// head: out = ((mean pooled) @ w2^T + b2) @ head_w^T + head_b.  2 blocks.
// ---------------------------------------------------------------------------
__global__ __launch_bounds__(256)
void head2_kernel(const float* __restrict__ pp, const float* __restrict__ w2,
                  const float* __restrict__ b2, const float* __restrict__ hw,
                  const float* __restrict__ hb, float* __restrict__ out)
{
  const int b = blockIdx.x, tid = threadIdx.x;
  __shared__ float pooled[HID];
  __shared__ float w2h[DM];
  {
    int c4 = tid*4;
    float4 s = make_float4(0,0,0,0);
    #pragma unroll 4
    for (int seg=0;seg<128;seg++){
      float4 v = *(const float4*)(pp + ((size_t)(b*128+seg))*HID + c4);
      s.x+=v.x; s.y+=v.y; s.z+=v.z; s.w+=v.w;
    }
    const float inv = 1.f/(float)SEQ;
    *(float4*)&pooled[c4] = make_float4(s.x*inv, s.y*inv, s.z*inv, s.w*inv);
  }
  __syncthreads();
  {
    float acc = 0.f;
    const float* wr = w2 + (size_t)tid*HID;
    #pragma unroll 8
    for (int k=0;k<HID;k+=4){
      float4 wv4 = *(const float4*)(wr+k);
      float4 pv  = *(const float4*)&pooled[k];
      acc += wv4.x*pv.x + wv4.y*pv.y + wv4.z*pv.z + wv4.w*pv.w;
    }
    w2h[tid] = acc + b2[tid];
  }
  __syncthreads();
  if (tid < 128){
    int cls = tid >> 6, lane = tid & 63;
    float acc = 0.f;
    for (int c=lane;c<DM;c+=64) acc += w2h[c]*hw[cls*DM+c];
    #pragma unroll
    for (int off=1;off<64;off<<=1) acc += __shfl_xor(acc, off);
    if (lane == 0) out[b*2 + cls] = acc + hb[cls];
  }
}

// ---------------------------------------------------------------------------
extern "C" void kernel_launch(void* const* d_in, const int* in_sizes, int n_in,
                              void* d_out, int out_size, void* d_ws, size_t ws_size,
                              hipStream_t stream)
{
  const float* x         = (const float*)d_in[0];
  const float* context   = (const float*)d_in[1];
  const float* in_proj_w = (const float*)d_in[2];
  const float* conv_w    = (const float*)d_in[3];
  const float* conv_b    = (const float*)d_in[4];
  const float* dt_bias   = (const float*)d_in[5];
  const float* A_log     = (const float*)d_in[6];
  const float* D_param   = (const float*)d_in[7];
  const float* norm_w    = (const float*)d_in[8];
  const float* out_proj_w= (const float*)d_in[9];
  const float* wq  = (const float*)d_in[10];
  const float* wk  = (const float*)d_in[11];
  const float* wv  = (const float*)d_in[12];
  const float* wo  = (const float*)d_in[13];
  const float* wo_b= (const float*)d_in[14];
  const float* w1  = (const float*)d_in[15];
  const float* b1  = (const float*)d_in[16];
  const float* ln_w= (const float*)d_in[17];
  const float* ln_b= (const float*)d_in[18];
  const float* w2  = (const float*)d_in[19];
  const float* b2  = (const float*)d_in[20];
  const float* head_w = (const float*)d_in[21];
  const float* head_b = (const float*)d_in[22];
  float* out = (float*)d_out;
  float* ws  = (float*)d_ws;

  // workspace layout (float offsets; bf16 regions cast). Aliases noted.
  __bf16* zx    = (__bf16*)ws;                     // 2,637,824 fl
  __bf16* xBC   = (__bf16*)(ws + 2637824);         // 1,572,864
  float* dtb    = ws + 4210688;                    // 32,768
  float* ldab   = ws + 4243456;                    // 32,768
  __bf16* Hcb   = (__bf16*)(ws + 4276224);         // 4,194,304 fl
  float* Acb    = ws + 8470528;                    // 1,024
  __bf16* ybuf  = (__bf16*)(ws + 8471552);         // 1,048,576
  __bf16* hres  = (__bf16*)(ws + 9520128);         // 524,288
  __bf16* qbf   = (__bf16*)(ws + 10044416);        // 524,288
  __bf16* kbf   = (__bf16*)(ws + 10568704);        // 524,288
  __bf16* vtbf  = (__bf16*)(ws + 11092992);        // 524,288
  float* opart  = ws + 11617280;                   // 2,097,152 (NSPLIT=2)
  float* lpart  = ws + 13714432;                   // 65,536
  __bf16* obf   = (__bf16*)(ws + 13779968);        // 524,288
  __bf16* o2bf  = (__bf16*)(ws + 14304256);        // 524,288
  __bf16* wbf   = (__bf16*)(ws + 14828544);        // 492,544 (985088 bf16)
  // h1 (4096x1024 bf16 = 1,048,576 fl) -> Hcb region (dead after chunk_out)
  __bf16* h1bf  = (__bf16*)(ws + 4276224);
  // poolp [256][1024] fp32 = 262,144 fl -> opart region (dead after combine)
  float* poolp  = ws + 11617280;

  const dim3 g64(MTOK/64, DM/64);                  // 256 blocks

  // 0. convert weights to bf16 pool (962 blocks)
  cvt_w<<<dim3(W_TOT/1024), dim3(256), 0, stream>>>(
      in_proj_w, out_proj_w, wq, wk, wv, wo, w1, wbf);
  // 1. in_proj (A fp32) -> zx bf16
  gemm128<0,false,true><<<dim3(MTOK/128, (DPROJ+127)/128), dim3(256), 0, stream>>>(
      x, wbf + W_INPROJ, nullptr, zx, MTOK, DPROJ, DM);
  // 2. conv + silu + dt/log-dA (fused, x4 channels)
  conv_dt_kernel<<<dim3(MTOK*CDIM/1024), dim3(256), 0, stream>>>(
      zx, conv_w, conv_b, dt_bias, A_log, xBC, dtb, ldab);
  // 3. SSD scan
  chunk_state<<<dim3(BATCH*NH*NCHUNK), dim3(256), 0, stream>>>(
      xBC, dtb, ldab, Hcb, Acb);
  state_prefix<<<dim3(256), dim3(256), 0, stream>>>(Hcb, Acb);
  chunk_out<<<dim3(BATCH*NH*NCHUNK), dim3(256), 0, stream>>>(
      xBC, dtb, ldab, Hcb, D_param, ybuf);
  // 4. gated rmsnorm (in place, bf16)
  rmsgate_kernel<<<dim3(MTOK), dim3(128), 0, stream>>>(ybuf, zx, norm_w);
  // 5. out_proj + residual x (fp32) -> hres bf16  (K=512)
  gemm64b<false,true><<<g64, dim3(256), 0, stream>>>(
      ybuf, wbf + W_OUTPROJ, nullptr, x, hres, MTOK, DM, DI);
  // 6. q,k,v in one launch; v written transposed
  qkv_gemm<<<dim3(MTOK/64, DM/64, 3), dim3(256), 0, stream>>>(
      hres, context, wbf, qbf, kbf, vtbf);
  // 7. attention partials (NSPLIT=2) + streaming combine
  flash_part<<<dim3(SEQ/128, NSPLIT, BATCH*NH), dim3(256), 0, stream>>>(
      qbf, kbf, vtbf, opart, lpart);
  flash_combine<<<dim3(MTOK*64/256), dim3(256), 0, stream>>>(opart, lpart, obf);
  // 8. attention out_proj (+bias) -> o2 bf16  (K=256)
  gemm64b<true,false><<<g64, dim3(256), 0, stream>>>(
      obf, wbf + W_O, wo_b, nullptr, o2bf, MTOK, DM, DM);
  // 9. mlp fc1 + gelu -> h1 bf16 (in Hcb region)
  gemm128<1,true,false><<<dim3(MTOK/128, HID/128), dim3(256), 0, stream>>>(
      o2bf, wbf + W_1, b1, h1bf, MTOK, HID, DM);
  // 10. fused layernorm + pool partials (no h1 writeback)
  ln_pool<<<dim3(256), dim3(256), 0, stream>>>(h1bf, ln_w, ln_b, poolp);
  // 11. head: (pooled @ w2^T + b2) @ head_w^T + head_b
  head2_kernel<<<dim3(BATCH), dim3(256), 0, stream>>>(
      poolp, w2, b2, head_w, head_b, out);
  (void)in_sizes; (void)n_in; (void)out_size; (void)ws_size;
}

// Round 11
// 300.452 us; speedup vs baseline: 1.0670x; 1.0129x over previous
//
#include <hip/hip_runtime.h>
#include <hip/hip_bf16.h>
#include <math.h>

#define DEVFN __device__ __forceinline__

constexpr int BATCH = 2;
constexpr int SEQ   = 2048;
constexpr int DM    = 256;    // d_model
constexpr int DI    = 512;    // d_inner
constexpr int DSTATE= 128;
constexpr int NH    = 8;
constexpr int HD    = 64;     // mamba head dim
constexpr int CDIM  = 768;    // conv dim
constexpr int DPROJ = 1288;
constexpr int MTOK  = BATCH*SEQ;  // 4096
constexpr int HID   = 1024;   // mlp hidden
constexpr int CHUNK = 32;
constexpr int NCHUNK= SEQ/CHUNK;  // 64
constexpr int NSPLIT= 4;          // flash KV splits (latency-bound: occupancy wins)
constexpr int KVLEN = SEQ/NSPLIT; // 512
constexpr int NKT   = KVLEN/64;   // 8

// bf16 weight pool offsets (elements)
constexpr int W_INPROJ = 0;              // 1288*256 = 329728
constexpr int W_OUTPROJ= 329728;         // 256*512  = 131072
constexpr int W_Q      = 460800;         // 65536
constexpr int W_K      = 526336;         // 65536
constexpr int W_V      = 591872;         // 65536
constexpr int W_O      = 657408;         // 65536
constexpr int W_1      = 722944;         // 262144
constexpr int W_TOT    = 985088;

typedef __bf16 bf16x8 __attribute__((ext_vector_type(8)));
typedef __bf16 bf16x4 __attribute__((ext_vector_type(4)));
typedef __bf16 bf16x2 __attribute__((ext_vector_type(2)));
typedef float  f32x4  __attribute__((ext_vector_type(4)));

DEVFN float gelu_exact(float x){ return 0.5f*x*(1.f+erff(x*0.70710678118654752f)); }
DEVFN float silu_f(float x){ return x/(1.f+expf(-x)); }

DEVFN bf16x8 pack8(float4 a, float4 b){
  bf16x8 r;
  r[0]=(__bf16)a.x; r[1]=(__bf16)a.y; r[2]=(__bf16)a.z; r[3]=(__bf16)a.w;
  r[4]=(__bf16)b.x; r[5]=(__bf16)b.y; r[6]=(__bf16)b.z; r[7]=(__bf16)b.w;
  return r;
}
DEVFN f32x4 mfma16(bf16x8 a, bf16x8 b, f32x4 c){
  return __builtin_amdgcn_mfma_f32_16x16x32_bf16(a, b, c, 0, 0, 0);
}

// ---------------------------------------------------------------------------
// convert all GEMM weights fp32 -> bf16 pool (one pass)
// ---------------------------------------------------------------------------
__global__ __launch_bounds__(256)
void cvt_w(const float* __restrict__ w_inproj, const float* __restrict__ w_outproj,
           const float* __restrict__ wq, const float* __restrict__ wk,
           const float* __restrict__ wv, const float* __restrict__ wo,
           const float* __restrict__ w1, __bf16* __restrict__ wbf)
{
  int i4 = (blockIdx.x*256 + threadIdx.x)*4;
  const float* src;
  if      (i4 < W_OUTPROJ) src = w_inproj  + i4;
  else if (i4 < W_Q)       src = w_outproj + (i4 - W_OUTPROJ);
  else if (i4 < W_K)       src = wq + (i4 - W_Q);
  else if (i4 < W_V)       src = wk + (i4 - W_K);
  else if (i4 < W_O)       src = wv + (i4 - W_V);
  else if (i4 < W_1)       src = wo + (i4 - W_O);
  else                     src = w1 + (i4 - W_1);
  float4 v = *(const float4*)src;
  bf16x4 o;
  o[0]=(__bf16)v.x; o[1]=(__bf16)v.y; o[2]=(__bf16)v.z; o[3]=(__bf16)v.w;
  *(bf16x4*)(wbf + i4) = o;
}

// ---------------------------------------------------------------------------
// bf16-MFMA GEMM, 128x128 tile, 4 waves, BK=32, register-prefetch pipeline.
// AF32: A fp32 (cvt during staging) else bf16. W bf16. Out bf16.
// ---------------------------------------------------------------------------
template<int ACT, bool HASBIAS, bool AF32>
__global__ __launch_bounds__(256)
void gemm128(const void* __restrict__ Av, const __bf16* __restrict__ W,
             const float* __restrict__ bias, __bf16* __restrict__ C,
             int M, int N, int K)
{
  __shared__ __bf16 As[128][40];
  __shared__ __bf16 Ws[128][40];
  const int tid = threadIdx.x;
  const int bm = blockIdx.x * 128, bn = blockIdx.y * 128;
  const int wv = tid >> 6, lane = tid & 63;
  const int quad = lane >> 4, mr = lane & 15;
  const int wm = (wv >> 1) * 64, wn = (wv & 1) * 64;
  const int srow = tid >> 2;
  const int skc  = (tid & 3) * 8;

  const float*  af0 = (const float*)Av + (size_t)(bm + srow)*K + skc;
  const float*  af1 = (const float*)Av + (size_t)(bm + srow + 64)*K + skc;
  const __bf16* ab0 = (const __bf16*)Av + (size_t)(bm + srow)*K + skc;
  const __bf16* ab1 = (const __bf16*)Av + (size_t)(bm + srow + 64)*K + skc;
  const bool wok0 = (bn + srow) < N;
  const bool wok1 = (bn + srow + 64) < N;
  const __bf16* wp0 = W + (size_t)(bn + srow)*K + skc;
  const __bf16* wp1 = W + (size_t)(bn + srow + 64)*K + skc;

  bf16x8 zb{};
  bf16x8 A0, A1;
  if (AF32){
    A0 = pack8(*(const float4*)af0, *(const float4*)(af0+4));
    A1 = pack8(*(const float4*)af1, *(const float4*)(af1+4));
  } else {
    A0 = *(const bf16x8*)ab0;
    A1 = *(const bf16x8*)ab1;
  }
  bf16x8 W0 = wok0 ? *(const bf16x8*)wp0 : zb;
  bf16x8 W1 = wok1 ? *(const bf16x8*)wp1 : zb;

  f32x4 acc[4][4];
  #pragma unroll
  for (int i=0;i<4;i++)
    #pragma unroll
    for (int j=0;j<4;j++) acc[i][j] = f32x4{0.f,0.f,0.f,0.f};

  for (int k0 = 0; k0 < K; k0 += 32) {
    __syncthreads();
    *(bf16x8*)&As[srow   ][skc] = A0;
    *(bf16x8*)&As[srow+64][skc] = A1;
    *(bf16x8*)&Ws[srow   ][skc] = W0;
    *(bf16x8*)&Ws[srow+64][skc] = W1;
    __syncthreads();
    if (k0 + 32 < K){
      int kn = k0 + 32;
      if (AF32){
        A0 = pack8(*(const float4*)(af0+kn), *(const float4*)(af0+kn+4));
        A1 = pack8(*(const float4*)(af1+kn), *(const float4*)(af1+kn+4));
      } else {
        A0 = *(const bf16x8*)(ab0+kn);
        A1 = *(const bf16x8*)(ab1+kn);
      }
      W0 = wok0 ? *(const bf16x8*)(wp0+kn) : zb;
      W1 = wok1 ? *(const bf16x8*)(wp1+kn) : zb;
    }
    bf16x8 afr[4], bfr[4];
    #pragma unroll
    for (int i=0;i<4;i++) afr[i] = *(const bf16x8*)&As[wm + i*16 + mr][quad*8];
    #pragma unroll
    for (int j=0;j<4;j++) bfr[j] = *(const bf16x8*)&Ws[wn + j*16 + mr][quad*8];
    #pragma unroll
    for (int i=0;i<4;i++)
      #pragma unroll
      for (int j=0;j<4;j++)
        acc[i][j] = mfma16(afr[i], bfr[j], acc[i][j]);
  }

  #pragma unroll
  for (int j=0;j<4;j++){
    int col = bn + wn + j*16 + mr;
    if (col >= N) continue;
    float bb = HASBIAS ? bias[col] : 0.f;
    #pragma unroll
    for (int i=0;i<4;i++){
      #pragma unroll
      for (int reg=0; reg<4; reg++){
        int row = bm + wm + i*16 + quad*4 + reg;
        float vv = acc[i][j][reg] + bb;
        if (ACT == 1) vv = gelu_exact(vv);
        C[(size_t)row*N + col] = (__bf16)vv;
      }
    }
  }
}

// ---------------------------------------------------------------------------
// 64x64-tile GEMM, A bf16, W bf16, register-prefetch pipelined.
// ---------------------------------------------------------------------------
template<bool HASBIAS, bool HASRESF>
__global__ __launch_bounds__(256)
void gemm64b(const __bf16* __restrict__ A, const __bf16* __restrict__ W,
             const float* __restrict__ bias, const float* __restrict__ residf,
             __bf16* __restrict__ Cb, int M, int N, int K)
{
  __shared__ __bf16 As[64][40];
  __shared__ __bf16 Ws[64][40];
  const int tid = threadIdx.x;
  const int bm = blockIdx.x*64, bn = blockIdx.y*64;
  const int w = tid >> 6, lane = tid & 63;
  const int quad = lane >> 4, mr = lane & 15;
  const int wm = (w >> 1) * 32, wn = (w & 1) * 32;
  const int srow = tid >> 2, skc = (tid & 3) * 8;

  const __bf16* ap = A + (size_t)(bm + srow)*K + skc;
  const __bf16* wp = W + (size_t)(bn + srow)*K + skc;
  bf16x8 a0 = *(const bf16x8*)ap;
  bf16x8 w0 = *(const bf16x8*)wp;

  f32x4 acc[2][2];
  #pragma unroll
  for (int i=0;i<2;i++)
    #pragma unroll
    for (int j=0;j<2;j++) acc[i][j] = f32x4{0.f,0.f,0.f,0.f};

  for (int k0 = 0; k0 < K; k0 += 32){
    __syncthreads();
    *(bf16x8*)&As[srow][skc] = a0;
    *(bf16x8*)&Ws[srow][skc] = w0;
    __syncthreads();
    if (k0 + 32 < K){
      a0 = *(const bf16x8*)(ap+k0+32);
      w0 = *(const bf16x8*)(wp+k0+32);
    }
    bf16x8 af[2], bfr[2];
    af[0]  = *(const bf16x8*)&As[wm      + mr][quad*8];
    af[1]  = *(const bf16x8*)&As[wm + 16 + mr][quad*8];
    bfr[0] = *(const bf16x8*)&Ws[wn      + mr][quad*8];
    bfr[1] = *(const bf16x8*)&Ws[wn + 16 + mr][quad*8];
    #pragma unroll
    for (int i=0;i<2;i++)
      #pragma unroll
      for (int j=0;j<2;j++)
        acc[i][j] = mfma16(af[i], bfr[j], acc[i][j]);
  }

  #pragma unroll
  for (int j=0;j<2;j++){
    int col = bn + wn + j*16 + mr;
    float bb = HASBIAS ? bias[col] : 0.f;
    #pragma unroll
    for (int i=0;i<2;i++)
      #pragma unroll
      for (int reg=0;reg<4;reg++){
        int row = bm + wm + i*16 + quad*4 + reg;
        float vv = acc[i][j][reg] + bb;
        if (HASRESF) vv += residf[(size_t)row*N + col];
        Cb[(size_t)row*N + col] = (__bf16)vv;
      }
  }
}

// ---------------------------------------------------------------------------
// batched q,k,v GEMM: grid (M/64, N/64, 3). z=2 writes transposed Vt.
// ---------------------------------------------------------------------------
__global__ __launch_bounds__(256)
void qkv_gemm(const __bf16* __restrict__ hres, const float* __restrict__ ctx,
              const __bf16* __restrict__ wbf, __bf16* __restrict__ qo,
              __bf16* __restrict__ ko, __bf16* __restrict__ vt)
{
  __shared__ __bf16 As[64][40];
  __shared__ __bf16 Ws[64][40];
  const int tid = threadIdx.x;
  const int bm = blockIdx.x*64, bn = blockIdx.y*64, z = blockIdx.z;
  const int K = DM, N = DM;
  const bool abf = (z == 0);
  const __bf16* W = wbf + ((z == 0) ? W_Q : (z == 1) ? W_K : W_V);
  const int w = tid >> 6, lane = tid & 63;
  const int quad = lane >> 4, mr = lane & 15;
  const int wm = (w >> 1) * 32, wn = (w & 1) * 32;
  const int srow = tid >> 2, skc = (tid & 3) * 8;

  const __bf16* apb = hres + (size_t)(bm + srow)*K + skc;
  const float*  apf = ctx  + (size_t)(bm + srow)*K + skc;
  const __bf16* wp  = W + (size_t)(bn + srow)*K + skc;
  bf16x8 a0;
  if (abf) a0 = *(const bf16x8*)apb;
  else     a0 = pack8(*(const float4*)apf, *(const float4*)(apf+4));
  bf16x8 w0 = *(const bf16x8*)wp;

  f32x4 acc[2][2];
  #pragma unroll
  for (int i=0;i<2;i++)
    #pragma unroll
    for (int j=0;j<2;j++) acc[i][j] = f32x4{0.f,0.f,0.f,0.f};

  for (int k0 = 0; k0 < K; k0 += 32){
    __syncthreads();
    *(bf16x8*)&As[srow][skc] = a0;
    *(bf16x8*)&Ws[srow][skc] = w0;
    __syncthreads();
    if (k0 + 32 < K){
      if (abf) a0 = *(const bf16x8*)(apb+k0+32);
      else     a0 = pack8(*(const float4*)(apf+k0+32), *(const float4*)(apf+k0+36));
      w0 = *(const bf16x8*)(wp+k0+32);
    }
    bf16x8 af[2], bfr[2];
    af[0]  = *(const bf16x8*)&As[wm      + mr][quad*8];
    af[1]  = *(const bf16x8*)&As[wm + 16 + mr][quad*8];
    bfr[0] = *(const bf16x8*)&Ws[wn      + mr][quad*8];
    bfr[1] = *(const bf16x8*)&Ws[wn + 16 + mr][quad*8];
    #pragma unroll
    for (int i=0;i<2;i++)
      #pragma unroll
      for (int j=0;j<2;j++)
        acc[i][j] = mfma16(af[i], bfr[j], acc[i][j]);
  }

  if (z < 2){
    __bf16* C = (z == 0) ? qo : ko;
    #pragma unroll
    for (int j=0;j<2;j++){
      int col = bn + wn + j*16 + mr;
      #pragma unroll
      for (int i=0;i<2;i++)
        #pragma unroll
        for (int reg=0;reg<4;reg++){
          int row = bm + wm + i*16 + quad*4 + reg;
          C[(size_t)row*N + col] = (__bf16)acc[i][j][reg];
        }
    }
  } else {
    #pragma unroll
    for (int j=0;j<2;j++){
      int col = bn + wn + j*16 + mr;
      int h = col >> 5, dl = col & 31;
      #pragma unroll
      for (int i=0;i<2;i++){
        int rowb = bm + wm + i*16 + quad*4;
        int b = rowb >> 11, t = rowb & 2047;
        bf16x4 o;
        #pragma unroll
        for (int reg=0;reg<4;reg++) o[reg] = (__bf16)acc[i][j][reg];
        *(bf16x4*)(vt + ((size_t)(b*NH + h)*32 + dl)*SEQ + t) = o;
      }
    }
  }
}

// ---------------------------------------------------------------------------
// fused causal depthwise conv(4)+SiLU (x4 channels) and dt/log-dA
// ---------------------------------------------------------------------------
__global__ __launch_bounds__(256)
void conv_dt_kernel(const __bf16* __restrict__ zx, const float* __restrict__ convw,
                    const float* __restrict__ convb, const float* __restrict__ dt_bias,
                    const float* __restrict__ A_log, __bf16* __restrict__ xBC,
                    float* __restrict__ dtb, float* __restrict__ ldab)
{
  int idx = blockIdx.x*256 + threadIdx.x;     // over MTOK*CDIM/4
  int c4 = (idx % (CDIM/4))*4;
  int bt = idx / (CDIM/4);
  int b = bt >> 11, t = bt & 2047;
  float acc[4];
  float4 cb = *(const float4*)(convb + c4);
  acc[0]=cb.x; acc[1]=cb.y; acc[2]=cb.z; acc[3]=cb.w;
  float4 wrow[4];
  #pragma unroll
  for (int j=0;j<4;j++) wrow[j] = *(const float4*)(convw + (c4+j)*4);
  #pragma unroll
  for (int k=0;k<4;k++){
    int ts = t - 3 + k;
    if (ts >= 0){
      bf16x4 xv = *(const bf16x4*)(zx + (size_t)(b*SEQ + ts)*DPROJ + DI + c4);
      const float* wk4[4] = {(const float*)&wrow[0], (const float*)&wrow[1],
                             (const float*)&wrow[2], (const float*)&wrow[3]};
      #pragma unroll
      for (int j=0;j<4;j++) acc[j] = fmaf(wk4[j][k], (float)xv[j], acc[j]);
    }
  }
  bf16x4 o;
  #pragma unroll
  for (int j=0;j<4;j++) o[j] = (__bf16)silu_f(acc[j]);
  *(bf16x4*)(xBC + (size_t)bt*CDIM + c4) = o;
  if (c4 < NH){
    #pragma unroll
    for (int j=0;j<4;j++){
      int h = c4 + j;
      float raw = (float)zx[(size_t)bt*DPROJ + 2*DI + 2*DSTATE + h] + dt_bias[h];
      float dt = fmaxf(raw, 0.f) + log1pf(expf(-fabsf(raw)));
      int oo = (b*NH + h)*SEQ + t;
      dtb[oo]  = dt;
      ldab[oo] = -__expf(A_log[h]) * dt;
    }
  }
}

// ---------------------------------------------------------------------------
// SSD chunk_state (bf16 xBC, bf16 Hc out)
// ---------------------------------------------------------------------------
__global__ __launch_bounds__(256)
void chunk_state(const __bf16* __restrict__ xBC, const float* __restrict__ dtb,
                 const float* __restrict__ ldab, __bf16* __restrict__ Hc,
                 float* __restrict__ Ac)
{
  const int blk = blockIdx.x;
  const int ch = blk & 63, bh = blk >> 6;
  const int b = bh >> 3, h = bh & 7;
  const int t0 = ch*CHUNK;
  const int tid = threadIdx.x;
  __shared__ float csS[CHUNK], wendS[CHUNK];
  __shared__ __bf16 Xw[64][40];
  __shared__ __bf16 Bt[128][40];

  if (tid < 32){
    float v  = ldab[bh*SEQ + t0 + tid];
    float dtv = dtb[bh*SEQ + t0 + tid];
    #pragma unroll
    for (int off=1; off<32; off<<=1){
      float o = __shfl_up(v, off, 32);
      if (tid >= off) v += o;
    }
    csS[tid] = v;
    float cs31 = __shfl(v, 31, 32);
    wendS[tid] = __expf(cs31 - v) * dtv;
  }
  __syncthreads();
  {
    int s  = tid >> 3;
    int pg = (tid & 7) * 8;
    bf16x8 xv = *(const bf16x8*)(xBC + (size_t)(b*SEQ + t0 + s)*CDIM + h*HD + pg);
    float wgt = wendS[s];
    #pragma unroll
    for (int e=0;e<8;e++) Xw[pg+e][s] = (__bf16)((float)xv[e] * wgt);
    int ng = (tid & 7) * 16;
    const __bf16* bp = xBC + (size_t)(b*SEQ + t0 + s)*CDIM + DI + ng;
    bf16x8 b0 = *(const bf16x8*)bp;
    bf16x8 b1 = *(const bf16x8*)(bp+8);
    #pragma unroll
    for (int e=0;e<8;e++){ Bt[ng+e][s] = b0[e]; Bt[ng+8+e][s] = b1[e]; }
  }
  if (tid == 0) Ac[blk] = __expf(csS[31]);
  __syncthreads();

  const int w = tid >> 6, lane = tid & 63, quad = lane >> 4, mr = lane & 15;
  bf16x8 af = *(const bf16x8*)&Xw[w*16 + mr][quad*8];
  __bf16* out = Hc + (size_t)blk*8192;
  #pragma unroll
  for (int j=0;j<8;j++){
    bf16x8 bfm = *(const bf16x8*)&Bt[j*16 + mr][quad*8];
    f32x4 a = mfma16(af, bfm, f32x4{0.f,0.f,0.f,0.f});
    #pragma unroll
    for (int reg=0; reg<4; reg++){
      int p = w*16 + quad*4 + reg;
      out[p*128 + j*16 + mr] = (__bf16)a[reg];
    }
  }
}

// ---------------------------------------------------------------------------
// state_prefix: batch loads then serial fma chain
// ---------------------------------------------------------------------------
__global__ __launch_bounds__(256)
void state_prefix(__bf16* __restrict__ Hc, const float* __restrict__ Ac)
{
  const int blk = blockIdx.x;
  const int bh = blk >> 4, sub = blk & 15;
  const int tid = threadIdx.x;
  const int off = sub*512 + tid*2;
  __shared__ float AcS[64];
  if (tid < 64) AcS[tid] = Ac[bh*64 + tid];
  __bf16* base = Hc + (size_t)bh*64*8192 + off;
  bf16x2 v[64];
  #pragma unroll
  for (int c=0;c<64;c++) v[c] = *(const bf16x2*)(base + (size_t)c*8192);
  __syncthreads();
  float r0 = 0.f, r1 = 0.f;
  #pragma unroll
  for (int c=0;c<64;c++){
    bf16x2 o; o[0] = (__bf16)r0; o[1] = (__bf16)r1;
    *(bf16x2*)(base + (size_t)c*8192) = o;
    float a = AcS[c];
    r0 = fmaf(a, r0, (float)v[c][0]);
    r1 = fmaf(a, r1, (float)v[c][1]);
  }
}

// ---------------------------------------------------------------------------
// SSD chunk_out (bf16 xBC/h0, bf16 y out)
// ---------------------------------------------------------------------------
__global__ __launch_bounds__(256)
void chunk_out(const __bf16* __restrict__ xBC, const float* __restrict__ dtb,
               const float* __restrict__ ldab, const __bf16* __restrict__ h0buf,
               const float* __restrict__ Dparam, __bf16* __restrict__ ybuf)
{
  const int blk = blockIdx.x;
  const int ch = blk & 63, bh = blk >> 6;
  const int b = bh >> 3, h = bh & 7;
  const int t0 = ch*CHUNK;
  const int tid = threadIdx.x;
  __shared__ float csS[CHUNK], dtS[CHUNK];
  __shared__ __bf16 Xct[64][40];
  __shared__ __bf16 Ms[32][40];

  if (tid < 32){
    float v = ldab[bh*SEQ + t0 + tid];
    dtS[tid] = dtb[bh*SEQ + t0 + tid];
    #pragma unroll
    for (int off=1; off<32; off<<=1){
      float o = __shfl_up(v, off, 32);
      if (tid >= off) v += o;
    }
    csS[tid] = v;
  }
  __syncthreads();
  {
    int s  = tid >> 3;
    int pg = (tid & 7) * 8;
    bf16x8 xv = *(const bf16x8*)(xBC + (size_t)(b*SEQ + t0 + s)*CDIM + h*HD + pg);
    #pragma unroll
    for (int e=0;e<8;e++) Xct[pg+e][s] = xv[e];
  }

  const int w = tid >> 6, lane = tid & 63, quad = lane >> 4, mr = lane & 15;
  const int ti = w >> 1, si = w & 1;

  const __bf16* Crow = xBC + (size_t)(b*SEQ + t0 + ti*16 + mr)*CDIM + DI + DSTATE;
  bf16x8 af[4];
  #pragma unroll
  for (int kk=0; kk<4; kk++)
    af[kk] = *(const bf16x8*)(Crow + kk*32 + quad*8);
  f32x4 sacc = f32x4{0.f,0.f,0.f,0.f};
  const __bf16* Brow = xBC + (size_t)(b*SEQ + t0 + si*16 + mr)*CDIM + DI;
  #pragma unroll
  for (int kk=0; kk<4; kk++){
    bf16x8 bfm = *(const bf16x8*)(Brow + kk*32 + quad*8);
    sacc = mfma16(af[kk], bfm, sacc);
  }
  #pragma unroll
  for (int reg=0; reg<4; reg++){
    int t = ti*16 + quad*4 + reg;
    int s = si*16 + mr;
    float m = 0.f;
    if (s <= t) m = __expf(csS[t] - csS[s]) * dtS[s] * sacc[reg];
    Ms[t][s] = (__bf16)m;
  }
  __syncthreads();

  f32x4 acc[2] = { f32x4{0.f,0.f,0.f,0.f}, f32x4{0.f,0.f,0.f,0.f} };
  const __bf16* h0r = h0buf + (size_t)blk*8192;
  #pragma unroll
  for (int j=0;j<2;j++){
    int p = (si*2 + j)*16 + mr;
    #pragma unroll
    for (int kk=0; kk<4; kk++){
      bf16x8 bh0 = *(const bf16x8*)(h0r + (size_t)p*128 + kk*32 + quad*8);
      acc[j] = mfma16(af[kk], bh0, acc[j]);
    }
  }
  #pragma unroll
  for (int reg=0;reg<4;reg++){
    int t = ti*16 + quad*4 + reg;
    float e = __expf(csS[t]);
    acc[0][reg] *= e;
    acc[1][reg] *= e;
  }
  bf16x8 am = *(const bf16x8*)&Ms[ti*16 + mr][quad*8];
  #pragma unroll
  for (int j=0;j<2;j++){
    int p = (si*2 + j)*16 + mr;
    bf16x8 bx = *(const bf16x8*)&Xct[p][quad*8];
    acc[j] = mfma16(am, bx, acc[j]);
  }
  const float Dv = Dparam[h];
  #pragma unroll
  for (int j=0;j<2;j++){
    int p = (si*2 + j)*16 + mr;
    #pragma unroll
    for (int reg=0;reg<4;reg++){
      int t = t0 + ti*16 + quad*4 + reg;
      float xv = (float)xBC[(size_t)(b*SEQ + t)*CDIM + h*HD + p];
      ybuf[(size_t)(b*SEQ + t)*DI + h*HD + p] = (__bf16)fmaf(Dv, xv, acc[j][reg]);
    }
  }
}

// ---------------------------------------------------------------------------
// gated RMSNorm (bf16 y in-place, bf16 z)
// ---------------------------------------------------------------------------
__global__ __launch_bounds__(128)
void rmsgate_kernel(__bf16* __restrict__ y, const __bf16* __restrict__ zx,
                    const float* __restrict__ normw)
{
  const int row = blockIdx.x, tid = threadIdx.x;
  const __bf16* zrow = zx + (size_t)row*DPROJ;
  __bf16* yrow = y + (size_t)row*DI;
  bf16x4 yv = *(const bf16x4*)(yrow + tid*4);
  bf16x4 zv = *(const bf16x4*)(zrow + tid*4);
  float g[4];
  float ss = 0.f;
  #pragma unroll
  for (int e=0;e<4;e++){
    g[e] = (float)yv[e] * silu_f((float)zv[e]);
    ss += g[e]*g[e];
  }
  #pragma unroll
  for (int off=1; off<64; off<<=1) ss += __shfl_xor(ss, off);
  __shared__ float red[2];
  if ((tid & 63)==0) red[tid>>6] = ss;
  __syncthreads();
  float tot = red[0] + red[1];
  float rs = rsqrtf(tot * (1.f/DI) + 1e-5f);
  float4 nw = *(const float4*)(normw + tid*4);
  const float* nwp = (const float*)&nw;
  bf16x4 o;
  #pragma unroll
  for (int e=0;e<4;e++) o[e] = (__bf16)(g[e]*rs*nwp[e]);
  *(bf16x4*)(yrow + tid*4) = o;
}

// ---------------------------------------------------------------------------
// Split-KV MFMA flash attention (hd=32), barrier-free K-loop, register
// prefetch of next iteration's K and Vt fragments. NSPLIT=4.
// ---------------------------------------------------------------------------
__global__ __launch_bounds__(256)
void flash_part(const __bf16* __restrict__ qb, const __bf16* __restrict__ kb,
                const __bf16* __restrict__ vt, float* __restrict__ opart,
                float* __restrict__ lpart)
{
  const int qt = blockIdx.x, ksp = blockIdx.y, bh = blockIdx.z;
  const int b = bh >> 3, h = bh & 7;
  const int tid = threadIdx.x;
  const int w = tid >> 6, lane = tid & 63;
  const int quad = lane >> 4, mr = lane & 15;
  const int qrow0 = b*SEQ + qt*128 + w*32;
  const float SC = 0.17677669529663687f;   // 1/sqrt(32)
  __shared__ __bf16 Pq[4][32][72];

  const __bf16* kbase_p = kb + (size_t)(b*SEQ + ksp*KVLEN + mr)*DM + h*32 + quad*8;
  const __bf16* vbase_p = vt + ((size_t)bh*32 + mr)*SEQ + ksp*KVLEN + quad*8;

  bf16x8 bq[2];
  #pragma unroll
  for (int i2=0;i2<2;i2++)
    bq[i2] = *(const bf16x8*)(qb + (size_t)(qrow0 + i2*16 + mr)*DM + h*32 + quad*8);

  f32x4 accO[2][2];
  #pragma unroll
  for (int i=0;i<2;i++)
    #pragma unroll
    for (int j=0;j<2;j++) accO[i][j] = f32x4{0.f,0.f,0.f,0.f};
  float lacc[2] = {0.f, 0.f};

  // preload kt=0 fragments
  bf16x8 akc[4], bvc[2][2];
  #pragma unroll
  for (int ik=0;ik<4;ik++)
    akc[ik] = *(const bf16x8*)(kbase_p + (size_t)ik*16*DM);
  #pragma unroll
  for (int ks=0;ks<2;ks++)
    #pragma unroll
    for (int j2=0;j2<2;j2++)
      bvc[ks][j2] = *(const bf16x8*)(vbase_p + (size_t)j2*16*SEQ + ks*32);

  for (int kt=0; kt<NKT; kt++){
    // prefetch next iteration's K/Vt fragments (in flight during body)
    bf16x8 akn[4], bvn[2][2];
    if (kt + 1 < NKT){
      #pragma unroll
      for (int ik=0;ik<4;ik++)
        akn[ik] = *(const bf16x8*)(kbase_p + (size_t)(kt+1)*64*DM + (size_t)ik*16*DM);
      #pragma unroll
      for (int ks=0;ks<2;ks++)
        #pragma unroll
        for (int j2=0;j2<2;j2++)
          bvn[ks][j2] = *(const bf16x8*)(vbase_p + (size_t)j2*16*SEQ + (kt+1)*64 + ks*32);
    }
    // S^T = K@Q^T ; P = exp(S*sc) -> LDS (b64, 4 consecutive keys)
    #pragma unroll
    for (int ik=0; ik<4; ik++){
      #pragma unroll
      for (int jq=0; jq<2; jq++){
        f32x4 st = mfma16(akc[ik], bq[jq], f32x4{0.f,0.f,0.f,0.f});
        bf16x4 e4;
        #pragma unroll
        for (int reg=0; reg<4; reg++){
          float e = __expf(st[reg] * SC);
          lacc[jq] += e;
          e4[reg] = (__bf16)e;
        }
        *(bf16x4*)&Pq[w][jq*16 + mr][ik*16 + quad*4] = e4;
      }
    }
    // O += P V (P A-frags from LDS, Vt B-frags from prefetched regs)
    #pragma unroll
    for (int ks=0; ks<2; ks++){
      bf16x8 pa0 = *(const bf16x8*)&Pq[w][     mr][ks*32 + quad*8];
      bf16x8 pa1 = *(const bf16x8*)&Pq[w][16 + mr][ks*32 + quad*8];
      #pragma unroll
      for (int j2=0; j2<2; j2++){
        accO[0][j2] = mfma16(pa0, bvc[ks][j2], accO[0][j2]);
        accO[1][j2] = mfma16(pa1, bvc[ks][j2], accO[1][j2]);
      }
    }
    // rotate prefetched registers
    #pragma unroll
    for (int ik=0;ik<4;ik++) akc[ik] = akn[ik];
    #pragma unroll
    for (int ks=0;ks<2;ks++)
      #pragma unroll
      for (int j2=0;j2<2;j2++) bvc[ks][j2] = bvn[ks][j2];
  }

  // deferred l reduction across the quad dimension (keys)
  #pragma unroll
  for (int jq=0;jq<2;jq++){
    float v = lacc[jq];
    v += __shfl_xor(v, 16);
    v += __shfl_xor(v, 32);
    lacc[jq] = v;
  }
  #pragma unroll
  for (int i2=0;i2<2;i2++)
    #pragma unroll
    for (int j2=0;j2<2;j2++)
      #pragma unroll
      for (int reg=0;reg<4;reg++){
        int row = qrow0 + i2*16 + quad*4 + reg;
        opart[((size_t)ksp*MTOK + row)*DM + h*32 + j2*16 + mr] = accO[i2][j2][reg];
      }
  if (quad == 0){
    #pragma unroll
    for (int jq=0;jq<2;jq++)
      lpart[((size_t)ksp*16 + bh)*SEQ + (qt*128 + w*32 + jq*16 + mr)] = lacc[jq];
  }
}

// combine: o = sum_s O_s / sum_s l_s  -> bf16 (streaming)
__global__ __launch_bounds__(256)
void flash_combine(const float* __restrict__ opart, const float* __restrict__ lpart,
                   __bf16* __restrict__ o)
{
  int idx = blockIdx.x*256 + threadIdx.x;   // over MTOK*64
  int row = idx >> 6, d4 = (idx & 63)*4;
  int h = d4 >> 5;
  int b = row >> 11, t = row & 2047;
  float sx=0.f, sy=0.f, sz=0.f, sw=0.f, lsum=0.f;
  #pragma unroll
  for (int s4=0; s4<NSPLIT; s4++){
    float4 vv = *(const float4*)(opart + ((size_t)s4*MTOK + row)*DM + d4);
    sx += vv.x; sy += vv.y; sz += vv.z; sw += vv.w;
    lsum += lpart[((size_t)s4*16 + b*8 + h)*SEQ + t];
  }
  float inv = 1.f / lsum;
  bf16x4 ov;
  ov[0]=(__bf16)(sx*inv); ov[1]=(__bf16)(sy*inv);
  ov[2]=(__bf16)(sz*inv); ov[3]=(__bf16)(sw*inv);
  *(bf16x4*)(o + (size_t)row*DM + d4) = ov;
}

// ---------------------------------------------------------------------------
// fused LayerNorm + pool partial: block = 16 rows; no h1 writeback.
// ---------------------------------------------------------------------------
__global__ __launch_bounds__(256)
void ln_pool(const __bf16* __restrict__ h1, const float* __restrict__ lnw,
             const float* __restrict__ lnb, float* __restrict__ pp)
{
  const int blk = blockIdx.x;
  const int tid = threadIdx.x;
  const int row0 = blk*16;
  __shared__ float s1[4], s2[4];
  float4 wv = *(const float4*)(lnw + tid*4);
  float4 bv = *(const float4*)(lnb + tid*4);
  const float* wp = (const float*)&wv;
  const float* bp = (const float*)&bv;
  float acc[4] = {0.f,0.f,0.f,0.f};
  for (int r=0;r<16;r++){
    bf16x4 v4 = *(const bf16x4*)(h1 + (size_t)(row0+r)*HID + tid*4);
    float v[4];
    float sum=0.f, sq=0.f;
    #pragma unroll
    for (int e=0;e<4;e++){ v[e]=(float)v4[e]; sum+=v[e]; sq+=v[e]*v[e]; }
    #pragma unroll
    for (int off=1; off<64; off<<=1){ sum += __shfl_xor(sum,off); sq += __shfl_xor(sq,off); }
    int w = tid>>6;
    __syncthreads();
    if ((tid & 63)==0){ s1[w]=sum; s2[w]=sq; }
    __syncthreads();
    sum = (s1[0]+s1[1])+(s1[2]+s1[3]);
    sq  = (s2[0]+s2[1])+(s2[2]+s2[3]);
    float mu = sum * (1.f/HID);
    float var = sq * (1.f/HID) - mu*mu;
    float rstd = rsqrtf(var + 1e-5f);
    #pragma unroll
    for (int e=0;e<4;e++) acc[e] += (v[e]-mu)*rstd*wp[e] + bp[e];
  }
  *(float4*)(pp + (size_t)blk*HID + tid*4) = make_float4(acc[0],acc[1],acc[2],acc[3]);
}

// ---------------------------------------------------------------------------
// head: out = ((mean pooled) @ w2^T + b2) @ head_w^T + head_b.  2 blocks.
// ---------------------------------------------------------------------------
__global__ __launch_bounds__(256)
void head2_kernel(const float* __restrict__ pp, const float* __restrict__ w2,
                  const float* __restrict__ b2, const float* __restrict__ hw,
                  const float* __restrict__ hb, float* __restrict__ out)
{
  const int b = blockIdx.x, tid = threadIdx.x;
  __shared__ float pooled[HID];
  __shared__ float w2h[DM];
  {
    int c4 = tid*4;
    float4 s = make_float4(0,0,0,0);
    #pragma unroll 4
    for (int seg=0;seg<128;seg++){
      float4 v = *(const float4*)(pp + ((size_t)(b*128+seg))*HID + c4);
      s.x+=v.x; s.y+=v.y; s.z+=v.z; s.w+=v.w;
    }
    const float inv = 1.f/(float)SEQ;
    *(float4*)&pooled[c4] = make_float4(s.x*inv, s.y*inv, s.z*inv, s.w*inv);
  }
  __syncthreads();
  {
    float acc = 0.f;
    const float* wr = w2 + (size_t)tid*HID;
    #pragma unroll 8
    for (int k=0;k<HID;k+=4){
      float4 wv4 = *(const float4*)(wr+k);
      float4 pv  = *(const float4*)&pooled[k];
      acc += wv4.x*pv.x + wv4.y*pv.y + wv4.z*pv.z + wv4.w*pv.w;
    }
    w2h[tid] = acc + b2[tid];
  }
  __syncthreads();
  if (tid < 128){
    int cls = tid >> 6, lane = tid & 63;
    float acc = 0.f;
    for (int c=lane;c<DM;c+=64) acc += w2h[c]*hw[cls*DM+c];
    #pragma unroll
    for (int off=1;off<64;off<<=1) acc += __shfl_xor(acc, off);
    if (lane == 0) out[b*2 + cls] = acc + hb[cls];
  }
}

// ---------------------------------------------------------------------------
extern "C" void kernel_launch(void* const* d_in, const int* in_sizes, int n_in,
                              void* d_out, int out_size, void* d_ws, size_t ws_size,
                              hipStream_t stream)
{
  const float* x         = (const float*)d_in[0];
  const float* context   = (const float*)d_in[1];
  const float* in_proj_w = (const float*)d_in[2];
  const float* conv_w    = (const float*)d_in[3];
  const float* conv_b    = (const float*)d_in[4];
  const float* dt_bias   = (const float*)d_in[5];
  const float* A_log     = (const float*)d_in[6];
  const float* D_param   = (const float*)d_in[7];
  const float* norm_w    = (const float*)d_in[8];
  const float* out_proj_w= (const float*)d_in[9];
  const float* wq  = (const float*)d_in[10];
  const float* wk  = (const float*)d_in[11];
  const float* wv  = (const float*)d_in[12];
  const float* wo  = (const float*)d_in[13];
  const float* wo_b= (const float*)d_in[14];
  const float* w1  = (const float*)d_in[15];
  const float* b1  = (const float*)d_in[16];
  const float* ln_w= (const float*)d_in[17];
  const float* ln_b= (const float*)d_in[18];
  const float* w2  = (const float*)d_in[19];
  const float* b2  = (const float*)d_in[20];
  const float* head_w = (const float*)d_in[21];
  const float* head_b = (const float*)d_in[22];
  float* out = (float*)d_out;
  float* ws  = (float*)d_ws;

  // workspace layout (float offsets; bf16 regions cast). Aliases noted.
  __bf16* zx    = (__bf16*)ws;                     // 2,637,824 fl
  __bf16* xBC   = (__bf16*)(ws + 2637824);         // 1,572,864
  float* dtb    = ws + 4210688;                    // 32,768
  float* ldab   = ws + 4243456;                    // 32,768
  __bf16* Hcb   = (__bf16*)(ws + 4276224);         // 4,194,304 fl
  float* Acb    = ws + 8470528;                    // 1,024
  __bf16* ybuf  = (__bf16*)(ws + 8471552);         // 1,048,576
  __bf16* hres  = (__bf16*)(ws + 9520128);         // 524,288
  __bf16* qbf   = (__bf16*)(ws + 10044416);        // 524,288
  __bf16* kbf   = (__bf16*)(ws + 10568704);        // 524,288
  __bf16* vtbf  = (__bf16*)(ws + 11092992);        // 524,288
  float* opart  = ws + 11617280;                   // 4,194,304 (NSPLIT=4)
  float* lpart  = ws + 15811584;                   // 131,072
  __bf16* obf   = (__bf16*)(ws + 15942656);        // 524,288
  __bf16* o2bf  = (__bf16*)(ws + 16466944);        // 524,288
  __bf16* wbf   = (__bf16*)(ws + 16991232);        // 492,544 (985088 bf16)
  // h1 (4096x1024 bf16 = 1,048,576 fl) -> Hcb region (dead after chunk_out)
  __bf16* h1bf  = (__bf16*)(ws + 4276224);
  // poolp [256][1024] fp32 = 262,144 fl -> opart region (dead after combine)
  float* poolp  = ws + 11617280;

  const dim3 g64(MTOK/64, DM/64);                  // 256 blocks

  // 0. convert weights to bf16 pool
  cvt_w<<<dim3(W_TOT/1024), dim3(256), 0, stream>>>(
      in_proj_w, out_proj_w, wq, wk, wv, wo, w1, wbf);
  // 1. in_proj (A fp32) -> zx bf16
  gemm128<0,false,true><<<dim3(MTOK/128, (DPROJ+127)/128), dim3(256), 0, stream>>>(
      x, wbf + W_INPROJ, nullptr, zx, MTOK, DPROJ, DM);
  // 2. conv + silu + dt/log-dA (fused, x4 channels)
  conv_dt_kernel<<<dim3(MTOK*CDIM/1024), dim3(256), 0, stream>>>(
      zx, conv_w, conv_b, dt_bias, A_log, xBC, dtb, ldab);
  // 3. SSD scan
  chunk_state<<<dim3(BATCH*NH*NCHUNK), dim3(256), 0, stream>>>(
      xBC, dtb, ldab, Hcb, Acb);
  state_prefix<<<dim3(256), dim3(256), 0, stream>>>(Hcb, Acb);
  chunk_out<<<dim3(BATCH*NH*NCHUNK), dim3(256), 0, stream>>>(
      xBC, dtb, ldab, Hcb, D_param, ybuf);
  // 4. gated rmsnorm (in place, bf16)
  rmsgate_kernel<<<dim3(MTOK), dim3(128), 0, stream>>>(ybuf, zx, norm_w);
  // 5. out_proj + residual x (fp32) -> hres bf16  (K=512)
  gemm64b<false,true><<<g64, dim3(256), 0, stream>>>(
      ybuf, wbf + W_OUTPROJ, nullptr, x, hres, MTOK, DM, DI);
  // 6. q,k,v in one launch; v written transposed
  qkv_gemm<<<dim3(MTOK/64, DM/64, 3), dim3(256), 0, stream>>>(
      hres, context, wbf, qbf, kbf, vtbf);
  // 7. attention partials (NSPLIT=4, prefetched) + streaming combine
  flash_part<<<dim3(SEQ/128, NSPLIT, BATCH*NH), dim3(256), 0, stream>>>(
      qbf, kbf, vtbf, opart, lpart);
  flash_combine<<<dim3(MTOK*64/256), dim3(256), 0, stream>>>(opart, lpart, obf);
  // 8. attention out_proj (+bias) -> o2 bf16  (K=256)
  gemm64b<true,false><<<g64, dim3(256), 0, stream>>>(
      obf, wbf + W_O, wo_b, nullptr, o2bf, MTOK, DM, DM);
  // 9. mlp fc1 + gelu -> h1 bf16 (in Hcb region)
  gemm128<1,true,false><<<dim3(MTOK/128, HID/128), dim3(256), 0, stream>>>(
      o2bf, wbf + W_1, b1, h1bf, MTOK, HID, DM);
  // 10. fused layernorm + pool partials (no h1 writeback)
  ln_pool<<<dim3(256), dim3(256), 0, stream>>>(h1bf, ln_w, ln_b, poolp);
  // 11. head: (pooled @ w2^T + b2) @ head_w^T + head_b
  head2_kernel<<<dim3(BATCH), dim3(256), 0, stream>>>(
      poolp, w2, b2, head_w, head_b, out);
  (void)in_sizes; (void)n_in; (void)out_size; (void)ws_size;
}

// Round 12
// 270.060 us; speedup vs baseline: 1.1870x; 1.1125x over previous
//
#include <hip/hip_runtime.h>
#include <hip/hip_bf16.h>
#include <math.h>

#define DEVFN __device__ __forceinline__

constexpr int BATCH = 2;
constexpr int SEQ   = 2048;
constexpr int DM    = 256;    // d_model
constexpr int DI    = 512;    // d_inner
constexpr int DSTATE= 128;
constexpr int NH    = 8;
constexpr int HD    = 64;     // mamba head dim
constexpr int CDIM  = 768;    // conv dim
constexpr int DPROJ = 1288;
constexpr int MTOK  = BATCH*SEQ;  // 4096
constexpr int HID   = 1024;   // mlp hidden
constexpr int CHUNK = 32;
constexpr int NCHUNK= SEQ/CHUNK;  // 64
constexpr int NSPLIT= 8;          // flash KV splits (occupancy: 8 blocks/CU)
constexpr int KVLEN = SEQ/NSPLIT; // 256
constexpr int NKT   = KVLEN/64;   // 4

// bf16 weight pool offsets (elements)
constexpr int W_INPROJ = 0;              // 1288*256 = 329728
constexpr int W_OUTPROJ= 329728;         // 256*512  = 131072
constexpr int W_Q      = 460800;         // 65536
constexpr int W_K      = 526336;         // 65536
constexpr int W_V      = 591872;         // 65536
constexpr int W_O      = 657408;         // 65536
constexpr int W_1      = 722944;         // 262144
constexpr int W_TOT    = 985088;

typedef __bf16 bf16x8 __attribute__((ext_vector_type(8)));
typedef __bf16 bf16x4 __attribute__((ext_vector_type(4)));
typedef __bf16 bf16x2 __attribute__((ext_vector_type(2)));
typedef float  f32x4  __attribute__((ext_vector_type(4)));

DEVFN float gelu_exact(float x){ return 0.5f*x*(1.f+erff(x*0.70710678118654752f)); }
DEVFN float silu_f(float x){ return x/(1.f+expf(-x)); }

DEVFN bf16x8 pack8(float4 a, float4 b){
  bf16x8 r;
  r[0]=(__bf16)a.x; r[1]=(__bf16)a.y; r[2]=(__bf16)a.z; r[3]=(__bf16)a.w;
  r[4]=(__bf16)b.x; r[5]=(__bf16)b.y; r[6]=(__bf16)b.z; r[7]=(__bf16)b.w;
  return r;
}
DEVFN f32x4 mfma16(bf16x8 a, bf16x8 b, f32x4 c){
  return __builtin_amdgcn_mfma_f32_16x16x32_bf16(a, b, c, 0, 0, 0);
}

// ---------------------------------------------------------------------------
// convert all GEMM weights fp32 -> bf16 pool (one pass)
// ---------------------------------------------------------------------------
__global__ __launch_bounds__(256)
void cvt_w(const float* __restrict__ w_inproj, const float* __restrict__ w_outproj,
           const float* __restrict__ wq, const float* __restrict__ wk,
           const float* __restrict__ wv, const float* __restrict__ wo,
           const float* __restrict__ w1, __bf16* __restrict__ wbf)
{
  int i4 = (blockIdx.x*256 + threadIdx.x)*4;
  const float* src;
  if      (i4 < W_OUTPROJ) src = w_inproj  + i4;
  else if (i4 < W_Q)       src = w_outproj + (i4 - W_OUTPROJ);
  else if (i4 < W_K)       src = wq + (i4 - W_Q);
  else if (i4 < W_V)       src = wk + (i4 - W_K);
  else if (i4 < W_O)       src = wv + (i4 - W_V);
  else if (i4 < W_1)       src = wo + (i4 - W_O);
  else                     src = w1 + (i4 - W_1);
  float4 v = *(const float4*)src;
  bf16x4 o;
  o[0]=(__bf16)v.x; o[1]=(__bf16)v.y; o[2]=(__bf16)v.z; o[3]=(__bf16)v.w;
  *(bf16x4*)(wbf + i4) = o;
}

// ---------------------------------------------------------------------------
// bf16-MFMA GEMM, 128x128 tile, 4 waves, BK=32, register-prefetch pipeline.
// ---------------------------------------------------------------------------
template<int ACT, bool HASBIAS, bool AF32>
__global__ __launch_bounds__(256)
void gemm128(const void* __restrict__ Av, const __bf16* __restrict__ W,
             const float* __restrict__ bias, __bf16* __restrict__ C,
             int M, int N, int K)
{
  __shared__ __bf16 As[128][40];
  __shared__ __bf16 Ws[128][40];
  const int tid = threadIdx.x;
  const int bm = blockIdx.x * 128, bn = blockIdx.y * 128;
  const int wv = tid >> 6, lane = tid & 63;
  const int quad = lane >> 4, mr = lane & 15;
  const int wm = (wv >> 1) * 64, wn = (wv & 1) * 64;
  const int srow = tid >> 2;
  const int skc  = (tid & 3) * 8;

  const float*  af0 = (const float*)Av + (size_t)(bm + srow)*K + skc;
  const float*  af1 = (const float*)Av + (size_t)(bm + srow + 64)*K + skc;
  const __bf16* ab0 = (const __bf16*)Av + (size_t)(bm + srow)*K + skc;
  const __bf16* ab1 = (const __bf16*)Av + (size_t)(bm + srow + 64)*K + skc;
  const bool wok0 = (bn + srow) < N;
  const bool wok1 = (bn + srow + 64) < N;
  const __bf16* wp0 = W + (size_t)(bn + srow)*K + skc;
  const __bf16* wp1 = W + (size_t)(bn + srow + 64)*K + skc;

  bf16x8 zb{};
  bf16x8 A0, A1;
  if (AF32){
    A0 = pack8(*(const float4*)af0, *(const float4*)(af0+4));
    A1 = pack8(*(const float4*)af1, *(const float4*)(af1+4));
  } else {
    A0 = *(const bf16x8*)ab0;
    A1 = *(const bf16x8*)ab1;
  }
  bf16x8 W0 = wok0 ? *(const bf16x8*)wp0 : zb;
  bf16x8 W1 = wok1 ? *(const bf16x8*)wp1 : zb;

  f32x4 acc[4][4];
  #pragma unroll
  for (int i=0;i<4;i++)
    #pragma unroll
    for (int j=0;j<4;j++) acc[i][j] = f32x4{0.f,0.f,0.f,0.f};

  for (int k0 = 0; k0 < K; k0 += 32) {
    __syncthreads();
    *(bf16x8*)&As[srow   ][skc] = A0;
    *(bf16x8*)&As[srow+64][skc] = A1;
    *(bf16x8*)&Ws[srow   ][skc] = W0;
    *(bf16x8*)&Ws[srow+64][skc] = W1;
    __syncthreads();
    if (k0 + 32 < K){
      int kn = k0 + 32;
      if (AF32){
        A0 = pack8(*(const float4*)(af0+kn), *(const float4*)(af0+kn+4));
        A1 = pack8(*(const float4*)(af1+kn), *(const float4*)(af1+kn+4));
      } else {
        A0 = *(const bf16x8*)(ab0+kn);
        A1 = *(const bf16x8*)(ab1+kn);
      }
      W0 = wok0 ? *(const bf16x8*)(wp0+kn) : zb;
      W1 = wok1 ? *(const bf16x8*)(wp1+kn) : zb;
    }
    bf16x8 afr[4], bfr[4];
    #pragma unroll
    for (int i=0;i<4;i++) afr[i] = *(const bf16x8*)&As[wm + i*16 + mr][quad*8];
    #pragma unroll
    for (int j=0;j<4;j++) bfr[j] = *(const bf16x8*)&Ws[wn + j*16 + mr][quad*8];
    #pragma unroll
    for (int i=0;i<4;i++)
      #pragma unroll
      for (int j=0;j<4;j++)
        acc[i][j] = mfma16(afr[i], bfr[j], acc[i][j]);
  }

  #pragma unroll
  for (int j=0;j<4;j++){
    int col = bn + wn + j*16 + mr;
    if (col >= N) continue;
    float bb = HASBIAS ? bias[col] : 0.f;
    #pragma unroll
    for (int i=0;i<4;i++){
      #pragma unroll
      for (int reg=0; reg<4; reg++){
        int row = bm + wm + i*16 + quad*4 + reg;
        float vv = acc[i][j][reg] + bb;
        if (ACT == 1) vv = gelu_exact(vv);
        C[(size_t)row*N + col] = (__bf16)vv;
      }
    }
  }
}

// ---------------------------------------------------------------------------
// 64x64-tile GEMM, A bf16, W bf16, register-prefetch pipelined.
// ---------------------------------------------------------------------------
template<bool HASBIAS, bool HASRESF>
__global__ __launch_bounds__(256)
void gemm64b(const __bf16* __restrict__ A, const __bf16* __restrict__ W,
             const float* __restrict__ bias, const float* __restrict__ residf,
             __bf16* __restrict__ Cb, int M, int N, int K)
{
  __shared__ __bf16 As[64][40];
  __shared__ __bf16 Ws[64][40];
  const int tid = threadIdx.x;
  const int bm = blockIdx.x*64, bn = blockIdx.y*64;
  const int w = tid >> 6, lane = tid & 63;
  const int quad = lane >> 4, mr = lane & 15;
  const int wm = (w >> 1) * 32, wn = (w & 1) * 32;
  const int srow = tid >> 2, skc = (tid & 3) * 8;

  const __bf16* ap = A + (size_t)(bm + srow)*K + skc;
  const __bf16* wp = W + (size_t)(bn + srow)*K + skc;
  bf16x8 a0 = *(const bf16x8*)ap;
  bf16x8 w0 = *(const bf16x8*)wp;

  f32x4 acc[2][2];
  #pragma unroll
  for (int i=0;i<2;i++)
    #pragma unroll
    for (int j=0;j<2;j++) acc[i][j] = f32x4{0.f,0.f,0.f,0.f};

  for (int k0 = 0; k0 < K; k0 += 32){
    __syncthreads();
    *(bf16x8*)&As[srow][skc] = a0;
    *(bf16x8*)&Ws[srow][skc] = w0;
    __syncthreads();
    if (k0 + 32 < K){
      a0 = *(const bf16x8*)(ap+k0+32);
      w0 = *(const bf16x8*)(wp+k0+32);
    }
    bf16x8 af[2], bfr[2];
    af[0]  = *(const bf16x8*)&As[wm      + mr][quad*8];
    af[1]  = *(const bf16x8*)&As[wm + 16 + mr][quad*8];
    bfr[0] = *(const bf16x8*)&Ws[wn      + mr][quad*8];
    bfr[1] = *(const bf16x8*)&Ws[wn + 16 + mr][quad*8];
    #pragma unroll
    for (int i=0;i<2;i++)
      #pragma unroll
      for (int j=0;j<2;j++)
        acc[i][j] = mfma16(af[i], bfr[j], acc[i][j]);
  }

  #pragma unroll
  for (int j=0;j<2;j++){
    int col = bn + wn + j*16 + mr;
    float bb = HASBIAS ? bias[col] : 0.f;
    #pragma unroll
    for (int i=0;i<2;i++)
      #pragma unroll
      for (int reg=0;reg<4;reg++){
        int row = bm + wm + i*16 + quad*4 + reg;
        float vv = acc[i][j][reg] + bb;
        if (HASRESF) vv += residf[(size_t)row*N + col];
        Cb[(size_t)row*N + col] = (__bf16)vv;
      }
  }
}

// ---------------------------------------------------------------------------
// batched q,k,v GEMM: grid (M/64, N/64, 3). z=2 writes transposed Vt.
// ---------------------------------------------------------------------------
__global__ __launch_bounds__(256)
void qkv_gemm(const __bf16* __restrict__ hres, const float* __restrict__ ctx,
              const __bf16* __restrict__ wbf, __bf16* __restrict__ qo,
              __bf16* __restrict__ ko, __bf16* __restrict__ vt)
{
  __shared__ __bf16 As[64][40];
  __shared__ __bf16 Ws[64][40];
  const int tid = threadIdx.x;
  const int bm = blockIdx.x*64, bn = blockIdx.y*64, z = blockIdx.z;
  const int K = DM, N = DM;
  const bool abf = (z == 0);
  const __bf16* W = wbf + ((z == 0) ? W_Q : (z == 1) ? W_K : W_V);
  const int w = tid >> 6, lane = tid & 63;
  const int quad = lane >> 4, mr = lane & 15;
  const int wm = (w >> 1) * 32, wn = (w & 1) * 32;
  const int srow = tid >> 2, skc = (tid & 3) * 8;

  const __bf16* apb = hres + (size_t)(bm + srow)*K + skc;
  const float*  apf = ctx  + (size_t)(bm + srow)*K + skc;
  const __bf16* wp  = W + (size_t)(bn + srow)*K + skc;
  bf16x8 a0;
  if (abf) a0 = *(const bf16x8*)apb;
  else     a0 = pack8(*(const float4*)apf, *(const float4*)(apf+4));
  bf16x8 w0 = *(const bf16x8*)wp;

  f32x4 acc[2][2];
  #pragma unroll
  for (int i=0;i<2;i++)
    #pragma unroll
    for (int j=0;j<2;j++) acc[i][j] = f32x4{0.f,0.f,0.f,0.f};

  for (int k0 = 0; k0 < K; k0 += 32){
    __syncthreads();
    *(bf16x8*)&As[srow][skc] = a0;
    *(bf16x8*)&Ws[srow][skc] = w0;
    __syncthreads();
    if (k0 + 32 < K){
      if (abf) a0 = *(const bf16x8*)(apb+k0+32);
      else     a0 = pack8(*(const float4*)(apf+k0+32), *(const float4*)(apf+k0+36));
      w0 = *(const bf16x8*)(wp+k0+32);
    }
    bf16x8 af[2], bfr[2];
    af[0]  = *(const bf16x8*)&As[wm      + mr][quad*8];
    af[1]  = *(const bf16x8*)&As[wm + 16 + mr][quad*8];
    bfr[0] = *(const bf16x8*)&Ws[wn      + mr][quad*8];
    bfr[1] = *(const bf16x8*)&Ws[wn + 16 + mr][quad*8];
    #pragma unroll
    for (int i=0;i<2;i++)
      #pragma unroll
      for (int j=0;j<2;j++)
        acc[i][j] = mfma16(af[i], bfr[j], acc[i][j]);
  }

  if (z < 2){
    __bf16* C = (z == 0) ? qo : ko;
    #pragma unroll
    for (int j=0;j<2;j++){
      int col = bn + wn + j*16 + mr;
      #pragma unroll
      for (int i=0;i<2;i++)
        #pragma unroll
        for (int reg=0;reg<4;reg++){
          int row = bm + wm + i*16 + quad*4 + reg;
          C[(size_t)row*N + col] = (__bf16)acc[i][j][reg];
        }
    }
  } else {
    #pragma unroll
    for (int j=0;j<2;j++){
      int col = bn + wn + j*16 + mr;
      int h = col >> 5, dl = col & 31;
      #pragma unroll
      for (int i=0;i<2;i++){
        int rowb = bm + wm + i*16 + quad*4;
        int b = rowb >> 11, t = rowb & 2047;
        bf16x4 o;
        #pragma unroll
        for (int reg=0;reg<4;reg++) o[reg] = (__bf16)acc[i][j][reg];
        *(bf16x4*)(vt + ((size_t)(b*NH + h)*32 + dl)*SEQ + t) = o;
      }
    }
  }
}

// ---------------------------------------------------------------------------
// fused causal depthwise conv(4)+SiLU (x4 channels) and dt/log-dA
// ---------------------------------------------------------------------------
__global__ __launch_bounds__(256)
void conv_dt_kernel(const __bf16* __restrict__ zx, const float* __restrict__ convw,
                    const float* __restrict__ convb, const float* __restrict__ dt_bias,
                    const float* __restrict__ A_log, __bf16* __restrict__ xBC,
                    float* __restrict__ dtb, float* __restrict__ ldab)
{
  int idx = blockIdx.x*256 + threadIdx.x;     // over MTOK*CDIM/4
  int c4 = (idx % (CDIM/4))*4;
  int bt = idx / (CDIM/4);
  int b = bt >> 11, t = bt & 2047;
  float acc[4];
  float4 cb = *(const float4*)(convb + c4);
  acc[0]=cb.x; acc[1]=cb.y; acc[2]=cb.z; acc[3]=cb.w;
  float4 wrow[4];
  #pragma unroll
  for (int j=0;j<4;j++) wrow[j] = *(const float4*)(convw + (c4+j)*4);
  #pragma unroll
  for (int k=0;k<4;k++){
    int ts = t - 3 + k;
    if (ts >= 0){
      bf16x4 xv = *(const bf16x4*)(zx + (size_t)(b*SEQ + ts)*DPROJ + DI + c4);
      const float* wk4[4] = {(const float*)&wrow[0], (const float*)&wrow[1],
                             (const float*)&wrow[2], (const float*)&wrow[3]};
      #pragma unroll
      for (int j=0;j<4;j++) acc[j] = fmaf(wk4[j][k], (float)xv[j], acc[j]);
    }
  }
  bf16x4 o;
  #pragma unroll
  for (int j=0;j<4;j++) o[j] = (__bf16)silu_f(acc[j]);
  *(bf16x4*)(xBC + (size_t)bt*CDIM + c4) = o;
  if (c4 < NH){
    #pragma unroll
    for (int j=0;j<4;j++){
      int h = c4 + j;
      float raw = (float)zx[(size_t)bt*DPROJ + 2*DI + 2*DSTATE + h] + dt_bias[h];
      float dt = fmaxf(raw, 0.f) + log1pf(expf(-fabsf(raw)));
      int oo = (b*NH + h)*SEQ + t;
      dtb[oo]  = dt;
      ldab[oo] = -__expf(A_log[h]) * dt;
    }
  }
}

// ---------------------------------------------------------------------------
// SSD chunk_state (bf16 xBC, bf16 Hc out)
// ---------------------------------------------------------------------------
__global__ __launch_bounds__(256)
void chunk_state(const __bf16* __restrict__ xBC, const float* __restrict__ dtb,
                 const float* __restrict__ ldab, __bf16* __restrict__ Hc,
                 float* __restrict__ Ac)
{
  const int blk = blockIdx.x;
  const int ch = blk & 63, bh = blk >> 6;
  const int b = bh >> 3, h = bh & 7;
  const int t0 = ch*CHUNK;
  const int tid = threadIdx.x;
  __shared__ float csS[CHUNK], wendS[CHUNK];
  __shared__ __bf16 Xw[64][40];
  __shared__ __bf16 Bt[128][40];

  if (tid < 32){
    float v  = ldab[bh*SEQ + t0 + tid];
    float dtv = dtb[bh*SEQ + t0 + tid];
    #pragma unroll
    for (int off=1; off<32; off<<=1){
      float o = __shfl_up(v, off, 32);
      if (tid >= off) v += o;
    }
    csS[tid] = v;
    float cs31 = __shfl(v, 31, 32);
    wendS[tid] = __expf(cs31 - v) * dtv;
  }
  __syncthreads();
  {
    int s  = tid >> 3;
    int pg = (tid & 7) * 8;
    bf16x8 xv = *(const bf16x8*)(xBC + (size_t)(b*SEQ + t0 + s)*CDIM + h*HD + pg);
    float wgt = wendS[s];
    #pragma unroll
    for (int e=0;e<8;e++) Xw[pg+e][s] = (__bf16)((float)xv[e] * wgt);
    int ng = (tid & 7) * 16;
    const __bf16* bp = xBC + (size_t)(b*SEQ + t0 + s)*CDIM + DI + ng;
    bf16x8 b0 = *(const bf16x8*)bp;
    bf16x8 b1 = *(const bf16x8*)(bp+8);
    #pragma unroll
    for (int e=0;e<8;e++){ Bt[ng+e][s] = b0[e]; Bt[ng+8+e][s] = b1[e]; }
  }
  if (tid == 0) Ac[blk] = __expf(csS[31]);
  __syncthreads();

  const int w = tid >> 6, lane = tid & 63, quad = lane >> 4, mr = lane & 15;
  bf16x8 af = *(const bf16x8*)&Xw[w*16 + mr][quad*8];
  __bf16* out = Hc + (size_t)blk*8192;
  #pragma unroll
  for (int j=0;j<8;j++){
    bf16x8 bfm = *(const bf16x8*)&Bt[j*16 + mr][quad*8];
    f32x4 a = mfma16(af, bfm, f32x4{0.f,0.f,0.f,0.f});
    #pragma unroll
    for (int reg=0; reg<4; reg++){
      int p = w*16 + quad*4 + reg;
      out[p*128 + j*16 + mr] = (__bf16)a[reg];
    }
  }
}

// ---------------------------------------------------------------------------
// state_prefix: batch loads then serial fma chain
// ---------------------------------------------------------------------------
__global__ __launch_bounds__(256)
void state_prefix(__bf16* __restrict__ Hc, const float* __restrict__ Ac)
{
  const int blk = blockIdx.x;
  const int bh = blk >> 4, sub = blk & 15;
  const int tid = threadIdx.x;
  const int off = sub*512 + tid*2;
  __shared__ float AcS[64];
  if (tid < 64) AcS[tid] = Ac[bh*64 + tid];
  __bf16* base = Hc + (size_t)bh*64*8192 + off;
  bf16x2 v[64];
  #pragma unroll
  for (int c=0;c<64;c++) v[c] = *(const bf16x2*)(base + (size_t)c*8192);
  __syncthreads();
  float r0 = 0.f, r1 = 0.f;
  #pragma unroll
  for (int c=0;c<64;c++){
    bf16x2 o; o[0] = (__bf16)r0; o[1] = (__bf16)r1;
    *(bf16x2*)(base + (size_t)c*8192) = o;
    float a = AcS[c];
    r0 = fmaf(a, r0, (float)v[c][0]);
    r1 = fmaf(a, r1, (float)v[c][1]);
  }
}

// ---------------------------------------------------------------------------
// SSD chunk_out (bf16 xBC/h0, bf16 y out)
// ---------------------------------------------------------------------------
__global__ __launch_bounds__(256)
void chunk_out(const __bf16* __restrict__ xBC, const float* __restrict__ dtb,
               const float* __restrict__ ldab, const __bf16* __restrict__ h0buf,
               const float* __restrict__ Dparam, __bf16* __restrict__ ybuf)
{
  const int blk = blockIdx.x;
  const int ch = blk & 63, bh = blk >> 6;
  const int b = bh >> 3, h = bh & 7;
  const int t0 = ch*CHUNK;
  const int tid = threadIdx.x;
  __shared__ float csS[CHUNK], dtS[CHUNK];
  __shared__ __bf16 Xct[64][40];
  __shared__ __bf16 Ms[32][40];

  if (tid < 32){
    float v = ldab[bh*SEQ + t0 + tid];
    dtS[tid] = dtb[bh*SEQ + t0 + tid];
    #pragma unroll
    for (int off=1; off<32; off<<=1){
      float o = __shfl_up(v, off, 32);
      if (tid >= off) v += o;
    }
    csS[tid] = v;
  }
  __syncthreads();
  {
    int s  = tid >> 3;
    int pg = (tid & 7) * 8;
    bf16x8 xv = *(const bf16x8*)(xBC + (size_t)(b*SEQ + t0 + s)*CDIM + h*HD + pg);
    #pragma unroll
    for (int e=0;e<8;e++) Xct[pg+e][s] = xv[e];
  }

  const int w = tid >> 6, lane = tid & 63, quad = lane >> 4, mr = lane & 15;
  const int ti = w >> 1, si = w & 1;

  const __bf16* Crow = xBC + (size_t)(b*SEQ + t0 + ti*16 + mr)*CDIM + DI + DSTATE;
  bf16x8 af[4];
  #pragma unroll
  for (int kk=0; kk<4; kk++)
    af[kk] = *(const bf16x8*)(Crow + kk*32 + quad*8);
  f32x4 sacc = f32x4{0.f,0.f,0.f,0.f};
  const __bf16* Brow = xBC + (size_t)(b*SEQ + t0 + si*16 + mr)*CDIM + DI;
  #pragma unroll
  for (int kk=0; kk<4; kk++){
    bf16x8 bfm = *(const bf16x8*)(Brow + kk*32 + quad*8);
    sacc = mfma16(af[kk], bfm, sacc);
  }
  #pragma unroll
  for (int reg=0; reg<4; reg++){
    int t = ti*16 + quad*4 + reg;
    int s = si*16 + mr;
    float m = 0.f;
    if (s <= t) m = __expf(csS[t] - csS[s]) * dtS[s] * sacc[reg];
    Ms[t][s] = (__bf16)m;
  }
  __syncthreads();

  f32x4 acc[2] = { f32x4{0.f,0.f,0.f,0.f}, f32x4{0.f,0.f,0.f,0.f} };
  const __bf16* h0r = h0buf + (size_t)blk*8192;
  #pragma unroll
  for (int j=0;j<2;j++){
    int p = (si*2 + j)*16 + mr;
    #pragma unroll
    for (int kk=0; kk<4; kk++){
      bf16x8 bh0 = *(const bf16x8*)(h0r + (size_t)p*128 + kk*32 + quad*8);
      acc[j] = mfma16(af[kk], bh0, acc[j]);
    }
  }
  #pragma unroll
  for (int reg=0;reg<4;reg++){
    int t = ti*16 + quad*4 + reg;
    float e = __expf(csS[t]);
    acc[0][reg] *= e;
    acc[1][reg] *= e;
  }
  bf16x8 am = *(const bf16x8*)&Ms[ti*16 + mr][quad*8];
  #pragma unroll
  for (int j=0;j<2;j++){
    int p = (si*2 + j)*16 + mr;
    bf16x8 bx = *(const bf16x8*)&Xct[p][quad*8];
    acc[j] = mfma16(am, bx, acc[j]);
  }
  const float Dv = Dparam[h];
  #pragma unroll
  for (int j=0;j<2;j++){
    int p = (si*2 + j)*16 + mr;
    #pragma unroll
    for (int reg=0;reg<4;reg++){
      int t = t0 + ti*16 + quad*4 + reg;
      float xv = (float)xBC[(size_t)(b*SEQ + t)*CDIM + h*HD + p];
      ybuf[(size_t)(b*SEQ + t)*DI + h*HD + p] = (__bf16)fmaf(Dv, xv, acc[j][reg]);
    }
  }
}

// ---------------------------------------------------------------------------
// gated RMSNorm (bf16 y in-place, bf16 z)
// ---------------------------------------------------------------------------
__global__ __launch_bounds__(128)
void rmsgate_kernel(__bf16* __restrict__ y, const __bf16* __restrict__ zx,
                    const float* __restrict__ normw)
{
  const int row = blockIdx.x, tid = threadIdx.x;
  const __bf16* zrow = zx + (size_t)row*DPROJ;
  __bf16* yrow = y + (size_t)row*DI;
  bf16x4 yv = *(const bf16x4*)(yrow + tid*4);
  bf16x4 zv = *(const bf16x4*)(zrow + tid*4);
  float g[4];
  float ss = 0.f;
  #pragma unroll
  for (int e=0;e<4;e++){
    g[e] = (float)yv[e] * silu_f((float)zv[e]);
    ss += g[e]*g[e];
  }
  #pragma unroll
  for (int off=1; off<64; off<<=1) ss += __shfl_xor(ss, off);
  __shared__ float red[2];
  if ((tid & 63)==0) red[tid>>6] = ss;
  __syncthreads();
  float tot = red[0] + red[1];
  float rs = rsqrtf(tot * (1.f/DI) + 1e-5f);
  float4 nw = *(const float4*)(normw + tid*4);
  const float* nwp = (const float*)&nw;
  bf16x4 o;
  #pragma unroll
  for (int e=0;e<4;e++) o[e] = (__bf16)(g[e]*rs*nwp[e]);
  *(bf16x4*)(yrow + tid*4) = o;
}

// ---------------------------------------------------------------------------
// Split-KV MFMA flash attention (hd=32), barrier-free K-loop, register
// prefetch. NSPLIT=8 -> 2048 blocks = 8 blocks/CU.
// ---------------------------------------------------------------------------
__global__ __launch_bounds__(256)
void flash_part(const __bf16* __restrict__ qb, const __bf16* __restrict__ kb,
                const __bf16* __restrict__ vt, float* __restrict__ opart,
                float* __restrict__ lpart)
{
  const int qt = blockIdx.x, ksp = blockIdx.y, bh = blockIdx.z;
  const int b = bh >> 3, h = bh & 7;
  const int tid = threadIdx.x;
  const int w = tid >> 6, lane = tid & 63;
  const int quad = lane >> 4, mr = lane & 15;
  const int qrow0 = b*SEQ + qt*128 + w*32;
  const float SC = 0.17677669529663687f;   // 1/sqrt(32)
  __shared__ __bf16 Pq[4][32][72];

  const __bf16* kbase_p = kb + (size_t)(b*SEQ + ksp*KVLEN + mr)*DM + h*32 + quad*8;
  const __bf16* vbase_p = vt + ((size_t)bh*32 + mr)*SEQ + ksp*KVLEN + quad*8;

  bf16x8 bq[2];
  #pragma unroll
  for (int i2=0;i2<2;i2++)
    bq[i2] = *(const bf16x8*)(qb + (size_t)(qrow0 + i2*16 + mr)*DM + h*32 + quad*8);

  f32x4 accO[2][2];
  #pragma unroll
  for (int i=0;i<2;i++)
    #pragma unroll
    for (int j=0;j<2;j++) accO[i][j] = f32x4{0.f,0.f,0.f,0.f};
  float lacc[2] = {0.f, 0.f};

  bf16x8 akc[4], bvc[2][2];
  #pragma unroll
  for (int ik=0;ik<4;ik++)
    akc[ik] = *(const bf16x8*)(kbase_p + (size_t)ik*16*DM);
  #pragma unroll
  for (int ks=0;ks<2;ks++)
    #pragma unroll
    for (int j2=0;j2<2;j2++)
      bvc[ks][j2] = *(const bf16x8*)(vbase_p + (size_t)j2*16*SEQ + ks*32);

  for (int kt=0; kt<NKT; kt++){
    bf16x8 akn[4], bvn[2][2];
    if (kt + 1 < NKT){
      #pragma unroll
      for (int ik=0;ik<4;ik++)
        akn[ik] = *(const bf16x8*)(kbase_p + (size_t)(kt+1)*64*DM + (size_t)ik*16*DM);
      #pragma unroll
      for (int ks=0;ks<2;ks++)
        #pragma unroll
        for (int j2=0;j2<2;j2++)
          bvn[ks][j2] = *(const bf16x8*)(vbase_p + (size_t)j2*16*SEQ + (kt+1)*64 + ks*32);
    }
    #pragma unroll
    for (int ik=0; ik<4; ik++){
      #pragma unroll
      for (int jq=0; jq<2; jq++){
        f32x4 st = mfma16(akc[ik], bq[jq], f32x4{0.f,0.f,0.f,0.f});
        bf16x4 e4;
        #pragma unroll
        for (int reg=0; reg<4; reg++){
          float e = __expf(st[reg] * SC);
          lacc[jq] += e;
          e4[reg] = (__bf16)e;
        }
        *(bf16x4*)&Pq[w][jq*16 + mr][ik*16 + quad*4] = e4;
      }
    }
    #pragma unroll
    for (int ks=0; ks<2; ks++){
      bf16x8 pa0 = *(const bf16x8*)&Pq[w][     mr][ks*32 + quad*8];
      bf16x8 pa1 = *(const bf16x8*)&Pq[w][16 + mr][ks*32 + quad*8];
      #pragma unroll
      for (int j2=0; j2<2; j2++){
        accO[0][j2] = mfma16(pa0, bvc[ks][j2], accO[0][j2]);
        accO[1][j2] = mfma16(pa1, bvc[ks][j2], accO[1][j2]);
      }
    }
    #pragma unroll
    for (int ik=0;ik<4;ik++) akc[ik] = akn[ik];
    #pragma unroll
    for (int ks=0;ks<2;ks++)
      #pragma unroll
      for (int j2=0;j2<2;j2++) bvc[ks][j2] = bvn[ks][j2];
  }

  #pragma unroll
  for (int jq=0;jq<2;jq++){
    float v = lacc[jq];
    v += __shfl_xor(v, 16);
    v += __shfl_xor(v, 32);
    lacc[jq] = v;
  }
  #pragma unroll
  for (int i2=0;i2<2;i2++)
    #pragma unroll
    for (int j2=0;j2<2;j2++)
      #pragma unroll
      for (int reg=0;reg<4;reg++){
        int row = qrow0 + i2*16 + quad*4 + reg;
        opart[((size_t)ksp*MTOK + row)*DM + h*32 + j2*16 + mr] = accO[i2][j2][reg];
      }
  if (quad == 0){
    #pragma unroll
    for (int jq=0;jq<2;jq++)
      lpart[((size_t)ksp*16 + bh)*SEQ + (qt*128 + w*32 + jq*16 + mr)] = lacc[jq];
  }
}

// combine: o = sum_s O_s / sum_s l_s  -> bf16 (streaming)
__global__ __launch_bounds__(256)
void flash_combine(const float* __restrict__ opart, const float* __restrict__ lpart,
                   __bf16* __restrict__ o)
{
  int idx = blockIdx.x*256 + threadIdx.x;   // over MTOK*64
  int row = idx >> 6, d4 = (idx & 63)*4;
  int h = d4 >> 5;
  int b = row >> 11, t = row & 2047;
  float sx=0.f, sy=0.f, sz=0.f, sw=0.f, lsum=0.f;
  #pragma unroll
  for (int s4=0; s4<NSPLIT; s4++){
    float4 vv = *(const float4*)(opart + ((size_t)s4*MTOK + row)*DM + d4);
    sx += vv.x; sy += vv.y; sz += vv.z; sw += vv.w;
    lsum += lpart[((size_t)s4*16 + b*8 + h)*SEQ + t];
  }
  float inv = 1.f / lsum;
  bf16x4 ov;
  ov[0]=(__bf16)(sx*inv); ov[1]=(__bf16)(sy*inv);
  ov[2]=(__bf16)(sz*inv); ov[3]=(__bf16)(sw*inv);
  *(bf16x4*)(o + (size_t)row*DM + d4) = ov;
}

// ---------------------------------------------------------------------------
// fused LayerNorm + pool partial: block = 16 rows; no h1 writeback.
// ---------------------------------------------------------------------------
__global__ __launch_bounds__(256)
void ln_pool(const __bf16* __restrict__ h1, const float* __restrict__ lnw,
             const float* __restrict__ lnb, float* __restrict__ pp)
{
  const int blk = blockIdx.x;
  const int tid = threadIdx.x;
  const int row0 = blk*16;
  __shared__ float s1[4], s2[4];
  float4 wv = *(const float4*)(lnw + tid*4);
  float4 bv = *(const float4*)(lnb + tid*4);
  const float* wp = (const float*)&wv;
  const float* bp = (const float*)&bv;
  float acc[4] = {0.f,0.f,0.f,0.f};
  for (int r=0;r<16;r++){
    bf16x4 v4 = *(const bf16x4*)(h1 + (size_t)(row0+r)*HID + tid*4);
    float v[4];
    float sum=0.f, sq=0.f;
    #pragma unroll
    for (int e=0;e<4;e++){ v[e]=(float)v4[e]; sum+=v[e]; sq+=v[e]*v[e]; }
    #pragma unroll
    for (int off=1; off<64; off<<=1){ sum += __shfl_xor(sum,off); sq += __shfl_xor(sq,off); }
    int w = tid>>6;
    __syncthreads();
    if ((tid & 63)==0){ s1[w]=sum; s2[w]=sq; }
    __syncthreads();
    sum = (s1[0]+s1[1])+(s1[2]+s1[3]);
    sq  = (s2[0]+s2[1])+(s2[2]+s2[3]);
    float mu = sum * (1.f/HID);
    float var = sq * (1.f/HID) - mu*mu;
    float rstd = rsqrtf(var + 1e-5f);
    #pragma unroll
    for (int e=0;e<4;e++) acc[e] += (v[e]-mu)*rstd*wp[e] + bp[e];
  }
  *(float4*)(pp + (size_t)blk*HID + tid*4) = make_float4(acc[0],acc[1],acc[2],acc[3]);
}

// ---------------------------------------------------------------------------
// head tail, parallelized: reduce_pool (16 blk) -> fc2head (64 blk) -> final
// ---------------------------------------------------------------------------
__global__ __launch_bounds__(128)
void reduce_pool(const float* __restrict__ pp, float* __restrict__ pooled)
{
  const int b = blockIdx.y, cg = blockIdx.x;       // grid (8, 2)
  const int c = cg*128 + threadIdx.x;
  float s = 0.f;
  #pragma unroll 8
  for (int seg=0; seg<128; seg++)
    s += pp[((size_t)(b*128+seg))*HID + c];
  pooled[b*HID + c] = s * (1.f/(float)SEQ);
}

__global__ __launch_bounds__(256)
void fc2head(const float* __restrict__ pooled, const float* __restrict__ w2,
             const float* __restrict__ b2, float* __restrict__ w2h)
{
  const int b = blockIdx.y, og = blockIdx.x;       // grid (32, 2)
  const int tid = threadIdx.x;
  const int r = tid >> 5, l32 = tid & 31;          // 8 rows x 32 lanes
  const int col = og*8 + r;
  const float* wr = w2 + (size_t)col*HID + l32*32;
  const float* pv = pooled + b*HID + l32*32;
  float acc = 0.f;
  #pragma unroll
  for (int k=0;k<32;k+=4){
    float4 wv4 = *(const float4*)(wr+k);
    float4 p4  = *(const float4*)(pv+k);
    acc += wv4.x*p4.x + wv4.y*p4.y + wv4.z*p4.z + wv4.w*p4.w;
  }
  #pragma unroll
  for (int off=1; off<32; off<<=1) acc += __shfl_xor(acc, off);
  if (l32 == 0) w2h[b*DM + col] = acc + b2[col];
}

__global__ __launch_bounds__(128)
void head_final(const float* __restrict__ w2h, const float* __restrict__ hw,
                const float* __restrict__ hb, float* __restrict__ out)
{
  const int b = blockIdx.x, tid = threadIdx.x;
  int cls = tid >> 6, lane = tid & 63;
  float acc = 0.f;
  for (int c=lane;c<DM;c+=64) acc += w2h[b*DM + c]*hw[cls*DM+c];
  #pragma unroll
  for (int off=1;off<64;off<<=1) acc += __shfl_xor(acc, off);
  if (lane == 0) out[b*2 + cls] = acc + hb[cls];
}

// ---------------------------------------------------------------------------
extern "C" void kernel_launch(void* const* d_in, const int* in_sizes, int n_in,
                              void* d_out, int out_size, void* d_ws, size_t ws_size,
                              hipStream_t stream)
{
  const float* x         = (const float*)d_in[0];
  const float* context   = (const float*)d_in[1];
  const float* in_proj_w = (const float*)d_in[2];
  const float* conv_w    = (const float*)d_in[3];
  const float* conv_b    = (const float*)d_in[4];
  const float* dt_bias   = (const float*)d_in[5];
  const float* A_log     = (const float*)d_in[6];
  const float* D_param   = (const float*)d_in[7];
  const float* norm_w    = (const float*)d_in[8];
  const float* out_proj_w= (const float*)d_in[9];
  const float* wq  = (const float*)d_in[10];
  const float* wk  = (const float*)d_in[11];
  const float* wv  = (const float*)d_in[12];
  const float* wo  = (const float*)d_in[13];
  const float* wo_b= (const float*)d_in[14];
  const float* w1  = (const float*)d_in[15];
  const float* b1  = (const float*)d_in[16];
  const float* ln_w= (const float*)d_in[17];
  const float* ln_b= (const float*)d_in[18];
  const float* w2  = (const float*)d_in[19];
  const float* b2  = (const float*)d_in[20];
  const float* head_w = (const float*)d_in[21];
  const float* head_b = (const float*)d_in[22];
  float* out = (float*)d_out;
  float* ws  = (float*)d_ws;

  // workspace layout (float offsets; bf16 regions cast). Aliases noted.
  __bf16* zx    = (__bf16*)ws;                     // 2,637,824 fl
  __bf16* xBC   = (__bf16*)(ws + 2637824);         // 1,572,864
  float* dtb    = ws + 4210688;                    // 32,768
  float* ldab   = ws + 4243456;                    // 32,768
  __bf16* Hcb   = (__bf16*)(ws + 4276224);         // 4,194,304 fl
  float* Acb    = ws + 8470528;                    // 1,024
  __bf16* ybuf  = (__bf16*)(ws + 8471552);         // 1,048,576
  __bf16* hres  = (__bf16*)(ws + 9520128);         // 524,288
  __bf16* qbf   = (__bf16*)(ws + 10044416);        // 524,288
  __bf16* kbf   = (__bf16*)(ws + 10568704);        // 524,288
  __bf16* vtbf  = (__bf16*)(ws + 11092992);        // 524,288
  float* opart  = ws + 11617280;                   // 8,388,608 (NSPLIT=8)
  float* lpart  = ws + 20005888;                   // 262,144
  __bf16* obf   = (__bf16*)(ws + 20268032);        // 524,288
  __bf16* o2bf  = (__bf16*)(ws + 20792320);        // 524,288
  __bf16* wbf   = (__bf16*)(ws + 21316608);        // 492,544
  float* pooled = ws + 21809152;                   // 2,048
  float* w2h    = ws + 21811200;                   // 512
  // h1 (4096x1024 bf16 = 1,048,576 fl) -> Hcb region (dead after chunk_out)
  __bf16* h1bf  = (__bf16*)(ws + 4276224);
  // poolp [256][1024] fp32 = 262,144 fl -> opart region (dead after combine)
  float* poolp  = ws + 11617280;

  const dim3 g64(MTOK/64, DM/64);                  // 256 blocks

  // 0. convert weights to bf16 pool
  cvt_w<<<dim3(W_TOT/1024), dim3(256), 0, stream>>>(
      in_proj_w, out_proj_w, wq, wk, wv, wo, w1, wbf);
  // 1. in_proj (A fp32) -> zx bf16
  gemm128<0,false,true><<<dim3(MTOK/128, (DPROJ+127)/128), dim3(256), 0, stream>>>(
      x, wbf + W_INPROJ, nullptr, zx, MTOK, DPROJ, DM);
  // 2. conv + silu + dt/log-dA (fused, x4 channels)
  conv_dt_kernel<<<dim3(MTOK*CDIM/1024), dim3(256), 0, stream>>>(
      zx, conv_w, conv_b, dt_bias, A_log, xBC, dtb, ldab);
  // 3. SSD scan
  chunk_state<<<dim3(BATCH*NH*NCHUNK), dim3(256), 0, stream>>>(
      xBC, dtb, ldab, Hcb, Acb);
  state_prefix<<<dim3(256), dim3(256), 0, stream>>>(Hcb, Acb);
  chunk_out<<<dim3(BATCH*NH*NCHUNK), dim3(256), 0, stream>>>(
      xBC, dtb, ldab, Hcb, D_param, ybuf);
  // 4. gated rmsnorm (in place, bf16)
  rmsgate_kernel<<<dim3(MTOK), dim3(128), 0, stream>>>(ybuf, zx, norm_w);
  // 5. out_proj + residual x (fp32) -> hres bf16  (K=512)
  gemm64b<false,true><<<g64, dim3(256), 0, stream>>>(
      ybuf, wbf + W_OUTPROJ, nullptr, x, hres, MTOK, DM, DI);
  // 6. q,k,v in one launch; v written transposed
  qkv_gemm<<<dim3(MTOK/64, DM/64, 3), dim3(256), 0, stream>>>(
      hres, context, wbf, qbf, kbf, vtbf);
  // 7. attention partials (NSPLIT=8) + streaming combine
  flash_part<<<dim3(SEQ/128, NSPLIT, BATCH*NH), dim3(256), 0, stream>>>(
      qbf, kbf, vtbf, opart, lpart);
  flash_combine<<<dim3(MTOK*64/256), dim3(256), 0, stream>>>(opart, lpart, obf);
  // 8. attention out_proj (+bias) -> o2 bf16  (K=256)
  gemm64b<true,false><<<g64, dim3(256), 0, stream>>>(
      obf, wbf + W_O, wo_b, nullptr, o2bf, MTOK, DM, DM);
  // 9. mlp fc1 + gelu -> h1 bf16 (in Hcb region)
  gemm128<1,true,false><<<dim3(MTOK/128, HID/128), dim3(256), 0, stream>>>(
      o2bf, wbf + W_1, b1, h1bf, MTOK, HID, DM);
  // 10. fused layernorm + pool partials (no h1 writeback)
  ln_pool<<<dim3(256), dim3(256), 0, stream>>>(h1bf, ln_w, ln_b, poolp);
  // 11. head tail, parallelized
  reduce_pool<<<dim3(8, BATCH), dim3(128), 0, stream>>>(poolp, pooled);
  fc2head<<<dim3(32, BATCH), dim3(256), 0, stream>>>(pooled, w2, b2, w2h);
  head_final<<<dim3(BATCH), dim3(128), 0, stream>>>(w2h, head_w, head_b, out);
  (void)in_sizes; (void)n_in; (void)out_size; (void)ws_size;
}

// Round 13
// 261.090 us; speedup vs baseline: 1.2278x; 1.0344x over previous
//
#include <hip/hip_runtime.h>
#include <hip/hip_bf16.h>
#include <math.h>

#define DEVFN __device__ __forceinline__

constexpr int BATCH = 2;
constexpr int SEQ   = 2048;
constexpr int DM    = 256;    // d_model
constexpr int DI    = 512;    // d_inner
constexpr int DSTATE= 128;
constexpr int NH    = 8;
constexpr int HD    = 64;     // mamba head dim
constexpr int CDIM  = 768;    // conv dim
constexpr int DPROJ = 1288;
constexpr int MTOK  = BATCH*SEQ;  // 4096
constexpr int HID   = 1024;   // mlp hidden
constexpr int CHUNK = 32;
constexpr int NCHUNK= SEQ/CHUNK;  // 64
constexpr int NSPLIT= 8;          // flash KV splits (8 blocks/CU)
constexpr int KVLEN = SEQ/NSPLIT; // 256
constexpr int NKT   = KVLEN/64;   // 4

// bf16 weight pool offsets (elements)
constexpr int W_INPROJ = 0;              // 1288*256 = 329728
constexpr int W_OUTPROJ= 329728;         // 256*512  = 131072
constexpr int W_Q      = 460800;         // 65536
constexpr int W_K      = 526336;         // 65536
constexpr int W_V      = 591872;         // 65536
constexpr int W_O      = 657408;         // 65536
constexpr int W_1      = 722944;         // 262144
constexpr int W_TOT    = 985088;

typedef __bf16 bf16x8 __attribute__((ext_vector_type(8)));
typedef __bf16 bf16x4 __attribute__((ext_vector_type(4)));
typedef __bf16 bf16x2 __attribute__((ext_vector_type(2)));
typedef float  f32x4  __attribute__((ext_vector_type(4)));

DEVFN float gelu_exact(float x){ return 0.5f*x*(1.f+erff(x*0.70710678118654752f)); }
DEVFN float silu_f(float x){ return x/(1.f+expf(-x)); }

DEVFN bf16x8 pack8(float4 a, float4 b){
  bf16x8 r;
  r[0]=(__bf16)a.x; r[1]=(__bf16)a.y; r[2]=(__bf16)a.z; r[3]=(__bf16)a.w;
  r[4]=(__bf16)b.x; r[5]=(__bf16)b.y; r[6]=(__bf16)b.z; r[7]=(__bf16)b.w;
  return r;
}
DEVFN f32x4 mfma16(bf16x8 a, bf16x8 b, f32x4 c){
  return __builtin_amdgcn_mfma_f32_16x16x32_bf16(a, b, c, 0, 0, 0);
}

// ---------------------------------------------------------------------------
// convert all GEMM weights fp32 -> bf16 pool (one pass)
// ---------------------------------------------------------------------------
__global__ __launch_bounds__(256)
void cvt_w(const float* __restrict__ w_inproj, const float* __restrict__ w_outproj,
           const float* __restrict__ wq, const float* __restrict__ wk,
           const float* __restrict__ wv, const float* __restrict__ wo,
           const float* __restrict__ w1, __bf16* __restrict__ wbf)
{
  int i4 = (blockIdx.x*256 + threadIdx.x)*4;
  const float* src;
  if      (i4 < W_OUTPROJ) src = w_inproj  + i4;
  else if (i4 < W_Q)       src = w_outproj + (i4 - W_OUTPROJ);
  else if (i4 < W_K)       src = wq + (i4 - W_Q);
  else if (i4 < W_V)       src = wk + (i4 - W_K);
  else if (i4 < W_O)       src = wv + (i4 - W_V);
  else if (i4 < W_1)       src = wo + (i4 - W_O);
  else                     src = w1 + (i4 - W_1);
  float4 v = *(const float4*)src;
  bf16x4 o;
  o[0]=(__bf16)v.x; o[1]=(__bf16)v.y; o[2]=(__bf16)v.z; o[3]=(__bf16)v.w;
  *(bf16x4*)(wbf + i4) = o;
}

// ---------------------------------------------------------------------------
// 64x64-tile GEMM, generalized: AF32 A-staging, optional GELU, N guarded.
// grid (M/64, ceil(N/64)); 4 waves; register-prefetch pipelined.
// ---------------------------------------------------------------------------
template<int ACT, bool HASBIAS, bool AF32>
__global__ __launch_bounds__(256)
void gemm64x(const void* __restrict__ Av, const __bf16* __restrict__ W,
             const float* __restrict__ bias, __bf16* __restrict__ C,
             int M, int N, int K)
{
  __shared__ __bf16 As[64][40];
  __shared__ __bf16 Ws[64][40];
  const int tid = threadIdx.x;
  const int bm = blockIdx.x*64, bn = blockIdx.y*64;
  const int w = tid >> 6, lane = tid & 63;
  const int quad = lane >> 4, mr = lane & 15;
  const int wm = (w >> 1) * 32, wn = (w & 1) * 32;
  const int srow = tid >> 2, skc = (tid & 3) * 8;

  const float*  apf = (const float*)Av + (size_t)(bm + srow)*K + skc;
  const __bf16* apb = (const __bf16*)Av + (size_t)(bm + srow)*K + skc;
  const bool wok = (bn + srow) < N;
  const __bf16* wp = W + (size_t)(bn + srow)*K + skc;

  bf16x8 zb{};
  bf16x8 a0;
  if (AF32) a0 = pack8(*(const float4*)apf, *(const float4*)(apf+4));
  else      a0 = *(const bf16x8*)apb;
  bf16x8 w0 = wok ? *(const bf16x8*)wp : zb;

  f32x4 acc[2][2];
  #pragma unroll
  for (int i=0;i<2;i++)
    #pragma unroll
    for (int j=0;j<2;j++) acc[i][j] = f32x4{0.f,0.f,0.f,0.f};

  for (int k0 = 0; k0 < K; k0 += 32){
    __syncthreads();
    *(bf16x8*)&As[srow][skc] = a0;
    *(bf16x8*)&Ws[srow][skc] = w0;
    __syncthreads();
    if (k0 + 32 < K){
      if (AF32) a0 = pack8(*(const float4*)(apf+k0+32), *(const float4*)(apf+k0+36));
      else      a0 = *(const bf16x8*)(apb+k0+32);
      w0 = wok ? *(const bf16x8*)(wp+k0+32) : zb;
    }
    bf16x8 af[2], bfr[2];
    af[0]  = *(const bf16x8*)&As[wm      + mr][quad*8];
    af[1]  = *(const bf16x8*)&As[wm + 16 + mr][quad*8];
    bfr[0] = *(const bf16x8*)&Ws[wn      + mr][quad*8];
    bfr[1] = *(const bf16x8*)&Ws[wn + 16 + mr][quad*8];
    #pragma unroll
    for (int i=0;i<2;i++)
      #pragma unroll
      for (int j=0;j<2;j++)
        acc[i][j] = mfma16(af[i], bfr[j], acc[i][j]);
  }

  #pragma unroll
  for (int j=0;j<2;j++){
    int col = bn + wn + j*16 + mr;
    if (col >= N) continue;
    float bb = HASBIAS ? bias[col] : 0.f;
    #pragma unroll
    for (int i=0;i<2;i++)
      #pragma unroll
      for (int reg=0;reg<4;reg++){
        int row = bm + wm + i*16 + quad*4 + reg;
        float vv = acc[i][j][reg] + bb;
        if (ACT == 1) vv = gelu_exact(vv);
        C[(size_t)row*N + col] = (__bf16)vv;
      }
  }
}

// ---------------------------------------------------------------------------
// 64x64-tile GEMM, A bf16, W bf16, register-prefetch pipelined.
// ---------------------------------------------------------------------------
template<bool HASBIAS, bool HASRESF>
__global__ __launch_bounds__(256)
void gemm64b(const __bf16* __restrict__ A, const __bf16* __restrict__ W,
             const float* __restrict__ bias, const float* __restrict__ residf,
             __bf16* __restrict__ Cb, int M, int N, int K)
{
  __shared__ __bf16 As[64][40];
  __shared__ __bf16 Ws[64][40];
  const int tid = threadIdx.x;
  const int bm = blockIdx.x*64, bn = blockIdx.y*64;
  const int w = tid >> 6, lane = tid & 63;
  const int quad = lane >> 4, mr = lane & 15;
  const int wm = (w >> 1) * 32, wn = (w & 1) * 32;
  const int srow = tid >> 2, skc = (tid & 3) * 8;

  const __bf16* ap = A + (size_t)(bm + srow)*K + skc;
  const __bf16* wp = W + (size_t)(bn + srow)*K + skc;
  bf16x8 a0 = *(const bf16x8*)ap;
  bf16x8 w0 = *(const bf16x8*)wp;

  f32x4 acc[2][2];
  #pragma unroll
  for (int i=0;i<2;i++)
    #pragma unroll
    for (int j=0;j<2;j++) acc[i][j] = f32x4{0.f,0.f,0.f,0.f};

  for (int k0 = 0; k0 < K; k0 += 32){
    __syncthreads();
    *(bf16x8*)&As[srow][skc] = a0;
    *(bf16x8*)&Ws[srow][skc] = w0;
    __syncthreads();
    if (k0 + 32 < K){
      a0 = *(const bf16x8*)(ap+k0+32);
      w0 = *(const bf16x8*)(wp+k0+32);
    }
    bf16x8 af[2], bfr[2];
    af[0]  = *(const bf16x8*)&As[wm      + mr][quad*8];
    af[1]  = *(const bf16x8*)&As[wm + 16 + mr][quad*8];
    bfr[0] = *(const bf16x8*)&Ws[wn      + mr][quad*8];
    bfr[1] = *(const bf16x8*)&Ws[wn + 16 + mr][quad*8];
    #pragma unroll
    for (int i=0;i<2;i++)
      #pragma unroll
      for (int j=0;j<2;j++)
        acc[i][j] = mfma16(af[i], bfr[j], acc[i][j]);
  }

  #pragma unroll
  for (int j=0;j<2;j++){
    int col = bn + wn + j*16 + mr;
    float bb = HASBIAS ? bias[col] : 0.f;
    #pragma unroll
    for (int i=0;i<2;i++)
      #pragma unroll
      for (int reg=0;reg<4;reg++){
        int row = bm + wm + i*16 + quad*4 + reg;
        float vv = acc[i][j][reg] + bb;
        if (HASRESF) vv += residf[(size_t)row*N + col];
        Cb[(size_t)row*N + col] = (__bf16)vv;
      }
  }
}

// ---------------------------------------------------------------------------
// batched q,k,v GEMM: grid (M/64, N/64, 3). z=2 writes transposed Vt.
// ---------------------------------------------------------------------------
__global__ __launch_bounds__(256)
void qkv_gemm(const __bf16* __restrict__ hres, const float* __restrict__ ctx,
              const __bf16* __restrict__ wbf, __bf16* __restrict__ qo,
              __bf16* __restrict__ ko, __bf16* __restrict__ vt)
{
  __shared__ __bf16 As[64][40];
  __shared__ __bf16 Ws[64][40];
  const int tid = threadIdx.x;
  const int bm = blockIdx.x*64, bn = blockIdx.y*64, z = blockIdx.z;
  const int K = DM, N = DM;
  const bool abf = (z == 0);
  const __bf16* W = wbf + ((z == 0) ? W_Q : (z == 1) ? W_K : W_V);
  const int w = tid >> 6, lane = tid & 63;
  const int quad = lane >> 4, mr = lane & 15;
  const int wm = (w >> 1) * 32, wn = (w & 1) * 32;
  const int srow = tid >> 2, skc = (tid & 3) * 8;

  const __bf16* apb = hres + (size_t)(bm + srow)*K + skc;
  const float*  apf = ctx  + (size_t)(bm + srow)*K + skc;
  const __bf16* wp  = W + (size_t)(bn + srow)*K + skc;
  bf16x8 a0;
  if (abf) a0 = *(const bf16x8*)apb;
  else     a0 = pack8(*(const float4*)apf, *(const float4*)(apf+4));
  bf16x8 w0 = *(const bf16x8*)wp;

  f32x4 acc[2][2];
  #pragma unroll
  for (int i=0;i<2;i++)
    #pragma unroll
    for (int j=0;j<2;j++) acc[i][j] = f32x4{0.f,0.f,0.f,0.f};

  for (int k0 = 0; k0 < K; k0 += 32){
    __syncthreads();
    *(bf16x8*)&As[srow][skc] = a0;
    *(bf16x8*)&Ws[srow][skc] = w0;
    __syncthreads();
    if (k0 + 32 < K){
      if (abf) a0 = *(const bf16x8*)(apb+k0+32);
      else     a0 = pack8(*(const float4*)(apf+k0+32), *(const float4*)(apf+k0+36));
      w0 = *(const bf16x8*)(wp+k0+32);
    }
    bf16x8 af[2], bfr[2];
    af[0]  = *(const bf16x8*)&As[wm      + mr][quad*8];
    af[1]  = *(const bf16x8*)&As[wm + 16 + mr][quad*8];
    bfr[0] = *(const bf16x8*)&Ws[wn      + mr][quad*8];
    bfr[1] = *(const bf16x8*)&Ws[wn + 16 + mr][quad*8];
    #pragma unroll
    for (int i=0;i<2;i++)
      #pragma unroll
      for (int j=0;j<2;j++)
        acc[i][j] = mfma16(af[i], bfr[j], acc[i][j]);
  }

  if (z < 2){
    __bf16* C = (z == 0) ? qo : ko;
    #pragma unroll
    for (int j=0;j<2;j++){
      int col = bn + wn + j*16 + mr;
      #pragma unroll
      for (int i=0;i<2;i++)
        #pragma unroll
        for (int reg=0;reg<4;reg++){
          int row = bm + wm + i*16 + quad*4 + reg;
          C[(size_t)row*N + col] = (__bf16)acc[i][j][reg];
        }
    }
  } else {
    #pragma unroll
    for (int j=0;j<2;j++){
      int col = bn + wn + j*16 + mr;
      int h = col >> 5, dl = col & 31;
      #pragma unroll
      for (int i=0;i<2;i++){
        int rowb = bm + wm + i*16 + quad*4;
        int b = rowb >> 11, t = rowb & 2047;
        bf16x4 o;
        #pragma unroll
        for (int reg=0;reg<4;reg++) o[reg] = (__bf16)acc[i][j][reg];
        *(bf16x4*)(vt + ((size_t)(b*NH + h)*32 + dl)*SEQ + t) = o;
      }
    }
  }
}

// ---------------------------------------------------------------------------
// fused causal depthwise conv(4)+SiLU (x4 channels) and dt/log-dA
// ---------------------------------------------------------------------------
__global__ __launch_bounds__(256)
void conv_dt_kernel(const __bf16* __restrict__ zx, const float* __restrict__ convw,
                    const float* __restrict__ convb, const float* __restrict__ dt_bias,
                    const float* __restrict__ A_log, __bf16* __restrict__ xBC,
                    float* __restrict__ dtb, float* __restrict__ ldab)
{
  int idx = blockIdx.x*256 + threadIdx.x;     // over MTOK*CDIM/4
  int c4 = (idx % (CDIM/4))*4;
  int bt = idx / (CDIM/4);
  int b = bt >> 11, t = bt & 2047;
  float acc[4];
  float4 cb = *(const float4*)(convb + c4);
  acc[0]=cb.x; acc[1]=cb.y; acc[2]=cb.z; acc[3]=cb.w;
  float4 wrow[4];
  #pragma unroll
  for (int j=0;j<4;j++) wrow[j] = *(const float4*)(convw + (c4+j)*4);
  #pragma unroll
  for (int k=0;k<4;k++){
    int ts = t - 3 + k;
    if (ts >= 0){
      bf16x4 xv = *(const bf16x4*)(zx + (size_t)(b*SEQ + ts)*DPROJ + DI + c4);
      const float* wk4[4] = {(const float*)&wrow[0], (const float*)&wrow[1],
                             (const float*)&wrow[2], (const float*)&wrow[3]};
      #pragma unroll
      for (int j=0;j<4;j++) acc[j] = fmaf(wk4[j][k], (float)xv[j], acc[j]);
    }
  }
  bf16x4 o;
  #pragma unroll
  for (int j=0;j<4;j++) o[j] = (__bf16)silu_f(acc[j]);
  *(bf16x4*)(xBC + (size_t)bt*CDIM + c4) = o;
  if (c4 < NH){
    #pragma unroll
    for (int j=0;j<4;j++){
      int h = c4 + j;
      float raw = (float)zx[(size_t)bt*DPROJ + 2*DI + 2*DSTATE + h] + dt_bias[h];
      float dt = fmaxf(raw, 0.f) + log1pf(expf(-fabsf(raw)));
      int oo = (b*NH + h)*SEQ + t;
      dtb[oo]  = dt;
      ldab[oo] = -__expf(A_log[h]) * dt;
    }
  }
}

// ---------------------------------------------------------------------------
// SSD chunk_state (bf16 xBC, bf16 Hc out)
// ---------------------------------------------------------------------------
__global__ __launch_bounds__(256)
void chunk_state(const __bf16* __restrict__ xBC, const float* __restrict__ dtb,
                 const float* __restrict__ ldab, __bf16* __restrict__ Hc,
                 float* __restrict__ Ac)
{
  const int blk = blockIdx.x;
  const int ch = blk & 63, bh = blk >> 6;
  const int b = bh >> 3, h = bh & 7;
  const int t0 = ch*CHUNK;
  const int tid = threadIdx.x;
  __shared__ float csS[CHUNK], wendS[CHUNK];
  __shared__ __bf16 Xw[64][40];
  __shared__ __bf16 Bt[128][40];

  if (tid < 32){
    float v  = ldab[bh*SEQ + t0 + tid];
    float dtv = dtb[bh*SEQ + t0 + tid];
    #pragma unroll
    for (int off=1; off<32; off<<=1){
      float o = __shfl_up(v, off, 32);
      if (tid >= off) v += o;
    }
    csS[tid] = v;
    float cs31 = __shfl(v, 31, 32);
    wendS[tid] = __expf(cs31 - v) * dtv;
  }
  __syncthreads();
  {
    int s  = tid >> 3;
    int pg = (tid & 7) * 8;
    bf16x8 xv = *(const bf16x8*)(xBC + (size_t)(b*SEQ + t0 + s)*CDIM + h*HD + pg);
    float wgt = wendS[s];
    #pragma unroll
    for (int e=0;e<8;e++) Xw[pg+e][s] = (__bf16)((float)xv[e] * wgt);
    int ng = (tid & 7) * 16;
    const __bf16* bp = xBC + (size_t)(b*SEQ + t0 + s)*CDIM + DI + ng;
    bf16x8 b0 = *(const bf16x8*)bp;
    bf16x8 b1 = *(const bf16x8*)(bp+8);
    #pragma unroll
    for (int e=0;e<8;e++){ Bt[ng+e][s] = b0[e]; Bt[ng+8+e][s] = b1[e]; }
  }
  if (tid == 0) Ac[blk] = __expf(csS[31]);
  __syncthreads();

  const int w = tid >> 6, lane = tid & 63, quad = lane >> 4, mr = lane & 15;
  bf16x8 af = *(const bf16x8*)&Xw[w*16 + mr][quad*8];
  __bf16* out = Hc + (size_t)blk*8192;
  #pragma unroll
  for (int j=0;j<8;j++){
    bf16x8 bfm = *(const bf16x8*)&Bt[j*16 + mr][quad*8];
    f32x4 a = mfma16(af, bfm, f32x4{0.f,0.f,0.f,0.f});
    #pragma unroll
    for (int reg=0; reg<4; reg++){
      int p = w*16 + quad*4 + reg;
      out[p*128 + j*16 + mr] = (__bf16)a[reg];
    }
  }
}

// ---------------------------------------------------------------------------
// state_prefix: batch loads then serial fma chain
// ---------------------------------------------------------------------------
__global__ __launch_bounds__(256)
void state_prefix(__bf16* __restrict__ Hc, const float* __restrict__ Ac)
{
  const int blk = blockIdx.x;
  const int bh = blk >> 4, sub = blk & 15;
  const int tid = threadIdx.x;
  const int off = sub*512 + tid*2;
  __shared__ float AcS[64];
  if (tid < 64) AcS[tid] = Ac[bh*64 + tid];
  __bf16* base = Hc + (size_t)bh*64*8192 + off;
  bf16x2 v[64];
  #pragma unroll
  for (int c=0;c<64;c++) v[c] = *(const bf16x2*)(base + (size_t)c*8192);
  __syncthreads();
  float r0 = 0.f, r1 = 0.f;
  #pragma unroll
  for (int c=0;c<64;c++){
    bf16x2 o; o[0] = (__bf16)r0; o[1] = (__bf16)r1;
    *(bf16x2*)(base + (size_t)c*8192) = o;
    float a = AcS[c];
    r0 = fmaf(a, r0, (float)v[c][0]);
    r1 = fmaf(a, r1, (float)v[c][1]);
  }
}

// ---------------------------------------------------------------------------
// SSD chunk_out (bf16 xBC/h0, bf16 y out)
// ---------------------------------------------------------------------------
__global__ __launch_bounds__(256)
void chunk_out(const __bf16* __restrict__ xBC, const float* __restrict__ dtb,
               const float* __restrict__ ldab, const __bf16* __restrict__ h0buf,
               const float* __restrict__ Dparam, __bf16* __restrict__ ybuf)
{
  const int blk = blockIdx.x;
  const int ch = blk & 63, bh = blk >> 6;
  const int b = bh >> 3, h = bh & 7;
  const int t0 = ch*CHUNK;
  const int tid = threadIdx.x;
  __shared__ float csS[CHUNK], dtS[CHUNK];
  __shared__ __bf16 Xct[64][40];
  __shared__ __bf16 Ms[32][40];

  if (tid < 32){
    float v = ldab[bh*SEQ + t0 + tid];
    dtS[tid] = dtb[bh*SEQ + t0 + tid];
    #pragma unroll
    for (int off=1; off<32; off<<=1){
      float o = __shfl_up(v, off, 32);
      if (tid >= off) v += o;
    }
    csS[tid] = v;
  }
  __syncthreads();
  {
    int s  = tid >> 3;
    int pg = (tid & 7) * 8;
    bf16x8 xv = *(const bf16x8*)(xBC + (size_t)(b*SEQ + t0 + s)*CDIM + h*HD + pg);
    #pragma unroll
    for (int e=0;e<8;e++) Xct[pg+e][s] = xv[e];
  }

  const int w = tid >> 6, lane = tid & 63, quad = lane >> 4, mr = lane & 15;
  const int ti = w >> 1, si = w & 1;

  const __bf16* Crow = xBC + (size_t)(b*SEQ + t0 + ti*16 + mr)*CDIM + DI + DSTATE;
  bf16x8 af[4];
  #pragma unroll
  for (int kk=0; kk<4; kk++)
    af[kk] = *(const bf16x8*)(Crow + kk*32 + quad*8);
  f32x4 sacc = f32x4{0.f,0.f,0.f,0.f};
  const __bf16* Brow = xBC + (size_t)(b*SEQ + t0 + si*16 + mr)*CDIM + DI;
  #pragma unroll
  for (int kk=0; kk<4; kk++){
    bf16x8 bfm = *(const bf16x8*)(Brow + kk*32 + quad*8);
    sacc = mfma16(af[kk], bfm, sacc);
  }
  #pragma unroll
  for (int reg=0; reg<4; reg++){
    int t = ti*16 + quad*4 + reg;
    int s = si*16 + mr;
    float m = 0.f;
    if (s <= t) m = __expf(csS[t] - csS[s]) * dtS[s] * sacc[reg];
    Ms[t][s] = (__bf16)m;
  }
  __syncthreads();

  f32x4 acc[2] = { f32x4{0.f,0.f,0.f,0.f}, f32x4{0.f,0.f,0.f,0.f} };
  const __bf16* h0r = h0buf + (size_t)blk*8192;
  #pragma unroll
  for (int j=0;j<2;j++){
    int p = (si*2 + j)*16 + mr;
    #pragma unroll
    for (int kk=0; kk<4; kk++){
      bf16x8 bh0 = *(const bf16x8*)(h0r + (size_t)p*128 + kk*32 + quad*8);
      acc[j] = mfma16(af[kk], bh0, acc[j]);
    }
  }
  #pragma unroll
  for (int reg=0;reg<4;reg++){
    int t = ti*16 + quad*4 + reg;
    float e = __expf(csS[t]);
    acc[0][reg] *= e;
    acc[1][reg] *= e;
  }
  bf16x8 am = *(const bf16x8*)&Ms[ti*16 + mr][quad*8];
  #pragma unroll
  for (int j=0;j<2;j++){
    int p = (si*2 + j)*16 + mr;
    bf16x8 bx = *(const bf16x8*)&Xct[p][quad*8];
    acc[j] = mfma16(am, bx, acc[j]);
  }
  const float Dv = Dparam[h];
  #pragma unroll
  for (int j=0;j<2;j++){
    int p = (si*2 + j)*16 + mr;
    #pragma unroll
    for (int reg=0;reg<4;reg++){
      int t = t0 + ti*16 + quad*4 + reg;
      float xv = (float)xBC[(size_t)(b*SEQ + t)*CDIM + h*HD + p];
      ybuf[(size_t)(b*SEQ + t)*DI + h*HD + p] = (__bf16)fmaf(Dv, xv, acc[j][reg]);
    }
  }
}

// ---------------------------------------------------------------------------
// gated RMSNorm (bf16 y in-place, bf16 z)
// ---------------------------------------------------------------------------
__global__ __launch_bounds__(128)
void rmsgate_kernel(__bf16* __restrict__ y, const __bf16* __restrict__ zx,
                    const float* __restrict__ normw)
{
  const int row = blockIdx.x, tid = threadIdx.x;
  const __bf16* zrow = zx + (size_t)row*DPROJ;
  __bf16* yrow = y + (size_t)row*DI;
  bf16x4 yv = *(const bf16x4*)(yrow + tid*4);
  bf16x4 zv = *(const bf16x4*)(zrow + tid*4);
  float g[4];
  float ss = 0.f;
  #pragma unroll
  for (int e=0;e<4;e++){
    g[e] = (float)yv[e] * silu_f((float)zv[e]);
    ss += g[e]*g[e];
  }
  #pragma unroll
  for (int off=1; off<64; off<<=1) ss += __shfl_xor(ss, off);
  __shared__ float red[2];
  if ((tid & 63)==0) red[tid>>6] = ss;
  __syncthreads();
  float tot = red[0] + red[1];
  float rs = rsqrtf(tot * (1.f/DI) + 1e-5f);
  float4 nw = *(const float4*)(normw + tid*4);
  const float* nwp = (const float*)&nw;
  bf16x4 o;
  #pragma unroll
  for (int e=0;e<4;e++) o[e] = (__bf16)(g[e]*rs*nwp[e]);
  *(bf16x4*)(yrow + tid*4) = o;
}

// ---------------------------------------------------------------------------
// Split-KV MFMA flash attention (hd=32), barrier-free K-loop, register
// prefetch. NSPLIT=8 -> 2048 blocks = 8 blocks/CU.
// ---------------------------------------------------------------------------
__global__ __launch_bounds__(256)
void flash_part(const __bf16* __restrict__ qb, const __bf16* __restrict__ kb,
                const __bf16* __restrict__ vt, float* __restrict__ opart,
                float* __restrict__ lpart)
{
  const int qt = blockIdx.x, ksp = blockIdx.y, bh = blockIdx.z;
  const int b = bh >> 3, h = bh & 7;
  const int tid = threadIdx.x;
  const int w = tid >> 6, lane = tid & 63;
  const int quad = lane >> 4, mr = lane & 15;
  const int qrow0 = b*SEQ + qt*128 + w*32;
  const float SC = 0.17677669529663687f;   // 1/sqrt(32)
  __shared__ __bf16 Pq[4][32][72];

  const __bf16* kbase_p = kb + (size_t)(b*SEQ + ksp*KVLEN + mr)*DM + h*32 + quad*8;
  const __bf16* vbase_p = vt + ((size_t)bh*32 + mr)*SEQ + ksp*KVLEN + quad*8;

  bf16x8 bq[2];
  #pragma unroll
  for (int i2=0;i2<2;i2++)
    bq[i2] = *(const bf16x8*)(qb + (size_t)(qrow0 + i2*16 + mr)*DM + h*32 + quad*8);

  f32x4 accO[2][2];
  #pragma unroll
  for (int i=0;i<2;i++)
    #pragma unroll
    for (int j=0;j<2;j++) accO[i][j] = f32x4{0.f,0.f,0.f,0.f};
  float lacc[2] = {0.f, 0.f};

  bf16x8 akc[4], bvc[2][2];
  #pragma unroll
  for (int ik=0;ik<4;ik++)
    akc[ik] = *(const bf16x8*)(kbase_p + (size_t)ik*16*DM);
  #pragma unroll
  for (int ks=0;ks<2;ks++)
    #pragma unroll
    for (int j2=0;j2<2;j2++)
      bvc[ks][j2] = *(const bf16x8*)(vbase_p + (size_t)j2*16*SEQ + ks*32);

  for (int kt=0; kt<NKT; kt++){
    bf16x8 akn[4], bvn[2][2];
    if (kt + 1 < NKT){
      #pragma unroll
      for (int ik=0;ik<4;ik++)
        akn[ik] = *(const bf16x8*)(kbase_p + (size_t)(kt+1)*64*DM + (size_t)ik*16*DM);
      #pragma unroll
      for (int ks=0;ks<2;ks++)
        #pragma unroll
        for (int j2=0;j2<2;j2++)
          bvn[ks][j2] = *(const bf16x8*)(vbase_p + (size_t)j2*16*SEQ + (kt+1)*64 + ks*32);
    }
    #pragma unroll
    for (int ik=0; ik<4; ik++){
      #pragma unroll
      for (int jq=0; jq<2; jq++){
        f32x4 st = mfma16(akc[ik], bq[jq], f32x4{0.f,0.f,0.f,0.f});
        bf16x4 e4;
        #pragma unroll
        for (int reg=0; reg<4; reg++){
          float e = __expf(st[reg] * SC);
          lacc[jq] += e;
          e4[reg] = (__bf16)e;
        }
        *(bf16x4*)&Pq[w][jq*16 + mr][ik*16 + quad*4] = e4;
      }
    }
    #pragma unroll
    for (int ks=0; ks<2; ks++){
      bf16x8 pa0 = *(const bf16x8*)&Pq[w][     mr][ks*32 + quad*8];
      bf16x8 pa1 = *(const bf16x8*)&Pq[w][16 + mr][ks*32 + quad*8];
      #pragma unroll
      for (int j2=0; j2<2; j2++){
        accO[0][j2] = mfma16(pa0, bvc[ks][j2], accO[0][j2]);
        accO[1][j2] = mfma16(pa1, bvc[ks][j2], accO[1][j2]);
      }
    }
    #pragma unroll
    for (int ik=0;ik<4;ik++) akc[ik] = akn[ik];
    #pragma unroll
    for (int ks=0;ks<2;ks++)
      #pragma unroll
      for (int j2=0;j2<2;j2++) bvc[ks][j2] = bvn[ks][j2];
  }

  #pragma unroll
  for (int jq=0;jq<2;jq++){
    float v = lacc[jq];
    v += __shfl_xor(v, 16);
    v += __shfl_xor(v, 32);
    lacc[jq] = v;
  }
  #pragma unroll
  for (int i2=0;i2<2;i2++)
    #pragma unroll
    for (int j2=0;j2<2;j2++)
      #pragma unroll
      for (int reg=0;reg<4;reg++){
        int row = qrow0 + i2*16 + quad*4 + reg;
        opart[((size_t)ksp*MTOK + row)*DM + h*32 + j2*16 + mr] = accO[i2][j2][reg];
      }
  if (quad == 0){
    #pragma unroll
    for (int jq=0;jq<2;jq++)
      lpart[((size_t)ksp*16 + bh)*SEQ + (qt*128 + w*32 + jq*16 + mr)] = lacc[jq];
  }
}

// combine: o = sum_s O_s / sum_s l_s  -> bf16 (streaming)
__global__ __launch_bounds__(256)
void flash_combine(const float* __restrict__ opart, const float* __restrict__ lpart,
                   __bf16* __restrict__ o)
{
  int idx = blockIdx.x*256 + threadIdx.x;   // over MTOK*64
  int row = idx >> 6, d4 = (idx & 63)*4;
  int h = d4 >> 5;
  int b = row >> 11, t = row & 2047;
  float sx=0.f, sy=0.f, sz=0.f, sw=0.f, lsum=0.f;
  #pragma unroll
  for (int s4=0; s4<NSPLIT; s4++){
    float4 vv = *(const float4*)(opart + ((size_t)s4*MTOK + row)*DM + d4);
    sx += vv.x; sy += vv.y; sz += vv.z; sw += vv.w;
    lsum += lpart[((size_t)s4*16 + b*8 + h)*SEQ + t];
  }
  float inv = 1.f / lsum;
  bf16x4 ov;
  ov[0]=(__bf16)(sx*inv); ov[1]=(__bf16)(sy*inv);
  ov[2]=(__bf16)(sz*inv); ov[3]=(__bf16)(sw*inv);
  *(bf16x4*)(o + (size_t)row*DM + d4) = ov;
}

// ---------------------------------------------------------------------------
// fused LayerNorm + pool partial: block = 16 rows; no h1 writeback.
// ---------------------------------------------------------------------------
__global__ __launch_bounds__(256)
void ln_pool(const __bf16* __restrict__ h1, const float* __restrict__ lnw,
             const float* __restrict__ lnb, float* __restrict__ pp)
{
  const int blk = blockIdx.x;
  const int tid = threadIdx.x;
  const int row0 = blk*16;
  __shared__ float s1[4], s2[4];
  float4 wv = *(const float4*)(lnw + tid*4);
  float4 bv = *(const float4*)(lnb + tid*4);
  const float* wp = (const float*)&wv;
  const float* bp = (const float*)&bv;
  float acc[4] = {0.f,0.f,0.f,0.f};
  for (int r=0;r<16;r++){
    bf16x4 v4 = *(const bf16x4*)(h1 + (size_t)(row0+r)*HID + tid*4);
    float v[4];
    float sum=0.f, sq=0.f;
    #pragma unroll
    for (int e=0;e<4;e++){ v[e]=(float)v4[e]; sum+=v[e]; sq+=v[e]*v[e]; }
    #pragma unroll
    for (int off=1; off<64; off<<=1){ sum += __shfl_xor(sum,off); sq += __shfl_xor(sq,off); }
    int w = tid>>6;
    __syncthreads();
    if ((tid & 63)==0){ s1[w]=sum; s2[w]=sq; }
    __syncthreads();
    sum = (s1[0]+s1[1])+(s1[2]+s1[3]);
    sq  = (s2[0]+s2[1])+(s2[2]+s2[3]);
    float mu = sum * (1.f/HID);
    float var = sq * (1.f/HID) - mu*mu;
    float rstd = rsqrtf(var + 1e-5f);
    #pragma unroll
    for (int e=0;e<4;e++) acc[e] += (v[e]-mu)*rstd*wp[e] + bp[e];
  }
  *(float4*)(pp + (size_t)blk*HID + tid*4) = make_float4(acc[0],acc[1],acc[2],acc[3]);
}

// ---------------------------------------------------------------------------
// head tail, parallelized: reduce_pool (16 blk) -> fc2head (64 blk) -> final
// ---------------------------------------------------------------------------
__global__ __launch_bounds__(128)
void reduce_pool(const float* __restrict__ pp, float* __restrict__ pooled)
{
  const int b = blockIdx.y, cg = blockIdx.x;       // grid (8, 2)
  const int c = cg*128 + threadIdx.x;
  float s = 0.f;
  #pragma unroll 8
  for (int seg=0; seg<128; seg++)
    s += pp[((size_t)(b*128+seg))*HID + c];
  pooled[b*HID + c] = s * (1.f/(float)SEQ);
}

__global__ __launch_bounds__(256)
void fc2head(const float* __restrict__ pooled, const float* __restrict__ w2,
             const float* __restrict__ b2, float* __restrict__ w2h)
{
  const int b = blockIdx.y, og = blockIdx.x;       // grid (32, 2)
  const int tid = threadIdx.x;
  const int r = tid >> 5, l32 = tid & 31;          // 8 rows x 32 lanes
  const int col = og*8 + r;
  const float* wr = w2 + (size_t)col*HID + l32*32;
  const float* pv = pooled + b*HID + l32*32;
  float acc = 0.f;
  #pragma unroll
  for (int k=0;k<32;k+=4){
    float4 wv4 = *(const float4*)(wr+k);
    float4 p4  = *(const float4*)(pv+k);
    acc += wv4.x*p4.x + wv4.y*p4.y + wv4.z*p4.z + wv4.w*p4.w;
  }
  #pragma unroll
  for (int off=1; off<32; off<<=1) acc += __shfl_xor(acc, off);
  if (l32 == 0) w2h[b*DM + col] = acc + b2[col];
}

__global__ __launch_bounds__(128)
void head_final(const float* __restrict__ w2h, const float* __restrict__ hw,
                const float* __restrict__ hb, float* __restrict__ out)
{
  const int b = blockIdx.x, tid = threadIdx.x;
  int cls = tid >> 6, lane = tid & 63;
  float acc = 0.f;
  for (int c=lane;c<DM;c+=64) acc += w2h[b*DM + c]*hw[cls*DM+c];
  #pragma unroll
  for (int off=1;off<64;off<<=1) acc += __shfl_xor(acc, off);
  if (lane == 0) out[b*2 + cls] = acc + hb[cls];
}

// ---------------------------------------------------------------------------
extern "C" void kernel_launch(void* const* d_in, const int* in_sizes, int n_in,
                              void* d_out, int out_size, void* d_ws, size_t ws_size,
                              hipStream_t stream)
{
  const float* x         = (const float*)d_in[0];
  const float* context   = (const float*)d_in[1];
  const float* in_proj_w = (const float*)d_in[2];
  const float* conv_w    = (const float*)d_in[3];
  const float* conv_b    = (const float*)d_in[4];
  const float* dt_bias   = (const float*)d_in[5];
  const float* A_log     = (const float*)d_in[6];
  const float* D_param   = (const float*)d_in[7];
  const float* norm_w    = (const float*)d_in[8];
  const float* out_proj_w= (const float*)d_in[9];
  const float* wq  = (const float*)d_in[10];
  const float* wk  = (const float*)d_in[11];
  const float* wv  = (const float*)d_in[12];
  const float* wo  = (const float*)d_in[13];
  const float* wo_b= (const float*)d_in[14];
  const float* w1  = (const float*)d_in[15];
  const float* b1  = (const float*)d_in[16];
  const float* ln_w= (const float*)d_in[17];
  const float* ln_b= (const float*)d_in[18];
  const float* w2  = (const float*)d_in[19];
  const float* b2  = (const float*)d_in[20];
  const float* head_w = (const float*)d_in[21];
  const float* head_b = (const float*)d_in[22];
  float* out = (float*)d_out;
  float* ws  = (float*)d_ws;

  // workspace layout (float offsets; bf16 regions cast). Aliases noted.
  __bf16* zx    = (__bf16*)ws;                     // 2,637,824 fl
  __bf16* xBC   = (__bf16*)(ws + 2637824);         // 1,572,864
  float* dtb    = ws + 4210688;                    // 32,768
  float* ldab   = ws + 4243456;                    // 32,768
  __bf16* Hcb   = (__bf16*)(ws + 4276224);         // 4,194,304 fl
  float* Acb    = ws + 8470528;                    // 1,024
  __bf16* ybuf  = (__bf16*)(ws + 8471552);         // 1,048,576
  __bf16* hres  = (__bf16*)(ws + 9520128);         // 524,288
  __bf16* qbf   = (__bf16*)(ws + 10044416);        // 524,288
  __bf16* kbf   = (__bf16*)(ws + 10568704);        // 524,288
  __bf16* vtbf  = (__bf16*)(ws + 11092992);        // 524,288
  float* opart  = ws + 11617280;                   // 8,388,608 (NSPLIT=8)
  float* lpart  = ws + 20005888;                   // 262,144
  __bf16* obf   = (__bf16*)(ws + 20268032);        // 524,288
  __bf16* o2bf  = (__bf16*)(ws + 20792320);        // 524,288
  __bf16* wbf   = (__bf16*)(ws + 21316608);        // 492,544
  float* pooled = ws + 21809152;                   // 2,048
  float* w2h    = ws + 21811200;                   // 512
  // h1 (4096x1024 bf16 = 1,048,576 fl) -> Hcb region (dead after chunk_out)
  __bf16* h1bf  = (__bf16*)(ws + 4276224);
  // poolp [256][1024] fp32 = 262,144 fl -> opart region (dead after combine)
  float* poolp  = ws + 11617280;

  const dim3 g64(MTOK/64, DM/64);                  // 256 blocks

  // 0. convert weights to bf16 pool
  cvt_w<<<dim3(W_TOT/1024), dim3(256), 0, stream>>>(
      in_proj_w, out_proj_w, wq, wk, wv, wo, w1, wbf);
  // 1. in_proj (A fp32) -> zx bf16 : 64-tile, (64,21) = 1344 blocks
  gemm64x<0,false,true><<<dim3(MTOK/64, (DPROJ+63)/64), dim3(256), 0, stream>>>(
      x, wbf + W_INPROJ, nullptr, zx, MTOK, DPROJ, DM);
  // 2. conv + silu + dt/log-dA (fused, x4 channels)
  conv_dt_kernel<<<dim3(MTOK*CDIM/1024), dim3(256), 0, stream>>>(
      zx, conv_w, conv_b, dt_bias, A_log, xBC, dtb, ldab);
  // 3. SSD scan
  chunk_state<<<dim3(BATCH*NH*NCHUNK), dim3(256), 0, stream>>>(
      xBC, dtb, ldab, Hcb, Acb);
  state_prefix<<<dim3(256), dim3(256), 0, stream>>>(Hcb, Acb);
  chunk_out<<<dim3(BATCH*NH*NCHUNK), dim3(256), 0, stream>>>(
      xBC, dtb, ldab, Hcb, D_param, ybuf);
  // 4. gated rmsnorm (in place, bf16)
  rmsgate_kernel<<<dim3(MTOK), dim3(128), 0, stream>>>(ybuf, zx, norm_w);
  // 5. out_proj + residual x (fp32) -> hres bf16  (K=512)
  gemm64b<false,true><<<g64, dim3(256), 0, stream>>>(
      ybuf, wbf + W_OUTPROJ, nullptr, x, hres, MTOK, DM, DI);
  // 6. q,k,v in one launch; v written transposed
  qkv_gemm<<<dim3(MTOK/64, DM/64, 3), dim3(256), 0, stream>>>(
      hres, context, wbf, qbf, kbf, vtbf);
  // 7. attention partials (NSPLIT=8) + streaming combine
  flash_part<<<dim3(SEQ/128, NSPLIT, BATCH*NH), dim3(256), 0, stream>>>(
      qbf, kbf, vtbf, opart, lpart);
  flash_combine<<<dim3(MTOK*64/256), dim3(256), 0, stream>>>(opart, lpart, obf);
  // 8. attention out_proj (+bias) -> o2 bf16  (K=256)
  gemm64b<true,false><<<g64, dim3(256), 0, stream>>>(
      obf, wbf + W_O, wo_b, nullptr, o2bf, MTOK, DM, DM);
  // 9. mlp fc1 + gelu -> h1 bf16 : 64-tile, (64,16) = 1024 blocks
  gemm64x<1,true,false><<<dim3(MTOK/64, HID/64), dim3(256), 0, stream>>>(
      o2bf, wbf + W_1, b1, h1bf, MTOK, HID, DM);
  // 10. fused layernorm + pool partials (no h1 writeback)
  ln_pool<<<dim3(256), dim3(256), 0, stream>>>(h1bf, ln_w, ln_b, poolp);
  // 11. head tail, parallelized
  reduce_pool<<<dim3(8, BATCH), dim3(128), 0, stream>>>(poolp, pooled);
  fc2head<<<dim3(32, BATCH), dim3(256), 0, stream>>>(pooled, w2, b2, w2h);
  head_final<<<dim3(BATCH), dim3(128), 0, stream>>>(w2h, head_w, head_b, out);
  (void)in_sizes; (void)n_in; (void)out_size; (void)ws_size;
}